// Round 7
// baseline (607.869 us; speedup 1.0000x reference)
//
#include <hip/hip_runtime.h>
#include <math.h>

#define BB 32
#define DD 128
#define TLEN 4096
#define NSEG 512
#define HOP 256
#define NFR 17
#define NBINS 257
#define STOT 4369
#define NPATCH 196
#define NFREQ 99
#define OLAL 4608

// workspace layout (float offsets)
#define FBT2_OFF 0
#define FBT2_SZ  (DD * NFR * NBINS * 2)       // 1,118,464
#define GBUF_OFF (FBT2_OFF + FBT2_SZ)
#define GATE_OFF (GBUF_OFF + BB * DD)
#define ZI_OFF   (GATE_OFF + BB * DD)
#define ZI_SZ    (BB * NFREQ * DD * 2)        // 811,008
#define X0I_OFF  (ZI_OFF + ZI_SZ)
#define X0I_SZ   (BB * NPATCH * DD)           // 802,816
#define XT_OFF   (X0I_OFF + X0I_SZ)
#define WF_OFF   (XT_OFF + BB * DD * TLEN)    // bf16 hi/lo weight fragments (4 mats x 32768 ushort)

typedef __attribute__((ext_vector_type(8))) short bf16x8;
typedef __attribute__((ext_vector_type(4))) float f32x4;
typedef __attribute__((ext_vector_type(8))) unsigned short u16x8;

__device__ __forceinline__ float gelu_exact(float x) {
    return 0.5f * x * (1.0f + erff(x * 0.70710678118654752f));
}

__device__ __forceinline__ short bf16_rne(float v) {
    unsigned b = __float_as_uint(v);
    return (short)((b + 0x7fffu + ((b >> 16) & 1u)) >> 16);
}

// split fp32 -> bf16 hi + bf16 lo (v ~= hi + lo, error ~2^-17 relative)
__device__ __forceinline__ void split8(float4 a, float4 b, bf16x8& hi, bf16x8& lo) {
    float v[8] = {a.x, a.y, a.z, a.w, b.x, b.y, b.z, b.w};
#pragma unroll
    for (int e = 0; e < 8; ++e) {
        unsigned bv = __float_as_uint(v[e]);
        unsigned hb = (bv + 0x7fffu + ((bv >> 16) & 1u)) & 0xffff0000u;
        float hf = __uint_as_float(hb);
        hi[e] = (short)(hb >> 16);
        lo[e] = bf16_rne(v[e] - hf);
    }
}

// ---------------------------------------------------- pack w1/w2 MFMA frags
__global__ __launch_bounds__(256) void prep_wfrag(
    const float* __restrict__ w0, const float* __restrict__ w1,
    const float* __restrict__ w2, const float* __restrict__ w3,
    unsigned short* __restrict__ outw) {
    int id = blockIdx.x * 256 + threadIdx.x;
    if (id >= 4 * 2048) return;
    int m = id >> 11;
    int r = id & 2047;                 // (kt, n, lane)
    int kt = r >> 9;
    int n = (r >> 6) & 7;
    int lane = r & 63;
    int k0 = kt * 32 + (lane >> 4) * 8;
    int col = n * 16 + (lane & 15);
    const float* w = (m == 0) ? w0 : (m == 1) ? w1 : (m == 2) ? w2 : w3;
    u16x8 hi, lo;
#pragma unroll
    for (int e = 0; e < 8; ++e) {
        float v = w[(size_t)(k0 + e) * DD + col];
        unsigned bv = __float_as_uint(v);
        unsigned hb = (bv + 0x7fffu + ((bv >> 16) & 1u)) & 0xffff0000u;
        float hf = __uint_as_float(hb);
        float lres = v - hf;
        unsigned bl = __float_as_uint(lres);
        hi[e] = (unsigned short)(hb >> 16);
        lo[e] = (unsigned short)((bl + 0x7fffu + ((bl >> 16) & 1u)) >> 16);
    }
    u16x8* base = (u16x8*)(outw + (size_t)m * 32768);
    base[r] = hi;
    base[2048 + r] = lo;
}

// --------------------------- tfb -> fbt2 (D,17,257,2); also zeroes gbuf
__global__ __launch_bounds__(256) void prep_fb(const float* __restrict__ tfb,
                                               float* __restrict__ fbt2,
                                               float* __restrict__ gbuf) {
    int idx = blockIdx.x * 256 + threadIdx.x;
    if (idx < BB * DD) gbuf[idx] = 0.0f;
    if (idx >= STOT * DD) return;
    int d = idx & 127;
    int s = idx >> 7;
    float2 a = ((const float2*)tfb)[s * DD + d];
    float2 b = ((const float2*)tfb)[STOT * DD + s * DD + d];
    int f = s / NFR, t = s % NFR;
    float2 r;
    r.x = -(a.x + b.x);
    r.y = -(a.y + b.y);
    ((float2*)fbt2)[((size_t)d * NFR + t) * NBINS + f] = r;
}

// ------------------------------------------------- ecg (B,T,D) -> (B,D,T)
__global__ __launch_bounds__(256) void transpose_btd(const float* __restrict__ in,
                                                     float* __restrict__ out) {
    __shared__ float tile[32][33];
    int b = blockIdx.z;
    int t0 = blockIdx.x * 32;
    int d0 = blockIdx.y * 32;
    int lx = threadIdx.x;
    int ly = threadIdx.y;
    for (int i = ly; i < 32; i += 8)
        tile[i][lx] = in[((size_t)b * TLEN + t0 + i) * DD + d0 + lx];
    __syncthreads();
    for (int i = ly; i < 32; i += 8)
        out[((size_t)b * DD + d0 + i) * TLEN + t0 + lx] = tile[lx][i];
}

// ---------------------------------------- image rfft(ortho) + filter + g acc
__global__ __launch_bounds__(128) void img_dft(const float* __restrict__ image,
                                               const float* __restrict__ ifb,
                                               const float* __restrict__ sel,
                                               float* __restrict__ zi,
                                               float* __restrict__ gbuf) {
    __shared__ float ctab[NPATCH], stab[NPATCH];
    int b = blockIdx.x / 11;
    int fg = blockIdx.x % 11;
    int d = threadIdx.x;
    for (int m = d; m < NPATCH; m += 128) {
        ctab[m] = cospif(m * (2.0f / 196.0f));
        stab[m] = sinpif(m * (2.0f / 196.0f));
    }
    __syncthreads();
    float accr[9], acci[9];
    int mc[9];
#pragma unroll
    for (int j = 0; j < 9; ++j) { accr[j] = 0.0f; acci[j] = 0.0f; mc[j] = 0; }
    const float* img = image + (size_t)b * NPATCH * DD + d;
    for (int n = 0; n < NPATCH; ++n) {
        float v = img[(size_t)n * DD];
#pragma unroll
        for (int j = 0; j < 9; ++j) {
            float c = ctab[mc[j]], s = stab[mc[j]];
            accr[j] += v * c;
            acci[j] -= v * s;
            mc[j] += fg * 9 + j;
            if (mc[j] >= NPATCH) mc[j] -= NPATCH;
        }
    }
    float gg = 0.0f;
#pragma unroll
    for (int j = 0; j < 9; ++j) {
        int f = fg * 9 + j;
        float Xr = accr[j] * (1.0f / 14.0f);
        float Xi = acci[j] * (1.0f / 14.0f);
        float sr = (Xr * Xr - Xi * Xi) * (1.0f / 99.0f);
        float si = 2.0f * Xr * Xi * (1.0f / 99.0f);
        float2 f0 = ((const float2*)ifb)[f * DD + d];
        float2 f1 = ((const float2*)ifb)[NFREQ * DD + f * DD + d];
        float fbr = -(f0.x + f1.x), fbi = -(f0.y + f1.y);
        float zr = sr * fbr - si * fbi;
        float zm = sr * fbi + si * fbr;
        float2 o; o.x = zr; o.y = zm;
        ((float2*)zi)[((size_t)b * NFREQ + f) * DD + d] = o;
        float2 sl = ((const float2*)sel)[f * DD + d];
        gg += zr * sl.x - zm * sl.y;
    }
    atomicAdd(gbuf + b * DD + d, gg * (1.0f / 99.0f));
}

// ----------------------------------------------------- gate = g @ w^T + b
__global__ __launch_bounds__(128) void gate_kernel(const float* __restrict__ gbuf,
                                                   const float* __restrict__ w,
                                                   const float* __restrict__ bias,
                                                   float* __restrict__ gate) {
    __shared__ float gs[DD];
    int b = blockIdx.x, e = threadIdx.x;
    gs[e] = gbuf[b * DD + e];
    __syncthreads();
    float acc = bias[e];
    const float* wr = w + (size_t)e * DD;
    for (int d = 0; d < DD; ++d) acc += gs[d] * wr[d];
    gate[b * DD + e] = acc;
}

// ------------------------- per-(b,d): STFT -> filter*gate -> ISTFT, in-place
// Register-resident 256-pt complex FFT per wave (point i = reg*64+lane).
// Fused middle phase (thread-local slot pair), 4 barriers total.
// 512 threads/block: same 4 blocks/CU (LDS-capped) -> 32 waves/CU (2x latency
// hiding vs 256-thr). Middle-phase trig from LDS table (identical bits).
#define SWZ(e) ((e) ^ (((e) >> 4) & 15))

#define CMULW(dr, di, c, s, xr, xi) { float _t = (dr)*(c) - (di)*(s); xi = (dr)*(s) + (di)*(c); xr = _t; }
#define BF(xr, xi, h) { \
    float pr_ = __shfl_xor(xr, h), pi_ = __shfl_xor(xi, h); \
    float dr2_ = fmaf(sg##h, xr, pr_), di2_ = fmaf(sg##h, xi, pi_); \
    CMULW(dr2_, di2_, tc##h, ts##h, xr, xi) }
#define SSTG(h) BF(a0r, a0i, h) BF(a1r, a1i, h) BF(a2r, a2i, h) BF(a3r, a3i, h)
#define BF1(xr, xi) { \
    float pr_ = __shfl_xor(xr, 1), pi_ = __shfl_xor(xi, 1); \
    xr = fmaf(sg1, xr, pr_); xi = fmaf(sg1, xi, pi_); }
#define DIF256() { \
    float dr_, di_; \
    dr_ = a0r - a2r; di_ = a0i - a2i; a0r += a2r; a0i += a2i; CMULW(dr_, di_, wa_c, wa_s, a2r, a2i) \
    dr_ = a1r - a3r; di_ = a1i - a3i; a1r += a3r; a1i += a3i; CMULW(dr_, di_, wb_c, wb_s, a3r, a3i) \
    dr_ = a0r - a1r; di_ = a0i - a1i; a0r += a1r; a0i += a1i; CMULW(dr_, di_, wc_c, wc_s, a1r, a1i) \
    dr_ = a2r - a3r; di_ = a2i - a3i; a2r += a3r; a2i += a3i; CMULW(dr_, di_, wc_c, wc_s, a3r, a3i) \
    SSTG(32) SSTG(16) SSTG(8) SSTG(4) SSTG(2) \
    BF1(a0r, a0i) BF1(a1r, a1i) BF1(a2r, a2i) BF1(a3r, a3i) }

__global__ __launch_bounds__(512) void stft_filter_istft(
    float* xT, const float* __restrict__ fbt2, const float* __restrict__ gate) {
    __shared__ float2 spec[NFR * 256];   // 34816 B
    __shared__ float win[NSEG];          // 2048 B
    __shared__ float rnorm[256];         // 1024 B
    __shared__ float mct[129], mst[129]; // 1032 B middle-phase trig
    int tid = threadIdx.x;
    int lane = tid & 63, wave = tid >> 6;  // wave 0..7
    int bd = blockIdx.x;              // b*128 + d
    int d = bd & 127;
    float gat = gate[bd];
    const float scl = gat * (1.0f / 4369.0f);
    float* xrow = xT + (size_t)bd * TLEN;
    const float2* fbrow = (const float2*)(fbt2 + (size_t)d * NFR * NBINS * 2);

    for (int j = tid; j < NSEG; j += 512)
        win[j] = 0.5f - 0.5f * cospif(j * (1.0f / 256.0f));   // sin^2(pi j/512)
    if (tid < 256) {
        float s2 = 0.5f - 0.5f * cospif(tid * (1.0f / 256.0f));
        float c2 = 1.0f - s2;
        rnorm[tid] = 1.0f / (s2 * s2 + c2 * c2);
    }
    for (int j = tid; j < 129; j += 512) {
        mct[j] = cospif(j * (1.0f / 256.0f));
        mst[j] = sinpif(j * (1.0f / 256.0f));
    }

    // ---- hoisted twiddles (W = e^{-2pi i k/256}; ts holds -sin)
    float wa_c = cospif(lane * (1.0f / 128.0f)), wa_s = -sinpif(lane * (1.0f / 128.0f));
    float wb_c = cospif((64 + lane) * (1.0f / 128.0f)), wb_s = -sinpif((64 + lane) * (1.0f / 128.0f));
    float wc_c = cospif(lane * (1.0f / 64.0f)),  wc_s = -sinpif(lane * (1.0f / 64.0f));
#define MKT(h) \
    float tc##h, ts##h, sg##h; \
    { int set_ = lane & h; float ang_ = (float)(lane & (h - 1)) * (1.0f / h); \
      tc##h = set_ ? cospif(ang_) : 1.0f; \
      ts##h = set_ ? -sinpif(ang_) : 0.0f; \
      sg##h = set_ ? -1.0f : 1.0f; }
    MKT(32) MKT(16) MKT(8) MKT(4) MKT(2)
    float sg1 = (lane & 1) ? -1.0f : 1.0f;
#undef MKT

    // scatter (bitrev) and gather (natural) element addresses, swizzled
    int eS[4], eL[4];
#pragma unroll
    for (int j = 0; j < 4; ++j) {
        int i = j * 64 + lane;
        eS[j] = SWZ((int)(__brev((unsigned)i) >> 24));
        eL[j] = SWZ(i);
    }
    __syncthreads();

    // ---- forward: load+window -> DIF -> scatter spectrum (natural order)
    for (int t = wave; t < NFR; t += 8) {
        float a0r, a0i, a1r, a1i, a2r, a2i, a3r, a3i;
#define LOADJ(j, xr, xi) { \
        int i_ = (j) * 64 + lane; \
        int src_ = t * HOP + 2 * i_ - HOP; \
        float er_ = 0.0f, oi_ = 0.0f; \
        if (src_ >= 0 && src_ < TLEN) { \
            float2 v_ = *(const float2*)(xrow + src_); er_ = v_.x; oi_ = v_.y; } \
        float2 w_ = *(const float2*)(win + 2 * i_); \
        xr = er_ * w_.x; xi = oi_ * w_.y; }
        LOADJ(0, a0r, a0i) LOADJ(1, a1r, a1i) LOADJ(2, a2r, a2i) LOADJ(3, a3r, a3i)
#undef LOADJ
        DIF256()
        float2* sp = spec + t * 256;
        sp[eS[0]] = make_float2(a0r, a0i);
        sp[eS[1]] = make_float2(a1r, a1i);
        sp[eS[2]] = make_float2(a2r, a2i);
        sp[eS[3]] = make_float2(a3r, a3i);
    }
    __syncthreads();

    // ---- middle (fused): rfft unpack -> square -> filter*gate -> conj repack
    for (int j = tid; j < NFR * 129; j += 512) {
        int t = j / 129, m = j - t * 129;
        float2* sp = spec + t * 256;
        const float2* fbr = fbrow + t * NBINS;
        if (m == 0) {
            float2 v = sp[0];
            float re = v.x, im = v.y;
            float z0 = (re + im) * (1.0f / 256.0f);
            float zN = (re - im) * (1.0f / 256.0f);
            float2 fb0 = fbr[0], fbN = fbr[256];
            float y1r = z0 * z0 * fb0.x * scl;
            float y2r = zN * zN * fbN.x * scl;
            float Er = 0.5f * (y1r + y2r);
            float Dr = 0.5f * (y1r - y2r);
            sp[0] = make_float2(Er, -Dr);
        } else if (m == 128) {
            float2 v = sp[SWZ(128)];
            float Zr = v.x, Zi = v.y;
            float zr = Zr * (1.0f / 256.0f), zi2 = -Zi * (1.0f / 256.0f);
            float sr = zr * zr - zi2 * zi2, si = 2.0f * zr * zi2;
            float2 fb = fbr[128];
            sp[SWZ(128)] = make_float2((sr * fb.x - si * fb.y) * scl,
                                       (sr * fb.y + si * fb.x) * scl);
        } else {
            float2 vm = sp[SWZ(m)];
            float2 vc = sp[SWZ(256 - m)];
            float Amr = vm.x, Ami = vm.y;
            float Acr = vc.x, Aci = vc.y;
            float c = mct[m];
            float sn = mst[m];
            float y1r, y1i, y2r, y2i;
            {
                float Br = Acr, Bi = -Aci;
                float xer = 0.5f * (Amr + Br), xei = 0.5f * (Ami + Bi);
                float xo_r = 0.5f * (Ami - Bi), xo_i = -0.5f * (Amr - Br);
                float Xr = xer + c * xo_r + sn * xo_i;
                float Xi = xei + c * xo_i - sn * xo_r;
                float zr = Xr * (1.0f / 256.0f), zi2 = Xi * (1.0f / 256.0f);
                float sr = zr * zr - zi2 * zi2, si = 2.0f * zr * zi2;
                float2 fb = fbr[m];
                y1r = (sr * fb.x - si * fb.y) * scl;
                y1i = (sr * fb.y + si * fb.x) * scl;
            }
            {
                float Br = Amr, Bi = -Ami;
                float xer = 0.5f * (Acr + Br), xei = 0.5f * (Aci + Bi);
                float xo_r = 0.5f * (Aci - Bi), xo_i = -0.5f * (Acr - Br);
                float Xr = xer - c * xo_r + sn * xo_i;
                float Xi = xei - c * xo_i - sn * xo_r;
                float zr = Xr * (1.0f / 256.0f), zi2 = Xi * (1.0f / 256.0f);
                float sr = zr * zr - zi2 * zi2, si = 2.0f * zr * zi2;
                float2 fb = fbr[256 - m];
                y2r = (sr * fb.x - si * fb.y) * scl;
                y2i = (sr * fb.y + si * fb.x) * scl;
            }
            float Er = 0.5f * (y1r + y2r);
            float Ei = 0.5f * (y1i - y2i);
            float Dr = 0.5f * (y1r - y2r);
            float Di = 0.5f * (y1i + y2i);
            float Or = Dr * c - Di * sn;
            float Oi = Dr * sn + Di * c;
            sp[SWZ(m)] = make_float2(Er - Oi, -(Ei + Or));
            sp[SWZ(256 - m)] = make_float2(Er + Oi, Ei - Or);
        }
    }
    __syncthreads();

    // ---- inverse: gather conj(B) natural -> same DIF -> scatter time domain
    for (int t = wave; t < NFR; t += 8) {
        float2* sp = spec + t * 256;
        float2 v0 = sp[eL[0]], v1 = sp[eL[1]], v2 = sp[eL[2]], v3 = sp[eL[3]];
        float a0r = v0.x, a0i = v0.y, a1r = v1.x, a1i = v1.y;
        float a2r = v2.x, a2i = v2.y, a3r = v3.x, a3i = v3.y;
        DIF256()
        sp[eS[0]] = make_float2(a0r, a0i);
        sp[eS[1]] = make_float2(a1r, a1i);
        sp[eS[2]] = make_float2(a2r, a2i);
        sp[eS[3]] = make_float2(a3r, a3i);
    }
    __syncthreads();

    // ---- OLA (even sample = re, odd = -im)
    const float* specf = (const float*)spec;
    for (int j = tid; j < TLEN; j += 512) {
        int p = j + HOP;
        int t1 = p >> 8, t0 = t1 - 1;
        int i1 = p & 255, i0 = i1 + 256;
        int comp = j & 1;
        float v1 = specf[(t1 * 256 + SWZ(i1 >> 1)) * 2 + comp];
        float v0 = specf[(t0 * 256 + SWZ(i0 >> 1)) * 2 + comp];
        if (comp) { v1 = -v1; v0 = -v0; }
        float s = v0 * win[i0] + v1 * win[i1];
        xrow[j] = s * rnorm[i1];
    }
}

// ------------------------------------------- image irfft(ortho) + add image
__global__ __launch_bounds__(128) void img_irfft(const float* __restrict__ zi,
                                                 const float* __restrict__ image,
                                                 float* __restrict__ x0img) {
    __shared__ float ctab[NPATCH], stab[NPATCH];
    int b = blockIdx.x / 14;
    int ng = blockIdx.x % 14;
    int d = threadIdx.x;
    for (int m = d; m < NPATCH; m += 128) {
        ctab[m] = cospif(m * (2.0f / 196.0f));
        stab[m] = sinpif(m * (2.0f / 196.0f));
    }
    __syncthreads();
    const float2* zrow = (const float2*)zi + (size_t)b * NFREQ * DD + d;
    float acc[14];
    int mc[14];
    float2 z0 = zrow[0];
#pragma unroll
    for (int j = 0; j < 14; ++j) { acc[j] = z0.x; mc[j] = 0; }
    for (int f = 1; f <= 97; ++f) {
        float2 z = zrow[(size_t)f * DD];
#pragma unroll
        for (int j = 0; j < 14; ++j) {
            int n = ng * 14 + j;
            mc[j] += n;
            if (mc[j] >= NPATCH) mc[j] -= NPATCH;
            acc[j] += 2.0f * (z.x * ctab[mc[j]] - z.y * stab[mc[j]]);
        }
    }
    float2 z98 = zrow[98 * (size_t)DD];
#pragma unroll
    for (int j = 0; j < 14; ++j) {
        int n = ng * 14 + j;
        float a = acc[j] + ((n & 1) ? -z98.x : z98.x);
        float y = a * (1.0f / 14.0f);
        size_t idx = ((size_t)b * NPATCH + n) * DD + d;
        x0img[idx] = y + image[idx];
    }
}

// ------------------------------- addnorm: LN1 -> MLP via split-bf16 MFMA -> LN2
// ROUND-4 VERBATIM (known-good): 64 rows/block, 4 waves; wave w owns rows
// [w*16, w*16+16). Slab-restructure attempts (r5/r6) failed verification.
#define XLNS 132

__device__ __forceinline__ void mlp_gemm(const float* __restrict__ ax,
                                         const unsigned short* __restrict__ wf,
                                         int lane, f32x4 acc[8]) {
#pragma unroll
    for (int n = 0; n < 8; ++n) acc[n] = (f32x4){0.f, 0.f, 0.f, 0.f};
    const bf16x8* bh0 = (const bf16x8*)wf;
    const bf16x8* bl0 = (const bf16x8*)(wf + 16384);
#pragma unroll 1
    for (int kt = 0; kt < 4; ++kt) {
        float4 va = *(const float4*)(ax + kt * 32);
        float4 vb = *(const float4*)(ax + kt * 32 + 4);
        bf16x8 ahi, alo;
        split8(va, vb, ahi, alo);
        const bf16x8* bh = bh0 + kt * 512 + lane;
        const bf16x8* bl = bl0 + kt * 512 + lane;
#pragma unroll
        for (int n = 0; n < 8; ++n) {
            bf16x8 wh = bh[n * 64];
            bf16x8 wl = bl[n * 64];
            acc[n] = __builtin_amdgcn_mfma_f32_16x16x32_bf16(ahi, wh, acc[n], 0, 0, 0);
            acc[n] = __builtin_amdgcn_mfma_f32_16x16x32_bf16(alo, wh, acc[n], 0, 0, 0);
            acc[n] = __builtin_amdgcn_mfma_f32_16x16x32_bf16(ahi, wl, acc[n], 0, 0, 0);
        }
    }
}

template <int FUSED>
__global__ __launch_bounds__(256) void addnorm_kernel(
    const float* __restrict__ srcA, const float* __restrict__ srcB,
    const float* __restrict__ ln1g, const float* __restrict__ ln1b,
    const unsigned short* __restrict__ w1f, const float* __restrict__ b1,
    const unsigned short* __restrict__ w2f, const float* __restrict__ b2,
    const float* __restrict__ ln2g, const float* __restrict__ ln2b,
    float* __restrict__ out) {
    __shared__ __align__(16) float xln[64 * XLNS];   // reused: x -> g
    int tid = threadIdx.x;
    int b = 0, t0 = 0;
    size_t R0 = 0;
    // ---- Phase A: build x0
    if (FUSED) {
        b = blockIdx.x >> 6;
        t0 = (blockIdx.x & 63) * 64;
        for (int i = tid; i < 64 * 128; i += 256) {
            int dd = i >> 6, r = i & 63;
            xln[r * XLNS + dd] = srcA[((size_t)b * DD + dd) * TLEN + t0 + r];
        }
        __syncthreads();
        for (int i = tid; i < 64 * 128; i += 256) {
            int r = i >> 7, dd = i & 127;
            xln[r * XLNS + dd] += srcB[((size_t)b * TLEN + t0 + r) * DD + dd];
        }
    } else {
        R0 = (size_t)blockIdx.x * 64;
        for (int i = tid; i < 64 * 128; i += 256) {
            int r = i >> 7, dd = i & 127;
            xln[r * XLNS + dd] = srcA[(R0 + r) * DD + dd];
        }
    }
    __syncthreads();
    // ---- LN1 (wave per row)
    int wave = tid >> 6, lane = tid & 63;
    for (int r = wave; r < 64; r += 4) {
        float v0 = xln[r * XLNS + lane];
        float v1 = xln[r * XLNS + 64 + lane];
        float s = v0 + v1, ss = v0 * v0 + v1 * v1;
        for (int off = 32; off > 0; off >>= 1) {
            s += __shfl_xor(s, off);
            ss += __shfl_xor(ss, off);
        }
        float mean = s * (1.0f / 128.0f);
        float var = ss * (1.0f / 128.0f) - mean * mean;
        float rstd = rsqrtf(var + 1e-5f);
        xln[r * XLNS + lane] = (v0 - mean) * rstd * ln1g[lane] + ln1b[lane];
        xln[r * XLNS + 64 + lane] = (v1 - mean) * rstd * ln1g[64 + lane] + ln1b[64 + lane];
    }
    __syncthreads();
    // ---- fragment coordinates
    int q = lane >> 4, c = lane & 15;
    int rbase = wave * 16 + q * 4;                          // C-frag rows (4)
    const float* ax = &xln[(wave * 16 + c) * XLNS + q * 8]; // A-frag base
    // ---- GEMM1: acc = x @ w1
    f32x4 acc[8];
    mlp_gemm(ax, w1f, lane, acc);
    // ---- residual (post-LN1 x) at this thread's C positions
    float res[8][4];
#pragma unroll
    for (int n = 0; n < 8; ++n)
#pragma unroll
        for (int r = 0; r < 4; ++r)
            res[n][r] = xln[(rbase + r) * XLNS + n * 16 + c];
    // ---- bias + gelu
#pragma unroll
    for (int n = 0; n < 8; ++n) {
        float bb = b1[n * 16 + c];
#pragma unroll
        for (int r = 0; r < 4; ++r)
            acc[n][r] = gelu_exact(acc[n][r] + bb);
    }
    __syncthreads();   // all reads of xln(=x) done
#pragma unroll
    for (int n = 0; n < 8; ++n)
#pragma unroll
        for (int r = 0; r < 4; ++r)
            xln[(rbase + r) * XLNS + n * 16 + c] = acc[n][r];   // xln := g
    __syncthreads();
    // ---- GEMM2: acc = g @ w2; h = acc + b2 + res
    mlp_gemm(ax, w2f, lane, acc);
#pragma unroll
    for (int n = 0; n < 8; ++n) {
        float bb = b2[n * 16 + c];
#pragma unroll
        for (int r = 0; r < 4; ++r)
            acc[n][r] += bb + res[n][r];
    }
    // ---- LN2 stats: rows live in 16-lane groups (cols spread over c and n)
    float s4[4] = {0.f, 0.f, 0.f, 0.f}, ss4[4] = {0.f, 0.f, 0.f, 0.f};
#pragma unroll
    for (int n = 0; n < 8; ++n)
#pragma unroll
        for (int r = 0; r < 4; ++r) {
            float h = acc[n][r];
            s4[r] += h; ss4[r] += h * h;
        }
#pragma unroll
    for (int off = 8; off > 0; off >>= 1) {
#pragma unroll
        for (int r = 0; r < 4; ++r) {
            s4[r] += __shfl_xor(s4[r], off);
            ss4[r] += __shfl_xor(ss4[r], off);
        }
    }
    float g2v[8], b2v[8];
#pragma unroll
    for (int n = 0; n < 8; ++n) {
        g2v[n] = ln2g[n * 16 + c];
        b2v[n] = ln2b[n * 16 + c];
    }
#pragma unroll
    for (int r = 0; r < 4; ++r) {
        float mean = s4[r] * (1.0f / 128.0f);
        float var = ss4[r] * (1.0f / 128.0f) - mean * mean;
        float rstd = rsqrtf(var + 1e-5f);
        size_t orow = FUSED ? ((size_t)b * TLEN + t0 + rbase + r) * DD
                            : (R0 + rbase + r) * DD;
#pragma unroll
        for (int n = 0; n < 8; ++n)
            out[orow + n * 16 + c] = (acc[n][r] - mean) * rstd * g2v[n] + b2v[n];
    }
}

extern "C" void kernel_launch(void* const* d_in, const int* in_sizes, int n_in,
                              void* d_out, int out_size, void* d_ws, size_t ws_size,
                              hipStream_t stream) {
    (void)in_sizes; (void)n_in; (void)out_size; (void)ws_size;
    const float* ecg   = (const float*)d_in[0];
    const float* image = (const float*)d_in[1];
    const float* tfb   = (const float*)d_in[2];
    const float* ifb   = (const float*)d_in[3];
    const float* sel   = (const float*)d_in[4];
    const float* i2t_w = (const float*)d_in[5];
    const float* i2t_b = (const float*)d_in[6];
    const float* t_ln1_g = (const float*)d_in[7];
    const float* t_ln1_b = (const float*)d_in[8];
    const float* t_w1 = (const float*)d_in[9];
    const float* t_b1 = (const float*)d_in[10];
    const float* t_w2 = (const float*)d_in[11];
    const float* t_b2 = (const float*)d_in[12];
    const float* t_ln2_g = (const float*)d_in[13];
    const float* t_ln2_b = (const float*)d_in[14];
    const float* i_ln1_g = (const float*)d_in[15];
    const float* i_ln1_b = (const float*)d_in[16];
    const float* i_w1 = (const float*)d_in[17];
    const float* i_b1 = (const float*)d_in[18];
    const float* i_w2 = (const float*)d_in[19];
    const float* i_b2 = (const float*)d_in[20];
    const float* i_ln2_g = (const float*)d_in[21];
    const float* i_ln2_b = (const float*)d_in[22];
    float* out = (float*)d_out;
    float* ws = (float*)d_ws;
    unsigned short* wfb = (unsigned short*)(ws + WF_OFF);

    prep_wfrag<<<32, 256, 0, stream>>>(t_w1, t_w2, i_w1, i_w2, wfb);
    prep_fb<<<(STOT * DD + 255) / 256, 256, 0, stream>>>(tfb, ws + FBT2_OFF, ws + GBUF_OFF);
    {
        dim3 tb(32, 8);
        dim3 tg(TLEN / 32, DD / 32, BB);
        transpose_btd<<<tg, tb, 0, stream>>>(ecg, ws + XT_OFF);
    }
    img_dft<<<BB * 11, 128, 0, stream>>>(image, ifb, sel, ws + ZI_OFF, ws + GBUF_OFF);
    gate_kernel<<<BB, 128, 0, stream>>>(ws + GBUF_OFF, i2t_w, i2t_b, ws + GATE_OFF);
    stft_filter_istft<<<BB * DD, 512, 0, stream>>>(ws + XT_OFF, ws + FBT2_OFF, ws + GATE_OFF);
    addnorm_kernel<1><<<BB * (TLEN / 64), 256, 0, stream>>>(
        ws + XT_OFF, ecg, t_ln1_g, t_ln1_b, wfb + 0, t_b1, wfb + 32768, t_b2,
        t_ln2_g, t_ln2_b, out);
    img_irfft<<<BB * 14, 128, 0, stream>>>(ws + ZI_OFF, image, ws + X0I_OFF);
    addnorm_kernel<0><<<(BB * NPATCH) / 64, 256, 0, stream>>>(
        ws + X0I_OFF, nullptr, i_ln1_g, i_ln1_b, wfb + 65536, i_b1, wfb + 98304, i_b2,
        i_ln2_g, i_ln2_b, out + (size_t)BB * TLEN * DD);
}

// Round 8
// 591.203 us; speedup vs baseline: 1.0282x; 1.0282x over previous
//
#include <hip/hip_runtime.h>
#include <math.h>

#define BB 32
#define DD 128
#define TLEN 4096
#define NSEG 512
#define HOP 256
#define NFR 17
#define NBINS 257
#define STOT 4369
#define NPATCH 196
#define NFREQ 99
#define OLAL 4608

// workspace layout (float offsets)
#define FBT2_OFF 0
#define FBT2_SZ  (DD * NFR * NBINS * 2)       // 1,118,464
#define GBUF_OFF (FBT2_OFF + FBT2_SZ)
#define GATE_OFF (GBUF_OFF + BB * DD)
#define ZI_OFF   (GATE_OFF + BB * DD)
#define ZI_SZ    (BB * NFREQ * DD * 2)        // 811,008
#define X0I_OFF  (ZI_OFF + ZI_SZ)
#define X0I_SZ   (BB * NPATCH * DD)           // 802,816
#define XT_OFF   (X0I_OFF + X0I_SZ)
#define WF_OFF   (XT_OFF + BB * DD * TLEN)    // bf16 hi/lo weight fragments (4 mats x 32768 ushort)

typedef __attribute__((ext_vector_type(8))) short bf16x8;
typedef __attribute__((ext_vector_type(4))) float f32x4;
typedef __attribute__((ext_vector_type(8))) unsigned short u16x8;

__device__ __forceinline__ float gelu_exact(float x) {
    return 0.5f * x * (1.0f + erff(x * 0.70710678118654752f));
}

__device__ __forceinline__ short bf16_rne(float v) {
    unsigned b = __float_as_uint(v);
    return (short)((b + 0x7fffu + ((b >> 16) & 1u)) >> 16);
}

// split fp32 -> bf16 hi + bf16 lo (v ~= hi + lo, error ~2^-17 relative)
__device__ __forceinline__ void split8(float4 a, float4 b, bf16x8& hi, bf16x8& lo) {
    float v[8] = {a.x, a.y, a.z, a.w, b.x, b.y, b.z, b.w};
#pragma unroll
    for (int e = 0; e < 8; ++e) {
        unsigned bv = __float_as_uint(v[e]);
        unsigned hb = (bv + 0x7fffu + ((bv >> 16) & 1u)) & 0xffff0000u;
        float hf = __uint_as_float(hb);
        hi[e] = (short)(hb >> 16);
        lo[e] = bf16_rne(v[e] - hf);
    }
}

// ---------------------------------------------------- pack w1/w2 MFMA frags
__global__ __launch_bounds__(256) void prep_wfrag(
    const float* __restrict__ w0, const float* __restrict__ w1,
    const float* __restrict__ w2, const float* __restrict__ w3,
    unsigned short* __restrict__ outw) {
    int id = blockIdx.x * 256 + threadIdx.x;
    if (id >= 4 * 2048) return;
    int m = id >> 11;
    int r = id & 2047;                 // (kt, n, lane)
    int kt = r >> 9;
    int n = (r >> 6) & 7;
    int lane = r & 63;
    int k0 = kt * 32 + (lane >> 4) * 8;
    int col = n * 16 + (lane & 15);
    const float* w = (m == 0) ? w0 : (m == 1) ? w1 : (m == 2) ? w2 : w3;
    u16x8 hi, lo;
#pragma unroll
    for (int e = 0; e < 8; ++e) {
        float v = w[(size_t)(k0 + e) * DD + col];
        unsigned bv = __float_as_uint(v);
        unsigned hb = (bv + 0x7fffu + ((bv >> 16) & 1u)) & 0xffff0000u;
        float hf = __uint_as_float(hb);
        float lres = v - hf;
        unsigned bl = __float_as_uint(lres);
        hi[e] = (unsigned short)(hb >> 16);
        lo[e] = (unsigned short)((bl + 0x7fffu + ((bl >> 16) & 1u)) >> 16);
    }
    u16x8* base = (u16x8*)(outw + (size_t)m * 32768);
    base[r] = hi;
    base[2048 + r] = lo;
}

// --------------------------- tfb -> fbt2 (D,17,257,2); also zeroes gbuf
__global__ __launch_bounds__(256) void prep_fb(const float* __restrict__ tfb,
                                               float* __restrict__ fbt2,
                                               float* __restrict__ gbuf) {
    int idx = blockIdx.x * 256 + threadIdx.x;
    if (idx < BB * DD) gbuf[idx] = 0.0f;
    if (idx >= STOT * DD) return;
    int d = idx & 127;
    int s = idx >> 7;
    float2 a = ((const float2*)tfb)[s * DD + d];
    float2 b = ((const float2*)tfb)[STOT * DD + s * DD + d];
    int f = s / NFR, t = s % NFR;
    float2 r;
    r.x = -(a.x + b.x);
    r.y = -(a.y + b.y);
    ((float2*)fbt2)[((size_t)d * NFR + t) * NBINS + f] = r;
}

// ------------------------------------------------- ecg (B,T,D) -> (B,D,T)
__global__ __launch_bounds__(256) void transpose_btd(const float* __restrict__ in,
                                                     float* __restrict__ out) {
    __shared__ float tile[32][33];
    int b = blockIdx.z;
    int t0 = blockIdx.x * 32;
    int d0 = blockIdx.y * 32;
    int lx = threadIdx.x;
    int ly = threadIdx.y;
    for (int i = ly; i < 32; i += 8)
        tile[i][lx] = in[((size_t)b * TLEN + t0 + i) * DD + d0 + lx];
    __syncthreads();
    for (int i = ly; i < 32; i += 8)
        out[((size_t)b * DD + d0 + i) * TLEN + t0 + lx] = tile[lx][i];
}

// ---------------------------------------- image rfft(ortho) + filter + g acc
__global__ __launch_bounds__(128) void img_dft(const float* __restrict__ image,
                                               const float* __restrict__ ifb,
                                               const float* __restrict__ sel,
                                               float* __restrict__ zi,
                                               float* __restrict__ gbuf) {
    __shared__ float ctab[NPATCH], stab[NPATCH];
    int b = blockIdx.x / 11;
    int fg = blockIdx.x % 11;
    int d = threadIdx.x;
    for (int m = d; m < NPATCH; m += 128) {
        ctab[m] = cospif(m * (2.0f / 196.0f));
        stab[m] = sinpif(m * (2.0f / 196.0f));
    }
    __syncthreads();
    float accr[9], acci[9];
    int mc[9];
#pragma unroll
    for (int j = 0; j < 9; ++j) { accr[j] = 0.0f; acci[j] = 0.0f; mc[j] = 0; }
    const float* img = image + (size_t)b * NPATCH * DD + d;
    for (int n = 0; n < NPATCH; ++n) {
        float v = img[(size_t)n * DD];
#pragma unroll
        for (int j = 0; j < 9; ++j) {
            float c = ctab[mc[j]], s = stab[mc[j]];
            accr[j] += v * c;
            acci[j] -= v * s;
            mc[j] += fg * 9 + j;
            if (mc[j] >= NPATCH) mc[j] -= NPATCH;
        }
    }
    float gg = 0.0f;
#pragma unroll
    for (int j = 0; j < 9; ++j) {
        int f = fg * 9 + j;
        float Xr = accr[j] * (1.0f / 14.0f);
        float Xi = acci[j] * (1.0f / 14.0f);
        float sr = (Xr * Xr - Xi * Xi) * (1.0f / 99.0f);
        float si = 2.0f * Xr * Xi * (1.0f / 99.0f);
        float2 f0 = ((const float2*)ifb)[f * DD + d];
        float2 f1 = ((const float2*)ifb)[NFREQ * DD + f * DD + d];
        float fbr = -(f0.x + f1.x), fbi = -(f0.y + f1.y);
        float zr = sr * fbr - si * fbi;
        float zm = sr * fbi + si * fbr;
        float2 o; o.x = zr; o.y = zm;
        ((float2*)zi)[((size_t)b * NFREQ + f) * DD + d] = o;
        float2 sl = ((const float2*)sel)[f * DD + d];
        gg += zr * sl.x - zm * sl.y;
    }
    atomicAdd(gbuf + b * DD + d, gg * (1.0f / 99.0f));
}

// ----------------------------------------------------- gate = g @ w^T + b
__global__ __launch_bounds__(128) void gate_kernel(const float* __restrict__ gbuf,
                                                   const float* __restrict__ w,
                                                   const float* __restrict__ bias,
                                                   float* __restrict__ gate) {
    __shared__ float gs[DD];
    int b = blockIdx.x, e = threadIdx.x;
    gs[e] = gbuf[b * DD + e];
    __syncthreads();
    float acc = bias[e];
    const float* wr = w + (size_t)e * DD;
    for (int d = 0; d < DD; ++d) acc += gs[d] * wr[d];
    gate[b * DD + e] = acc;
}

// ------------------------- per-(b,d): STFT -> filter*gate -> ISTFT, in-place
// Register-resident 256-pt complex FFT per wave (point i = reg*64+lane).
// Fused middle phase (thread-local slot pair), 4 barriers total.
// 256 threads/block (round-4 geometry; 512-thr regressed -16us: LDS caps
// blocks/CU at 4 regardless, wider blocks only widen barrier scope).
// Middle-phase trig from LDS table (identical bits, verified r7).
#define SWZ(e) ((e) ^ (((e) >> 4) & 15))

#define CMULW(dr, di, c, s, xr, xi) { float _t = (dr)*(c) - (di)*(s); xi = (dr)*(s) + (di)*(c); xr = _t; }
#define BF(xr, xi, h) { \
    float pr_ = __shfl_xor(xr, h), pi_ = __shfl_xor(xi, h); \
    float dr2_ = fmaf(sg##h, xr, pr_), di2_ = fmaf(sg##h, xi, pi_); \
    CMULW(dr2_, di2_, tc##h, ts##h, xr, xi) }
#define SSTG(h) BF(a0r, a0i, h) BF(a1r, a1i, h) BF(a2r, a2i, h) BF(a3r, a3i, h)
#define BF1(xr, xi) { \
    float pr_ = __shfl_xor(xr, 1), pi_ = __shfl_xor(xi, 1); \
    xr = fmaf(sg1, xr, pr_); xi = fmaf(sg1, xi, pi_); }
#define DIF256() { \
    float dr_, di_; \
    dr_ = a0r - a2r; di_ = a0i - a2i; a0r += a2r; a0i += a2i; CMULW(dr_, di_, wa_c, wa_s, a2r, a2i) \
    dr_ = a1r - a3r; di_ = a1i - a3i; a1r += a3r; a1i += a3i; CMULW(dr_, di_, wb_c, wb_s, a3r, a3i) \
    dr_ = a0r - a1r; di_ = a0i - a1i; a0r += a1r; a0i += a1i; CMULW(dr_, di_, wc_c, wc_s, a1r, a1i) \
    dr_ = a2r - a3r; di_ = a2i - a3i; a2r += a3r; a2i += a3i; CMULW(dr_, di_, wc_c, wc_s, a3r, a3i) \
    SSTG(32) SSTG(16) SSTG(8) SSTG(4) SSTG(2) \
    BF1(a0r, a0i) BF1(a1r, a1i) BF1(a2r, a2i) BF1(a3r, a3i) }

__global__ __launch_bounds__(256, 4) void stft_filter_istft(
    float* xT, const float* __restrict__ fbt2, const float* __restrict__ gate) {
    __shared__ float2 spec[NFR * 256];   // 34816 B
    __shared__ float win[NSEG];          // 2048 B
    __shared__ float rnorm[256];         // 1024 B
    __shared__ float mct[129], mst[129]; // 1032 B middle-phase trig
    int tid = threadIdx.x;
    int lane = tid & 63, wave = tid >> 6;
    int bd = blockIdx.x;              // b*128 + d
    int d = bd & 127;
    float gat = gate[bd];
    const float scl = gat * (1.0f / 4369.0f);
    float* xrow = xT + (size_t)bd * TLEN;
    const float2* fbrow = (const float2*)(fbt2 + (size_t)d * NFR * NBINS * 2);

    for (int j = tid; j < NSEG; j += 256)
        win[j] = 0.5f - 0.5f * cospif(j * (1.0f / 256.0f));   // sin^2(pi j/512)
    {
        float s2 = 0.5f - 0.5f * cospif(tid * (1.0f / 256.0f));
        float c2 = 1.0f - s2;
        rnorm[tid] = 1.0f / (s2 * s2 + c2 * c2);
    }
    if (tid < 129) {
        mct[tid] = cospif(tid * (1.0f / 256.0f));
        mst[tid] = sinpif(tid * (1.0f / 256.0f));
    }

    // ---- hoisted twiddles (W = e^{-2pi i k/256}; ts holds -sin)
    float wa_c = cospif(lane * (1.0f / 128.0f)), wa_s = -sinpif(lane * (1.0f / 128.0f));
    float wb_c = cospif((64 + lane) * (1.0f / 128.0f)), wb_s = -sinpif((64 + lane) * (1.0f / 128.0f));
    float wc_c = cospif(lane * (1.0f / 64.0f)),  wc_s = -sinpif(lane * (1.0f / 64.0f));
#define MKT(h) \
    float tc##h, ts##h, sg##h; \
    { int set_ = lane & h; float ang_ = (float)(lane & (h - 1)) * (1.0f / h); \
      tc##h = set_ ? cospif(ang_) : 1.0f; \
      ts##h = set_ ? -sinpif(ang_) : 0.0f; \
      sg##h = set_ ? -1.0f : 1.0f; }
    MKT(32) MKT(16) MKT(8) MKT(4) MKT(2)
    float sg1 = (lane & 1) ? -1.0f : 1.0f;
#undef MKT

    // scatter (bitrev) and gather (natural) element addresses, swizzled
    int eS[4], eL[4];
#pragma unroll
    for (int j = 0; j < 4; ++j) {
        int i = j * 64 + lane;
        eS[j] = SWZ((int)(__brev((unsigned)i) >> 24));
        eL[j] = SWZ(i);
    }
    __syncthreads();

    // ---- forward: load+window -> DIF -> scatter spectrum (natural order)
    for (int t = wave; t < NFR; t += 4) {
        float a0r, a0i, a1r, a1i, a2r, a2i, a3r, a3i;
#define LOADJ(j, xr, xi) { \
        int i_ = (j) * 64 + lane; \
        int src_ = t * HOP + 2 * i_ - HOP; \
        float er_ = 0.0f, oi_ = 0.0f; \
        if (src_ >= 0 && src_ < TLEN) { \
            float2 v_ = *(const float2*)(xrow + src_); er_ = v_.x; oi_ = v_.y; } \
        float2 w_ = *(const float2*)(win + 2 * i_); \
        xr = er_ * w_.x; xi = oi_ * w_.y; }
        LOADJ(0, a0r, a0i) LOADJ(1, a1r, a1i) LOADJ(2, a2r, a2i) LOADJ(3, a3r, a3i)
#undef LOADJ
        DIF256()
        float2* sp = spec + t * 256;
        sp[eS[0]] = make_float2(a0r, a0i);
        sp[eS[1]] = make_float2(a1r, a1i);
        sp[eS[2]] = make_float2(a2r, a2i);
        sp[eS[3]] = make_float2(a3r, a3i);
    }
    __syncthreads();

    // ---- middle (fused): rfft unpack -> square -> filter*gate -> conj repack
    for (int j = tid; j < NFR * 129; j += 256) {
        int t = j / 129, m = j - t * 129;
        float2* sp = spec + t * 256;
        const float2* fbr = fbrow + t * NBINS;
        if (m == 0) {
            float2 v = sp[0];
            float re = v.x, im = v.y;
            float z0 = (re + im) * (1.0f / 256.0f);
            float zN = (re - im) * (1.0f / 256.0f);
            float2 fb0 = fbr[0], fbN = fbr[256];
            float y1r = z0 * z0 * fb0.x * scl;
            float y2r = zN * zN * fbN.x * scl;
            float Er = 0.5f * (y1r + y2r);
            float Dr = 0.5f * (y1r - y2r);
            sp[0] = make_float2(Er, -Dr);
        } else if (m == 128) {
            float2 v = sp[SWZ(128)];
            float Zr = v.x, Zi = v.y;
            float zr = Zr * (1.0f / 256.0f), zi2 = -Zi * (1.0f / 256.0f);
            float sr = zr * zr - zi2 * zi2, si = 2.0f * zr * zi2;
            float2 fb = fbr[128];
            sp[SWZ(128)] = make_float2((sr * fb.x - si * fb.y) * scl,
                                       (sr * fb.y + si * fb.x) * scl);
        } else {
            float2 vm = sp[SWZ(m)];
            float2 vc = sp[SWZ(256 - m)];
            float Amr = vm.x, Ami = vm.y;
            float Acr = vc.x, Aci = vc.y;
            float c = mct[m];
            float sn = mst[m];
            float y1r, y1i, y2r, y2i;
            {
                float Br = Acr, Bi = -Aci;
                float xer = 0.5f * (Amr + Br), xei = 0.5f * (Ami + Bi);
                float xo_r = 0.5f * (Ami - Bi), xo_i = -0.5f * (Amr - Br);
                float Xr = xer + c * xo_r + sn * xo_i;
                float Xi = xei + c * xo_i - sn * xo_r;
                float zr = Xr * (1.0f / 256.0f), zi2 = Xi * (1.0f / 256.0f);
                float sr = zr * zr - zi2 * zi2, si = 2.0f * zr * zi2;
                float2 fb = fbr[m];
                y1r = (sr * fb.x - si * fb.y) * scl;
                y1i = (sr * fb.y + si * fb.x) * scl;
            }
            {
                float Br = Amr, Bi = -Ami;
                float xer = 0.5f * (Acr + Br), xei = 0.5f * (Aci + Bi);
                float xo_r = 0.5f * (Aci - Bi), xo_i = -0.5f * (Acr - Br);
                float Xr = xer - c * xo_r + sn * xo_i;
                float Xi = xei - c * xo_i - sn * xo_r;
                float zr = Xr * (1.0f / 256.0f), zi2 = Xi * (1.0f / 256.0f);
                float sr = zr * zr - zi2 * zi2, si = 2.0f * zr * zi2;
                float2 fb = fbr[256 - m];
                y2r = (sr * fb.x - si * fb.y) * scl;
                y2i = (sr * fb.y + si * fb.x) * scl;
            }
            float Er = 0.5f * (y1r + y2r);
            float Ei = 0.5f * (y1i - y2i);
            float Dr = 0.5f * (y1r - y2r);
            float Di = 0.5f * (y1i + y2i);
            float Or = Dr * c - Di * sn;
            float Oi = Dr * sn + Di * c;
            sp[SWZ(m)] = make_float2(Er - Oi, -(Ei + Or));
            sp[SWZ(256 - m)] = make_float2(Er + Oi, Ei - Or);
        }
    }
    __syncthreads();

    // ---- inverse: gather conj(B) natural -> same DIF -> scatter time domain
    for (int t = wave; t < NFR; t += 4) {
        float2* sp = spec + t * 256;
        float2 v0 = sp[eL[0]], v1 = sp[eL[1]], v2 = sp[eL[2]], v3 = sp[eL[3]];
        float a0r = v0.x, a0i = v0.y, a1r = v1.x, a1i = v1.y;
        float a2r = v2.x, a2i = v2.y, a3r = v3.x, a3i = v3.y;
        DIF256()
        sp[eS[0]] = make_float2(a0r, a0i);
        sp[eS[1]] = make_float2(a1r, a1i);
        sp[eS[2]] = make_float2(a2r, a2i);
        sp[eS[3]] = make_float2(a3r, a3i);
    }
    __syncthreads();

    // ---- OLA (even sample = re, odd = -im)
    const float* specf = (const float*)spec;
    for (int j = tid; j < TLEN; j += 256) {
        int p = j + HOP;
        int t1 = p >> 8, t0 = t1 - 1;
        int i1 = p & 255, i0 = i1 + 256;
        int comp = j & 1;
        float v1 = specf[(t1 * 256 + SWZ(i1 >> 1)) * 2 + comp];
        float v0 = specf[(t0 * 256 + SWZ(i0 >> 1)) * 2 + comp];
        if (comp) { v1 = -v1; v0 = -v0; }
        float s = v0 * win[i0] + v1 * win[i1];
        xrow[j] = s * rnorm[i1];
    }
}

// ------------------------------------------- image irfft(ortho) + add image
__global__ __launch_bounds__(128) void img_irfft(const float* __restrict__ zi,
                                                 const float* __restrict__ image,
                                                 float* __restrict__ x0img) {
    __shared__ float ctab[NPATCH], stab[NPATCH];
    int b = blockIdx.x / 14;
    int ng = blockIdx.x % 14;
    int d = threadIdx.x;
    for (int m = d; m < NPATCH; m += 128) {
        ctab[m] = cospif(m * (2.0f / 196.0f));
        stab[m] = sinpif(m * (2.0f / 196.0f));
    }
    __syncthreads();
    const float2* zrow = (const float2*)zi + (size_t)b * NFREQ * DD + d;
    float acc[14];
    int mc[14];
    float2 z0 = zrow[0];
#pragma unroll
    for (int j = 0; j < 14; ++j) { acc[j] = z0.x; mc[j] = 0; }
    for (int f = 1; f <= 97; ++f) {
        float2 z = zrow[(size_t)f * DD];
#pragma unroll
        for (int j = 0; j < 14; ++j) {
            int n = ng * 14 + j;
            mc[j] += n;
            if (mc[j] >= NPATCH) mc[j] -= NPATCH;
            acc[j] += 2.0f * (z.x * ctab[mc[j]] - z.y * stab[mc[j]]);
        }
    }
    float2 z98 = zrow[98 * (size_t)DD];
#pragma unroll
    for (int j = 0; j < 14; ++j) {
        int n = ng * 14 + j;
        float a = acc[j] + ((n & 1) ? -z98.x : z98.x);
        float y = a * (1.0f / 14.0f);
        size_t idx = ((size_t)b * NPATCH + n) * DD + d;
        x0img[idx] = y + image[idx];
    }
}

// ------------------------------- addnorm: LN1 -> MLP via split-bf16 MFMA -> LN2
// ROUND-4 VERBATIM (known-good): 64 rows/block, 4 waves; wave w owns rows
// [w*16, w*16+16). Slab-restructure attempts (r5/r6) failed verification.
#define XLNS 132

__device__ __forceinline__ void mlp_gemm(const float* __restrict__ ax,
                                         const unsigned short* __restrict__ wf,
                                         int lane, f32x4 acc[8]) {
#pragma unroll
    for (int n = 0; n < 8; ++n) acc[n] = (f32x4){0.f, 0.f, 0.f, 0.f};
    const bf16x8* bh0 = (const bf16x8*)wf;
    const bf16x8* bl0 = (const bf16x8*)(wf + 16384);
#pragma unroll 1
    for (int kt = 0; kt < 4; ++kt) {
        float4 va = *(const float4*)(ax + kt * 32);
        float4 vb = *(const float4*)(ax + kt * 32 + 4);
        bf16x8 ahi, alo;
        split8(va, vb, ahi, alo);
        const bf16x8* bh = bh0 + kt * 512 + lane;
        const bf16x8* bl = bl0 + kt * 512 + lane;
#pragma unroll
        for (int n = 0; n < 8; ++n) {
            bf16x8 wh = bh[n * 64];
            bf16x8 wl = bl[n * 64];
            acc[n] = __builtin_amdgcn_mfma_f32_16x16x32_bf16(ahi, wh, acc[n], 0, 0, 0);
            acc[n] = __builtin_amdgcn_mfma_f32_16x16x32_bf16(alo, wh, acc[n], 0, 0, 0);
            acc[n] = __builtin_amdgcn_mfma_f32_16x16x32_bf16(ahi, wl, acc[n], 0, 0, 0);
        }
    }
}

template <int FUSED>
__global__ __launch_bounds__(256) void addnorm_kernel(
    const float* __restrict__ srcA, const float* __restrict__ srcB,
    const float* __restrict__ ln1g, const float* __restrict__ ln1b,
    const unsigned short* __restrict__ w1f, const float* __restrict__ b1,
    const unsigned short* __restrict__ w2f, const float* __restrict__ b2,
    const float* __restrict__ ln2g, const float* __restrict__ ln2b,
    float* __restrict__ out) {
    __shared__ __align__(16) float xln[64 * XLNS];   // reused: x -> g
    int tid = threadIdx.x;
    int b = 0, t0 = 0;
    size_t R0 = 0;
    // ---- Phase A: build x0
    if (FUSED) {
        b = blockIdx.x >> 6;
        t0 = (blockIdx.x & 63) * 64;
        for (int i = tid; i < 64 * 128; i += 256) {
            int dd = i >> 6, r = i & 63;
            xln[r * XLNS + dd] = srcA[((size_t)b * DD + dd) * TLEN + t0 + r];
        }
        __syncthreads();
        for (int i = tid; i < 64 * 128; i += 256) {
            int r = i >> 7, dd = i & 127;
            xln[r * XLNS + dd] += srcB[((size_t)b * TLEN + t0 + r) * DD + dd];
        }
    } else {
        R0 = (size_t)blockIdx.x * 64;
        for (int i = tid; i < 64 * 128; i += 256) {
            int r = i >> 7, dd = i & 127;
            xln[r * XLNS + dd] = srcA[(R0 + r) * DD + dd];
        }
    }
    __syncthreads();
    // ---- LN1 (wave per row)
    int wave = tid >> 6, lane = tid & 63;
    for (int r = wave; r < 64; r += 4) {
        float v0 = xln[r * XLNS + lane];
        float v1 = xln[r * XLNS + 64 + lane];
        float s = v0 + v1, ss = v0 * v0 + v1 * v1;
        for (int off = 32; off > 0; off >>= 1) {
            s += __shfl_xor(s, off);
            ss += __shfl_xor(ss, off);
        }
        float mean = s * (1.0f / 128.0f);
        float var = ss * (1.0f / 128.0f) - mean * mean;
        float rstd = rsqrtf(var + 1e-5f);
        xln[r * XLNS + lane] = (v0 - mean) * rstd * ln1g[lane] + ln1b[lane];
        xln[r * XLNS + 64 + lane] = (v1 - mean) * rstd * ln1g[64 + lane] + ln1b[64 + lane];
    }
    __syncthreads();
    // ---- fragment coordinates
    int q = lane >> 4, c = lane & 15;
    int rbase = wave * 16 + q * 4;                          // C-frag rows (4)
    const float* ax = &xln[(wave * 16 + c) * XLNS + q * 8]; // A-frag base
    // ---- GEMM1: acc = x @ w1
    f32x4 acc[8];
    mlp_gemm(ax, w1f, lane, acc);
    // ---- residual (post-LN1 x) at this thread's C positions
    float res[8][4];
#pragma unroll
    for (int n = 0; n < 8; ++n)
#pragma unroll
        for (int r = 0; r < 4; ++r)
            res[n][r] = xln[(rbase + r) * XLNS + n * 16 + c];
    // ---- bias + gelu
#pragma unroll
    for (int n = 0; n < 8; ++n) {
        float bb = b1[n * 16 + c];
#pragma unroll
        for (int r = 0; r < 4; ++r)
            acc[n][r] = gelu_exact(acc[n][r] + bb);
    }
    __syncthreads();   // all reads of xln(=x) done
#pragma unroll
    for (int n = 0; n < 8; ++n)
#pragma unroll
        for (int r = 0; r < 4; ++r)
            xln[(rbase + r) * XLNS + n * 16 + c] = acc[n][r];   // xln := g
    __syncthreads();
    // ---- GEMM2: acc = g @ w2; h = acc + b2 + res
    mlp_gemm(ax, w2f, lane, acc);
#pragma unroll
    for (int n = 0; n < 8; ++n) {
        float bb = b2[n * 16 + c];
#pragma unroll
        for (int r = 0; r < 4; ++r)
            acc[n][r] += bb + res[n][r];
    }
    // ---- LN2 stats: rows live in 16-lane groups (cols spread over c and n)
    float s4[4] = {0.f, 0.f, 0.f, 0.f}, ss4[4] = {0.f, 0.f, 0.f, 0.f};
#pragma unroll
    for (int n = 0; n < 8; ++n)
#pragma unroll
        for (int r = 0; r < 4; ++r) {
            float h = acc[n][r];
            s4[r] += h; ss4[r] += h * h;
        }
#pragma unroll
    for (int off = 8; off > 0; off >>= 1) {
#pragma unroll
        for (int r = 0; r < 4; ++r) {
            s4[r] += __shfl_xor(s4[r], off);
            ss4[r] += __shfl_xor(ss4[r], off);
        }
    }
    float g2v[8], b2v[8];
#pragma unroll
    for (int n = 0; n < 8; ++n) {
        g2v[n] = ln2g[n * 16 + c];
        b2v[n] = ln2b[n * 16 + c];
    }
#pragma unroll
    for (int r = 0; r < 4; ++r) {
        float mean = s4[r] * (1.0f / 128.0f);
        float var = ss4[r] * (1.0f / 128.0f) - mean * mean;
        float rstd = rsqrtf(var + 1e-5f);
        size_t orow = FUSED ? ((size_t)b * TLEN + t0 + rbase + r) * DD
                            : (R0 + rbase + r) * DD;
#pragma unroll
        for (int n = 0; n < 8; ++n)
            out[orow + n * 16 + c] = (acc[n][r] - mean) * rstd * g2v[n] + b2v[n];
    }
}

extern "C" void kernel_launch(void* const* d_in, const int* in_sizes, int n_in,
                              void* d_out, int out_size, void* d_ws, size_t ws_size,
                              hipStream_t stream) {
    (void)in_sizes; (void)n_in; (void)out_size; (void)ws_size;
    const float* ecg   = (const float*)d_in[0];
    const float* image = (const float*)d_in[1];
    const float* tfb   = (const float*)d_in[2];
    const float* ifb   = (const float*)d_in[3];
    const float* sel   = (const float*)d_in[4];
    const float* i2t_w = (const float*)d_in[5];
    const float* i2t_b = (const float*)d_in[6];
    const float* t_ln1_g = (const float*)d_in[7];
    const float* t_ln1_b = (const float*)d_in[8];
    const float* t_w1 = (const float*)d_in[9];
    const float* t_b1 = (const float*)d_in[10];
    const float* t_w2 = (const float*)d_in[11];
    const float* t_b2 = (const float*)d_in[12];
    const float* t_ln2_g = (const float*)d_in[13];
    const float* t_ln2_b = (const float*)d_in[14];
    const float* i_ln1_g = (const float*)d_in[15];
    const float* i_ln1_b = (const float*)d_in[16];
    const float* i_w1 = (const float*)d_in[17];
    const float* i_b1 = (const float*)d_in[18];
    const float* i_w2 = (const float*)d_in[19];
    const float* i_b2 = (const float*)d_in[20];
    const float* i_ln2_g = (const float*)d_in[21];
    const float* i_ln2_b = (const float*)d_in[22];
    float* out = (float*)d_out;
    float* ws = (float*)d_ws;
    unsigned short* wfb = (unsigned short*)(ws + WF_OFF);

    prep_wfrag<<<32, 256, 0, stream>>>(t_w1, t_w2, i_w1, i_w2, wfb);
    prep_fb<<<(STOT * DD + 255) / 256, 256, 0, stream>>>(tfb, ws + FBT2_OFF, ws + GBUF_OFF);
    {
        dim3 tb(32, 8);
        dim3 tg(TLEN / 32, DD / 32, BB);
        transpose_btd<<<tg, tb, 0, stream>>>(ecg, ws + XT_OFF);
    }
    img_dft<<<BB * 11, 128, 0, stream>>>(image, ifb, sel, ws + ZI_OFF, ws + GBUF_OFF);
    gate_kernel<<<BB, 128, 0, stream>>>(ws + GBUF_OFF, i2t_w, i2t_b, ws + GATE_OFF);
    stft_filter_istft<<<BB * DD, 256, 0, stream>>>(ws + XT_OFF, ws + FBT2_OFF, ws + GATE_OFF);
    addnorm_kernel<1><<<BB * (TLEN / 64), 256, 0, stream>>>(
        ws + XT_OFF, ecg, t_ln1_g, t_ln1_b, wfb + 0, t_b1, wfb + 32768, t_b2,
        t_ln2_g, t_ln2_b, out);
    img_irfft<<<BB * 14, 128, 0, stream>>>(ws + ZI_OFF, image, ws + X0I_OFF);
    addnorm_kernel<0><<<(BB * NPATCH) / 64, 256, 0, stream>>>(
        ws + X0I_OFF, nullptr, i_ln1_g, i_ln1_b, wfb + 65536, i_b1, wfb + 98304, i_b2,
        i_ln2_g, i_ln2_b, out + (size_t)BB * TLEN * DD);
}

// Round 9
// 569.951 us; speedup vs baseline: 1.0665x; 1.0373x over previous
//
#include <hip/hip_runtime.h>
#include <math.h>

#define BB 32
#define DD 128
#define TLEN 4096
#define NSEG 512
#define HOP 256
#define NFR 17
#define NBINS 257
#define STOT 4369
#define NPATCH 196
#define NFREQ 99
#define OLAL 4608

// workspace layout (float offsets)
#define FBT2_OFF 0
#define FBT2_SZ  (DD * NFR * NBINS * 2)       // 1,118,464
#define GBUF_OFF (FBT2_OFF + FBT2_SZ)
#define GATE_OFF (GBUF_OFF + BB * DD)
#define ZI_OFF   (GATE_OFF + BB * DD)
#define ZI_SZ    (BB * NFREQ * DD * 2)        // 811,008
#define X0I_OFF  (ZI_OFF + ZI_SZ)             // reused: gpart (launch1-2), x0img (launch4-5)
#define X0I_SZ   (BB * NPATCH * DD)           // 802,816
#define XT_OFF   (X0I_OFF + X0I_SZ)
#define WF_OFF   (XT_OFF + BB * DD * TLEN)    // bf16 hi/lo weight fragments (4 mats x 32768 ushort)

typedef __attribute__((ext_vector_type(8))) short bf16x8;
typedef __attribute__((ext_vector_type(4))) float f32x4;
typedef __attribute__((ext_vector_type(8))) unsigned short u16x8;

__device__ __forceinline__ float gelu_exact(float x) {
    return 0.5f * x * (1.0f + erff(x * 0.70710678118654752f));
}

__device__ __forceinline__ short bf16_rne(float v) {
    unsigned b = __float_as_uint(v);
    return (short)((b + 0x7fffu + ((b >> 16) & 1u)) >> 16);
}

// split fp32 -> bf16 hi + bf16 lo (v ~= hi + lo, error ~2^-17 relative)
__device__ __forceinline__ void split8(float4 a, float4 b, bf16x8& hi, bf16x8& lo) {
    float v[8] = {a.x, a.y, a.z, a.w, b.x, b.y, b.z, b.w};
#pragma unroll
    for (int e = 0; e < 8; ++e) {
        unsigned bv = __float_as_uint(v[e]);
        unsigned hb = (bv + 0x7fffu + ((bv >> 16) & 1u)) & 0xffff0000u;
        float hf = __uint_as_float(hb);
        hi[e] = (short)(hb >> 16);
        lo[e] = bf16_rne(v[e] - hf);
    }
}

// =============== merged prep kernel: img_dft | prep_wfrag | prep_fb | transpose
// block ranges (img_dft first: longest per-block latency, start early):
#define PA_DFT0   0
#define PA_DFTN   (BB * 11)                     // 352
#define PA_WF0    (PA_DFT0 + PA_DFTN)           // 352
#define PA_WFN    32
#define PA_FB0    (PA_WF0 + PA_WFN)             // 384
#define PA_FBN    ((STOT * DD + 255) / 256)     // 2185
#define PA_TR0    (PA_FB0 + PA_FBN)             // 2569
#define PA_TRN    ((TLEN / 32) * (DD / 32) * BB) // 16384
#define PA_TOT    (PA_TR0 + PA_TRN)             // 18953

__global__ __launch_bounds__(256) void prep_all(
    const float* __restrict__ tw1, const float* __restrict__ tw2,
    const float* __restrict__ iw1, const float* __restrict__ iw2,
    unsigned short* __restrict__ outw,
    const float* __restrict__ tfb, float* __restrict__ fbt2,
    const float* __restrict__ ecg, float* __restrict__ xT,
    const float* __restrict__ image, const float* __restrict__ ifb,
    const float* __restrict__ sel, float* __restrict__ zi,
    float* __restrict__ gpart) {
    __shared__ float smem[32 * 33];   // transpose tile / img_dft trig tables
    int bid = blockIdx.x;
    int tid = threadIdx.x;

    if (bid < PA_DFTN) {
        // ---------------- img_dft: rfft(ortho) + filter; partial g to gpart
        float* ctab = smem;           // [196]
        float* stab = smem + 200;     // [196]
        int b = bid / 11;
        int fg = bid % 11;
        for (int m = tid; m < NPATCH; m += 256) {
            ctab[m] = cospif(m * (2.0f / 196.0f));
            stab[m] = sinpif(m * (2.0f / 196.0f));
        }
        __syncthreads();
        if (tid < 128) {
            int d = tid;
            float accr[9], acci[9];
            int mc[9];
#pragma unroll
            for (int j = 0; j < 9; ++j) { accr[j] = 0.0f; acci[j] = 0.0f; mc[j] = 0; }
            const float* img = image + (size_t)b * NPATCH * DD + d;
            for (int n = 0; n < NPATCH; ++n) {
                float v = img[(size_t)n * DD];
#pragma unroll
                for (int j = 0; j < 9; ++j) {
                    float c = ctab[mc[j]], s = stab[mc[j]];
                    accr[j] += v * c;
                    acci[j] -= v * s;
                    mc[j] += fg * 9 + j;
                    if (mc[j] >= NPATCH) mc[j] -= NPATCH;
                }
            }
            float gg = 0.0f;
#pragma unroll
            for (int j = 0; j < 9; ++j) {
                int f = fg * 9 + j;
                float Xr = accr[j] * (1.0f / 14.0f);
                float Xi = acci[j] * (1.0f / 14.0f);
                float sr = (Xr * Xr - Xi * Xi) * (1.0f / 99.0f);
                float si = 2.0f * Xr * Xi * (1.0f / 99.0f);
                float2 f0 = ((const float2*)ifb)[f * DD + d];
                float2 f1 = ((const float2*)ifb)[NFREQ * DD + f * DD + d];
                float fbr = -(f0.x + f1.x), fbi = -(f0.y + f1.y);
                float zr = sr * fbr - si * fbi;
                float zm = sr * fbi + si * fbr;
                float2 o; o.x = zr; o.y = zm;
                ((float2*)zi)[((size_t)b * NFREQ + f) * DD + d] = o;
                float2 sl = ((const float2*)sel)[f * DD + d];
                gg += zr * sl.x - zm * sl.y;
            }
            gpart[((size_t)fg * BB + b) * DD + d] = gg * (1.0f / 99.0f);
        }
    } else if (bid < PA_FB0) {
        // ---------------- prep_wfrag
        int id = (bid - PA_WF0) * 256 + tid;
        if (id < 4 * 2048) {
            int m = id >> 11;
            int r = id & 2047;
            int kt = r >> 9;
            int n = (r >> 6) & 7;
            int lane = r & 63;
            int k0 = kt * 32 + (lane >> 4) * 8;
            int col = n * 16 + (lane & 15);
            const float* w = (m == 0) ? tw1 : (m == 1) ? tw2 : (m == 2) ? iw1 : iw2;
            u16x8 hi, lo;
#pragma unroll
            for (int e = 0; e < 8; ++e) {
                float v = w[(size_t)(k0 + e) * DD + col];
                unsigned bv = __float_as_uint(v);
                unsigned hb = (bv + 0x7fffu + ((bv >> 16) & 1u)) & 0xffff0000u;
                float hf = __uint_as_float(hb);
                float lres = v - hf;
                unsigned bl = __float_as_uint(lres);
                hi[e] = (unsigned short)(hb >> 16);
                lo[e] = (unsigned short)((bl + 0x7fffu + ((bl >> 16) & 1u)) >> 16);
            }
            u16x8* base = (u16x8*)(outw + (size_t)m * 32768);
            base[r] = hi;
            base[2048 + r] = lo;
        }
    } else if (bid < PA_TR0) {
        // ---------------- prep_fb: tfb -> fbt2 (D,17,257,2)
        int idx = (bid - PA_FB0) * 256 + tid;
        if (idx < STOT * DD) {
            int d = idx & 127;
            int s = idx >> 7;
            float2 a = ((const float2*)tfb)[s * DD + d];
            float2 b2 = ((const float2*)tfb)[STOT * DD + s * DD + d];
            int f = s / NFR, t = s % NFR;
            float2 r;
            r.x = -(a.x + b2.x);
            r.y = -(a.y + b2.y);
            ((float2*)fbt2)[((size_t)d * NFR + t) * NBINS + f] = r;
        }
    } else {
        // ---------------- transpose ecg (B,T,D) -> (B,D,T)
        int rel = bid - PA_TR0;
        int t0 = (rel & 127) * 32;
        int d0 = ((rel >> 7) & 3) * 32;
        int b = rel >> 9;
        int lx = tid & 31;
        int ly = tid >> 5;   // 0..7
        float (*tile)[33] = (float (*)[33])smem;
        for (int i = ly; i < 32; i += 8)
            tile[i][lx] = ecg[((size_t)b * TLEN + t0 + i) * DD + d0 + lx];
        __syncthreads();
        for (int i = ly; i < 32; i += 8)
            xT[((size_t)b * DD + d0 + i) * TLEN + t0 + lx] = tile[lx][i];
    }
}

// ----------------------------------------------------- gate = g @ w^T + b
__global__ __launch_bounds__(128) void gate_kernel(const float* __restrict__ gpart,
                                                   const float* __restrict__ w,
                                                   const float* __restrict__ bias,
                                                   float* __restrict__ gate) {
    __shared__ float gs[DD];
    int b = blockIdx.x, e = threadIdx.x;
    float acc0 = 0.0f;
#pragma unroll
    for (int fg = 0; fg < 11; ++fg)
        acc0 += gpart[((size_t)fg * BB + b) * DD + e];
    gs[e] = acc0;
    __syncthreads();
    float acc = bias[e];
    const float* wr = w + (size_t)e * DD;
    for (int d = 0; d < DD; ++d) acc += gs[d] * wr[d];
    gate[b * DD + e] = acc;
}

// ------------------------- per-(b,d): STFT -> filter*gate -> ISTFT, in-place
// Register-resident 256-pt complex FFT per wave (point i = reg*64+lane).
// Fused middle phase (thread-local slot pair), 4 barriers total.
// 256 threads/block (512-thr regressed: LDS caps blocks/CU at 4 regardless,
// wider blocks only widen barrier scope). Middle-phase trig via LDS table.
#define SWZ(e) ((e) ^ (((e) >> 4) & 15))

#define CMULW(dr, di, c, s, xr, xi) { float _t = (dr)*(c) - (di)*(s); xi = (dr)*(s) + (di)*(c); xr = _t; }
#define BF(xr, xi, h) { \
    float pr_ = __shfl_xor(xr, h), pi_ = __shfl_xor(xi, h); \
    float dr2_ = fmaf(sg##h, xr, pr_), di2_ = fmaf(sg##h, xi, pi_); \
    CMULW(dr2_, di2_, tc##h, ts##h, xr, xi) }
#define SSTG(h) BF(a0r, a0i, h) BF(a1r, a1i, h) BF(a2r, a2i, h) BF(a3r, a3i, h)
#define BF1(xr, xi) { \
    float pr_ = __shfl_xor(xr, 1), pi_ = __shfl_xor(xi, 1); \
    xr = fmaf(sg1, xr, pr_); xi = fmaf(sg1, xi, pi_); }
#define DIF256() { \
    float dr_, di_; \
    dr_ = a0r - a2r; di_ = a0i - a2i; a0r += a2r; a0i += a2i; CMULW(dr_, di_, wa_c, wa_s, a2r, a2i) \
    dr_ = a1r - a3r; di_ = a1i - a3i; a1r += a3r; a1i += a3i; CMULW(dr_, di_, wb_c, wb_s, a3r, a3i) \
    dr_ = a0r - a1r; di_ = a0i - a1i; a0r += a1r; a0i += a1i; CMULW(dr_, di_, wc_c, wc_s, a1r, a1i) \
    dr_ = a2r - a3r; di_ = a2i - a3i; a2r += a3r; a2i += a3i; CMULW(dr_, di_, wc_c, wc_s, a3r, a3i) \
    SSTG(32) SSTG(16) SSTG(8) SSTG(4) SSTG(2) \
    BF1(a0r, a0i) BF1(a1r, a1i) BF1(a2r, a2i) BF1(a3r, a3i) }

__global__ __launch_bounds__(256, 4) void stft_filter_istft(
    float* xT, const float* __restrict__ fbt2, const float* __restrict__ gate) {
    __shared__ float2 spec[NFR * 256];   // 34816 B
    __shared__ float win[NSEG];          // 2048 B
    __shared__ float rnorm[256];         // 1024 B
    __shared__ float mct[129], mst[129]; // 1032 B middle-phase trig
    int tid = threadIdx.x;
    int lane = tid & 63, wave = tid >> 6;
    int bd = blockIdx.x;              // b*128 + d
    int d = bd & 127;
    float gat = gate[bd];
    const float scl = gat * (1.0f / 4369.0f);
    float* xrow = xT + (size_t)bd * TLEN;
    const float2* fbrow = (const float2*)(fbt2 + (size_t)d * NFR * NBINS * 2);

    for (int j = tid; j < NSEG; j += 256)
        win[j] = 0.5f - 0.5f * cospif(j * (1.0f / 256.0f));   // sin^2(pi j/512)
    {
        float s2 = 0.5f - 0.5f * cospif(tid * (1.0f / 256.0f));
        float c2 = 1.0f - s2;
        rnorm[tid] = 1.0f / (s2 * s2 + c2 * c2);
    }
    if (tid < 129) {
        mct[tid] = cospif(tid * (1.0f / 256.0f));
        mst[tid] = sinpif(tid * (1.0f / 256.0f));
    }

    // ---- hoisted twiddles (W = e^{-2pi i k/256}; ts holds -sin)
    float wa_c = cospif(lane * (1.0f / 128.0f)), wa_s = -sinpif(lane * (1.0f / 128.0f));
    float wb_c = cospif((64 + lane) * (1.0f / 128.0f)), wb_s = -sinpif((64 + lane) * (1.0f / 128.0f));
    float wc_c = cospif(lane * (1.0f / 64.0f)),  wc_s = -sinpif(lane * (1.0f / 64.0f));
#define MKT(h) \
    float tc##h, ts##h, sg##h; \
    { int set_ = lane & h; float ang_ = (float)(lane & (h - 1)) * (1.0f / h); \
      tc##h = set_ ? cospif(ang_) : 1.0f; \
      ts##h = set_ ? -sinpif(ang_) : 0.0f; \
      sg##h = set_ ? -1.0f : 1.0f; }
    MKT(32) MKT(16) MKT(8) MKT(4) MKT(2)
    float sg1 = (lane & 1) ? -1.0f : 1.0f;
#undef MKT

    // scatter (bitrev) and gather (natural) element addresses, swizzled
    int eS[4], eL[4];
#pragma unroll
    for (int j = 0; j < 4; ++j) {
        int i = j * 64 + lane;
        eS[j] = SWZ((int)(__brev((unsigned)i) >> 24));
        eL[j] = SWZ(i);
    }
    __syncthreads();

    // ---- forward: load+window -> DIF -> scatter spectrum (natural order)
    for (int t = wave; t < NFR; t += 4) {
        float a0r, a0i, a1r, a1i, a2r, a2i, a3r, a3i;
#define LOADJ(j, xr, xi) { \
        int i_ = (j) * 64 + lane; \
        int src_ = t * HOP + 2 * i_ - HOP; \
        float er_ = 0.0f, oi_ = 0.0f; \
        if (src_ >= 0 && src_ < TLEN) { \
            float2 v_ = *(const float2*)(xrow + src_); er_ = v_.x; oi_ = v_.y; } \
        float2 w_ = *(const float2*)(win + 2 * i_); \
        xr = er_ * w_.x; xi = oi_ * w_.y; }
        LOADJ(0, a0r, a0i) LOADJ(1, a1r, a1i) LOADJ(2, a2r, a2i) LOADJ(3, a3r, a3i)
#undef LOADJ
        DIF256()
        float2* sp = spec + t * 256;
        sp[eS[0]] = make_float2(a0r, a0i);
        sp[eS[1]] = make_float2(a1r, a1i);
        sp[eS[2]] = make_float2(a2r, a2i);
        sp[eS[3]] = make_float2(a3r, a3i);
    }
    __syncthreads();

    // ---- middle (fused): rfft unpack -> square -> filter*gate -> conj repack
    for (int j = tid; j < NFR * 129; j += 256) {
        int t = j / 129, m = j - t * 129;
        float2* sp = spec + t * 256;
        const float2* fbr = fbrow + t * NBINS;
        if (m == 0) {
            float2 v = sp[0];
            float re = v.x, im = v.y;
            float z0 = (re + im) * (1.0f / 256.0f);
            float zN = (re - im) * (1.0f / 256.0f);
            float2 fb0 = fbr[0], fbN = fbr[256];
            float y1r = z0 * z0 * fb0.x * scl;
            float y2r = zN * zN * fbN.x * scl;
            float Er = 0.5f * (y1r + y2r);
            float Dr = 0.5f * (y1r - y2r);
            sp[0] = make_float2(Er, -Dr);
        } else if (m == 128) {
            float2 v = sp[SWZ(128)];
            float Zr = v.x, Zi = v.y;
            float zr = Zr * (1.0f / 256.0f), zi2 = -Zi * (1.0f / 256.0f);
            float sr = zr * zr - zi2 * zi2, si = 2.0f * zr * zi2;
            float2 fb = fbr[128];
            sp[SWZ(128)] = make_float2((sr * fb.x - si * fb.y) * scl,
                                       (sr * fb.y + si * fb.x) * scl);
        } else {
            float2 vm = sp[SWZ(m)];
            float2 vc = sp[SWZ(256 - m)];
            float Amr = vm.x, Ami = vm.y;
            float Acr = vc.x, Aci = vc.y;
            float c = mct[m];
            float sn = mst[m];
            float y1r, y1i, y2r, y2i;
            {
                float Br = Acr, Bi = -Aci;
                float xer = 0.5f * (Amr + Br), xei = 0.5f * (Ami + Bi);
                float xo_r = 0.5f * (Ami - Bi), xo_i = -0.5f * (Amr - Br);
                float Xr = xer + c * xo_r + sn * xo_i;
                float Xi = xei + c * xo_i - sn * xo_r;
                float zr = Xr * (1.0f / 256.0f), zi2 = Xi * (1.0f / 256.0f);
                float sr = zr * zr - zi2 * zi2, si = 2.0f * zr * zi2;
                float2 fb = fbr[m];
                y1r = (sr * fb.x - si * fb.y) * scl;
                y1i = (sr * fb.y + si * fb.x) * scl;
            }
            {
                float Br = Amr, Bi = -Ami;
                float xer = 0.5f * (Acr + Br), xei = 0.5f * (Aci + Bi);
                float xo_r = 0.5f * (Aci - Bi), xo_i = -0.5f * (Acr - Br);
                float Xr = xer - c * xo_r + sn * xo_i;
                float Xi = xei - c * xo_i - sn * xo_r;
                float zr = Xr * (1.0f / 256.0f), zi2 = Xi * (1.0f / 256.0f);
                float sr = zr * zr - zi2 * zi2, si = 2.0f * zr * zi2;
                float2 fb = fbr[256 - m];
                y2r = (sr * fb.x - si * fb.y) * scl;
                y2i = (sr * fb.y + si * fb.x) * scl;
            }
            float Er = 0.5f * (y1r + y2r);
            float Ei = 0.5f * (y1i - y2i);
            float Dr = 0.5f * (y1r - y2r);
            float Di = 0.5f * (y1i + y2i);
            float Or = Dr * c - Di * sn;
            float Oi = Dr * sn + Di * c;
            sp[SWZ(m)] = make_float2(Er - Oi, -(Ei + Or));
            sp[SWZ(256 - m)] = make_float2(Er + Oi, Ei - Or);
        }
    }
    __syncthreads();

    // ---- inverse: gather conj(B) natural -> same DIF -> scatter time domain
    for (int t = wave; t < NFR; t += 4) {
        float2* sp = spec + t * 256;
        float2 v0 = sp[eL[0]], v1 = sp[eL[1]], v2 = sp[eL[2]], v3 = sp[eL[3]];
        float a0r = v0.x, a0i = v0.y, a1r = v1.x, a1i = v1.y;
        float a2r = v2.x, a2i = v2.y, a3r = v3.x, a3i = v3.y;
        DIF256()
        sp[eS[0]] = make_float2(a0r, a0i);
        sp[eS[1]] = make_float2(a1r, a1i);
        sp[eS[2]] = make_float2(a2r, a2i);
        sp[eS[3]] = make_float2(a3r, a3i);
    }
    __syncthreads();

    // ---- OLA (even sample = re, odd = -im)
    const float* specf = (const float*)spec;
    for (int j = tid; j < TLEN; j += 256) {
        int p = j + HOP;
        int t1 = p >> 8, t0 = t1 - 1;
        int i1 = p & 255, i0 = i1 + 256;
        int comp = j & 1;
        float v1 = specf[(t1 * 256 + SWZ(i1 >> 1)) * 2 + comp];
        float v0 = specf[(t0 * 256 + SWZ(i0 >> 1)) * 2 + comp];
        if (comp) { v1 = -v1; v0 = -v0; }
        float s = v0 * win[i0] + v1 * win[i1];
        xrow[j] = s * rnorm[i1];
    }
}

// ------------------------------- addnorm body: LN1 -> split-bf16 MFMA MLP -> LN2
// ROUND-4 structure (verified). Change vs r4: srcB add folded into LN1's read
// (coalesced direct global read) -- deletes one 8K LDS RMW pass + one barrier.
#define XLNS 132

__device__ __forceinline__ void mlp_gemm(const float* __restrict__ ax,
                                         const unsigned short* __restrict__ wf,
                                         int lane, f32x4 acc[8]) {
#pragma unroll
    for (int n = 0; n < 8; ++n) acc[n] = (f32x4){0.f, 0.f, 0.f, 0.f};
    const bf16x8* bh0 = (const bf16x8*)wf;
    const bf16x8* bl0 = (const bf16x8*)(wf + 16384);
#pragma unroll 1
    for (int kt = 0; kt < 4; ++kt) {
        float4 va = *(const float4*)(ax + kt * 32);
        float4 vb = *(const float4*)(ax + kt * 32 + 4);
        bf16x8 ahi, alo;
        split8(va, vb, ahi, alo);
        const bf16x8* bh = bh0 + kt * 512 + lane;
        const bf16x8* bl = bl0 + kt * 512 + lane;
#pragma unroll
        for (int n = 0; n < 8; ++n) {
            bf16x8 wh = bh[n * 64];
            bf16x8 wl = bl[n * 64];
            acc[n] = __builtin_amdgcn_mfma_f32_16x16x32_bf16(ahi, wh, acc[n], 0, 0, 0);
            acc[n] = __builtin_amdgcn_mfma_f32_16x16x32_bf16(alo, wh, acc[n], 0, 0, 0);
            acc[n] = __builtin_amdgcn_mfma_f32_16x16x32_bf16(ahi, wl, acc[n], 0, 0, 0);
        }
    }
}

template <int FUSED>
__device__ __forceinline__ void addnorm_body(
    int bid, float* xln,
    const float* __restrict__ srcA, const float* __restrict__ srcB,
    const float* __restrict__ ln1g, const float* __restrict__ ln1b,
    const unsigned short* __restrict__ w1f, const float* __restrict__ b1,
    const unsigned short* __restrict__ w2f, const float* __restrict__ b2,
    const float* __restrict__ ln2g, const float* __restrict__ ln2b,
    float* __restrict__ out) {
    int tid = threadIdx.x;
    int b = 0, t0 = 0;
    size_t R0 = 0;
    // ---- Phase A: stage srcA tile
    if (FUSED) {
        b = bid >> 6;
        t0 = (bid & 63) * 64;
        for (int i = tid; i < 64 * 128; i += 256) {
            int dd = i >> 6, r = i & 63;
            xln[r * XLNS + dd] = srcA[((size_t)b * DD + dd) * TLEN + t0 + r];
        }
    } else {
        R0 = (size_t)bid * 64;
        for (int i = tid; i < 64 * 128; i += 256) {
            int r = i >> 7, dd = i & 127;
            xln[r * XLNS + dd] = srcA[(R0 + r) * DD + dd];
        }
    }
    __syncthreads();
    // ---- LN1 (wave per row); srcB added inline (FUSED)
    int wave = tid >> 6, lane = tid & 63;
    const float* pB = FUSED ? srcB + ((size_t)b * TLEN + t0) * DD : nullptr;
    for (int r = wave; r < 64; r += 4) {
        float v0 = xln[r * XLNS + lane];
        float v1 = xln[r * XLNS + 64 + lane];
        if (FUSED) {
            v0 += pB[(size_t)r * DD + lane];
            v1 += pB[(size_t)r * DD + 64 + lane];
        }
        float s = v0 + v1, ss = v0 * v0 + v1 * v1;
        for (int off = 32; off > 0; off >>= 1) {
            s += __shfl_xor(s, off);
            ss += __shfl_xor(ss, off);
        }
        float mean = s * (1.0f / 128.0f);
        float var = ss * (1.0f / 128.0f) - mean * mean;
        float rstd = rsqrtf(var + 1e-5f);
        xln[r * XLNS + lane] = (v0 - mean) * rstd * ln1g[lane] + ln1b[lane];
        xln[r * XLNS + 64 + lane] = (v1 - mean) * rstd * ln1g[64 + lane] + ln1b[64 + lane];
    }
    __syncthreads();
    // ---- fragment coordinates
    int q = lane >> 4, c = lane & 15;
    int rbase = wave * 16 + q * 4;                          // C-frag rows (4)
    const float* ax = &xln[(wave * 16 + c) * XLNS + q * 8]; // A-frag base
    // ---- GEMM1: acc = x @ w1
    f32x4 acc[8];
    mlp_gemm(ax, w1f, lane, acc);
    // ---- residual (post-LN1 x) at this thread's C positions
    float res[8][4];
#pragma unroll
    for (int n = 0; n < 8; ++n)
#pragma unroll
        for (int r = 0; r < 4; ++r)
            res[n][r] = xln[(rbase + r) * XLNS + n * 16 + c];
    // ---- bias + gelu
#pragma unroll
    for (int n = 0; n < 8; ++n) {
        float bb = b1[n * 16 + c];
#pragma unroll
        for (int r = 0; r < 4; ++r)
            acc[n][r] = gelu_exact(acc[n][r] + bb);
    }
    __syncthreads();   // all reads of xln(=x) done
#pragma unroll
    for (int n = 0; n < 8; ++n)
#pragma unroll
        for (int r = 0; r < 4; ++r)
            xln[(rbase + r) * XLNS + n * 16 + c] = acc[n][r];   // xln := g
    __syncthreads();
    // ---- GEMM2: acc = g @ w2; h = acc + b2 + res
    mlp_gemm(ax, w2f, lane, acc);
#pragma unroll
    for (int n = 0; n < 8; ++n) {
        float bb = b2[n * 16 + c];
#pragma unroll
        for (int r = 0; r < 4; ++r)
            acc[n][r] += bb + res[n][r];
    }
    // ---- LN2 stats: rows live in 16-lane groups (cols spread over c and n)
    float s4[4] = {0.f, 0.f, 0.f, 0.f}, ss4[4] = {0.f, 0.f, 0.f, 0.f};
#pragma unroll
    for (int n = 0; n < 8; ++n)
#pragma unroll
        for (int r = 0; r < 4; ++r) {
            float h = acc[n][r];
            s4[r] += h; ss4[r] += h * h;
        }
#pragma unroll
    for (int off = 8; off > 0; off >>= 1) {
#pragma unroll
        for (int r = 0; r < 4; ++r) {
            s4[r] += __shfl_xor(s4[r], off);
            ss4[r] += __shfl_xor(ss4[r], off);
        }
    }
    float g2v[8], b2v[8];
#pragma unroll
    for (int n = 0; n < 8; ++n) {
        g2v[n] = ln2g[n * 16 + c];
        b2v[n] = ln2b[n * 16 + c];
    }
#pragma unroll
    for (int r = 0; r < 4; ++r) {
        float mean = s4[r] * (1.0f / 128.0f);
        float var = ss4[r] * (1.0f / 128.0f) - mean * mean;
        float rstd = rsqrtf(var + 1e-5f);
        size_t orow = FUSED ? ((size_t)b * TLEN + t0 + rbase + r) * DD
                            : (R0 + rbase + r) * DD;
#pragma unroll
        for (int n = 0; n < 8; ++n)
            out[orow + n * 16 + c] = (acc[n][r] - mean) * rstd * g2v[n] + b2v[n];
    }
}

// =============== fused2: addnorm<1> (blocks 0..2047) | img_irfft (2048..2495)
#define F2_AN  (BB * (TLEN / 64))   // 2048
#define F2_IR  (BB * 14)            // 448

__global__ __launch_bounds__(256) void fused_text_img(
    const float* __restrict__ srcA, const float* __restrict__ ecg,
    const float* __restrict__ ln1g, const float* __restrict__ ln1b,
    const unsigned short* __restrict__ w1f, const float* __restrict__ b1,
    const unsigned short* __restrict__ w2f, const float* __restrict__ b2,
    const float* __restrict__ ln2g, const float* __restrict__ ln2b,
    float* __restrict__ out,
    const float* __restrict__ zi, const float* __restrict__ image,
    float* __restrict__ x0img) {
    __shared__ __align__(16) float xln[64 * XLNS];
    int bid = blockIdx.x;
    int tid = threadIdx.x;
    if (bid < F2_AN) {
        addnorm_body<1>(bid, xln, srcA, ecg, ln1g, ln1b, w1f, b1, w2f, b2,
                        ln2g, ln2b, out);
    } else {
        // ---------------- img_irfft (ortho) + add image (LDS reuses xln)
        int rel = bid - F2_AN;
        float* ctab = xln;          // [196]
        float* stab = xln + 200;    // [196]
        int b = rel / 14;
        int ng = rel % 14;
        for (int m = tid; m < NPATCH; m += 256) {
            ctab[m] = cospif(m * (2.0f / 196.0f));
            stab[m] = sinpif(m * (2.0f / 196.0f));
        }
        __syncthreads();
        if (tid < 128) {
            int d = tid;
            const float2* zrow = (const float2*)zi + (size_t)b * NFREQ * DD + d;
            float acc[14];
            int mc[14];
            float2 z0 = zrow[0];
#pragma unroll
            for (int j = 0; j < 14; ++j) { acc[j] = z0.x; mc[j] = 0; }
            for (int f = 1; f <= 97; ++f) {
                float2 z = zrow[(size_t)f * DD];
#pragma unroll
                for (int j = 0; j < 14; ++j) {
                    int n = ng * 14 + j;
                    mc[j] += n;
                    if (mc[j] >= NPATCH) mc[j] -= NPATCH;
                    acc[j] += 2.0f * (z.x * ctab[mc[j]] - z.y * stab[mc[j]]);
                }
            }
            float2 z98 = zrow[98 * (size_t)DD];
#pragma unroll
            for (int j = 0; j < 14; ++j) {
                int n = ng * 14 + j;
                float a = acc[j] + ((n & 1) ? -z98.x : z98.x);
                float y = a * (1.0f / 14.0f);
                size_t idx = ((size_t)b * NPATCH + n) * DD + d;
                x0img[idx] = y + image[idx];
            }
        }
    }
}

// non-fused addnorm (image branch, runs last)
__global__ __launch_bounds__(256) void addnorm_img(
    const float* __restrict__ srcA,
    const float* __restrict__ ln1g, const float* __restrict__ ln1b,
    const unsigned short* __restrict__ w1f, const float* __restrict__ b1,
    const unsigned short* __restrict__ w2f, const float* __restrict__ b2,
    const float* __restrict__ ln2g, const float* __restrict__ ln2b,
    float* __restrict__ out) {
    __shared__ __align__(16) float xln[64 * XLNS];
    addnorm_body<0>(blockIdx.x, xln, srcA, nullptr, ln1g, ln1b, w1f, b1,
                    w2f, b2, ln2g, ln2b, out);
}

extern "C" void kernel_launch(void* const* d_in, const int* in_sizes, int n_in,
                              void* d_out, int out_size, void* d_ws, size_t ws_size,
                              hipStream_t stream) {
    (void)in_sizes; (void)n_in; (void)out_size; (void)ws_size;
    const float* ecg   = (const float*)d_in[0];
    const float* image = (const float*)d_in[1];
    const float* tfb   = (const float*)d_in[2];
    const float* ifb   = (const float*)d_in[3];
    const float* sel   = (const float*)d_in[4];
    const float* i2t_w = (const float*)d_in[5];
    const float* i2t_b = (const float*)d_in[6];
    const float* t_ln1_g = (const float*)d_in[7];
    const float* t_ln1_b = (const float*)d_in[8];
    const float* t_w1 = (const float*)d_in[9];
    const float* t_b1 = (const float*)d_in[10];
    const float* t_w2 = (const float*)d_in[11];
    const float* t_b2 = (const float*)d_in[12];
    const float* t_ln2_g = (const float*)d_in[13];
    const float* t_ln2_b = (const float*)d_in[14];
    const float* i_ln1_g = (const float*)d_in[15];
    const float* i_ln1_b = (const float*)d_in[16];
    const float* i_w1 = (const float*)d_in[17];
    const float* i_b1 = (const float*)d_in[18];
    const float* i_w2 = (const float*)d_in[19];
    const float* i_b2 = (const float*)d_in[20];
    const float* i_ln2_g = (const float*)d_in[21];
    const float* i_ln2_b = (const float*)d_in[22];
    float* out = (float*)d_out;
    float* ws = (float*)d_ws;
    unsigned short* wfb = (unsigned short*)(ws + WF_OFF);
    float* gpart = ws + X0I_OFF;   // scratch: free until img_irfft writes x0img

    // launch 1: all independent prep work (img_dft | wfrag | prep_fb | transpose)
    prep_all<<<PA_TOT, 256, 0, stream>>>(
        t_w1, t_w2, i_w1, i_w2, wfb,
        tfb, ws + FBT2_OFF,
        ecg, ws + XT_OFF,
        image, ifb, sel, ws + ZI_OFF, gpart);
    // launch 2: gate (sums img_dft partials)
    gate_kernel<<<BB, 128, 0, stream>>>(gpart, i2t_w, i2t_b, ws + GATE_OFF);
    // launch 3: stft -> filter -> istft
    stft_filter_istft<<<BB * DD, 256, 0, stream>>>(ws + XT_OFF, ws + FBT2_OFF, ws + GATE_OFF);
    // launch 4: text addnorm | image irfft (independent)
    fused_text_img<<<F2_AN + F2_IR, 256, 0, stream>>>(
        ws + XT_OFF, ecg, t_ln1_g, t_ln1_b, wfb + 0, t_b1, wfb + 32768, t_b2,
        t_ln2_g, t_ln2_b, out,
        ws + ZI_OFF, image, ws + X0I_OFF);
    // launch 5: image addnorm
    addnorm_img<<<(BB * NPATCH) / 64, 256, 0, stream>>>(
        ws + X0I_OFF, i_ln1_g, i_ln1_b, wfb + 65536, i_b1, wfb + 98304, i_b2,
        i_ln2_g, i_ln2_b, out + (size_t)BB * TLEN * DD);
}

// Round 10
// 545.948 us; speedup vs baseline: 1.1134x; 1.0440x over previous
//
#include <hip/hip_runtime.h>
#include <math.h>

#define BB 32
#define DD 128
#define TLEN 4096
#define NSEG 512
#define HOP 256
#define NFR 17
#define NBINS 257
#define STOT 4369
#define NPATCH 196
#define NFREQ 99
#define OLAL 4608

// workspace layout (float offsets)
#define FBT2_OFF 0
#define FBT2_SZ  (DD * NFR * NBINS * 2)       // 1,118,464
#define GBUF_OFF (FBT2_OFF + FBT2_SZ)
#define GATE_OFF (GBUF_OFF + BB * DD)
#define ZI_OFF   (GATE_OFF + BB * DD)
#define ZI_SZ    (BB * NFREQ * DD * 2)        // 811,008
#define X0I_OFF  (ZI_OFF + ZI_SZ)             // reused: gpart (launch1-2), x0img (launch4-5)
#define X0I_SZ   (BB * NPATCH * DD)           // 802,816
#define XT_OFF   (X0I_OFF + X0I_SZ)
#define WF_OFF   (XT_OFF + BB * DD * TLEN)    // bf16 hi/lo weight fragments (4 mats x 32768 ushort)

typedef __attribute__((ext_vector_type(8))) short bf16x8;
typedef __attribute__((ext_vector_type(4))) float f32x4;
typedef __attribute__((ext_vector_type(8))) unsigned short u16x8;

__device__ __forceinline__ float gelu_exact(float x) {
    return 0.5f * x * (1.0f + erff(x * 0.70710678118654752f));
}

__device__ __forceinline__ short bf16_rne(float v) {
    unsigned b = __float_as_uint(v);
    return (short)((b + 0x7fffu + ((b >> 16) & 1u)) >> 16);
}

// split fp32 -> bf16 hi + bf16 lo (v ~= hi + lo, error ~2^-17 relative)
__device__ __forceinline__ void split8(float4 a, float4 b, bf16x8& hi, bf16x8& lo) {
    float v[8] = {a.x, a.y, a.z, a.w, b.x, b.y, b.z, b.w};
#pragma unroll
    for (int e = 0; e < 8; ++e) {
        unsigned bv = __float_as_uint(v[e]);
        unsigned hb = (bv + 0x7fffu + ((bv >> 16) & 1u)) & 0xffff0000u;
        float hf = __uint_as_float(hb);
        hi[e] = (short)(hb >> 16);
        lo[e] = bf16_rne(v[e] - hf);
    }
}

// =============== merged prep kernel: img_dft | prep_wfrag | prep_fb | transpose
// block ranges (img_dft first: longest per-block latency, start early):
#define PA_DFT0   0
#define PA_DFTN   (BB * 11)                     // 352
#define PA_WF0    (PA_DFT0 + PA_DFTN)           // 352
#define PA_WFN    32
#define PA_FB0    (PA_WF0 + PA_WFN)             // 384
#define PA_FBN    ((STOT * DD + 255) / 256)     // 2185
#define PA_TR0    (PA_FB0 + PA_FBN)             // 2569
#define PA_TRN    ((TLEN / 32) * (DD / 32) * BB) // 16384
#define PA_TOT    (PA_TR0 + PA_TRN)             // 18953

__global__ __launch_bounds__(256) void prep_all(
    const float* __restrict__ tw1, const float* __restrict__ tw2,
    const float* __restrict__ iw1, const float* __restrict__ iw2,
    unsigned short* __restrict__ outw,
    const float* __restrict__ tfb, float* __restrict__ fbt2,
    const float* __restrict__ ecg, float* __restrict__ xT,
    const float* __restrict__ image, const float* __restrict__ ifb,
    const float* __restrict__ sel, float* __restrict__ zi,
    float* __restrict__ gpart) {
    __shared__ float smem[32 * 33];   // transpose tile / img_dft trig tables
    int bid = blockIdx.x;
    int tid = threadIdx.x;

    if (bid < PA_DFTN) {
        // ---------------- img_dft: rfft(ortho) + filter; partial g to gpart
        float* ctab = smem;           // [196]
        float* stab = smem + 200;     // [196]
        int b = bid / 11;
        int fg = bid % 11;
        for (int m = tid; m < NPATCH; m += 256) {
            ctab[m] = cospif(m * (2.0f / 196.0f));
            stab[m] = sinpif(m * (2.0f / 196.0f));
        }
        __syncthreads();
        if (tid < 128) {
            int d = tid;
            float accr[9], acci[9];
            int mc[9];
#pragma unroll
            for (int j = 0; j < 9; ++j) { accr[j] = 0.0f; acci[j] = 0.0f; mc[j] = 0; }
            const float* img = image + (size_t)b * NPATCH * DD + d;
            for (int n = 0; n < NPATCH; ++n) {
                float v = img[(size_t)n * DD];
#pragma unroll
                for (int j = 0; j < 9; ++j) {
                    float c = ctab[mc[j]], s = stab[mc[j]];
                    accr[j] += v * c;
                    acci[j] -= v * s;
                    mc[j] += fg * 9 + j;
                    if (mc[j] >= NPATCH) mc[j] -= NPATCH;
                }
            }
            float gg = 0.0f;
#pragma unroll
            for (int j = 0; j < 9; ++j) {
                int f = fg * 9 + j;
                float Xr = accr[j] * (1.0f / 14.0f);
                float Xi = acci[j] * (1.0f / 14.0f);
                float sr = (Xr * Xr - Xi * Xi) * (1.0f / 99.0f);
                float si = 2.0f * Xr * Xi * (1.0f / 99.0f);
                float2 f0 = ((const float2*)ifb)[f * DD + d];
                float2 f1 = ((const float2*)ifb)[NFREQ * DD + f * DD + d];
                float fbr = -(f0.x + f1.x), fbi = -(f0.y + f1.y);
                float zr = sr * fbr - si * fbi;
                float zm = sr * fbi + si * fbr;
                float2 o; o.x = zr; o.y = zm;
                ((float2*)zi)[((size_t)b * NFREQ + f) * DD + d] = o;
                float2 sl = ((const float2*)sel)[f * DD + d];
                gg += zr * sl.x - zm * sl.y;
            }
            gpart[((size_t)fg * BB + b) * DD + d] = gg * (1.0f / 99.0f);
        }
    } else if (bid < PA_FB0) {
        // ---------------- prep_wfrag
        int id = (bid - PA_WF0) * 256 + tid;
        if (id < 4 * 2048) {
            int m = id >> 11;
            int r = id & 2047;
            int kt = r >> 9;
            int n = (r >> 6) & 7;
            int lane = r & 63;
            int k0 = kt * 32 + (lane >> 4) * 8;
            int col = n * 16 + (lane & 15);
            const float* w = (m == 0) ? tw1 : (m == 1) ? tw2 : (m == 2) ? iw1 : iw2;
            u16x8 hi, lo;
#pragma unroll
            for (int e = 0; e < 8; ++e) {
                float v = w[(size_t)(k0 + e) * DD + col];
                unsigned bv = __float_as_uint(v);
                unsigned hb = (bv + 0x7fffu + ((bv >> 16) & 1u)) & 0xffff0000u;
                float hf = __uint_as_float(hb);
                float lres = v - hf;
                unsigned bl = __float_as_uint(lres);
                hi[e] = (unsigned short)(hb >> 16);
                lo[e] = (unsigned short)((bl + 0x7fffu + ((bl >> 16) & 1u)) >> 16);
            }
            u16x8* base = (u16x8*)(outw + (size_t)m * 32768);
            base[r] = hi;
            base[2048 + r] = lo;
        }
    } else if (bid < PA_TR0) {
        // ---------------- prep_fb: tfb -> fbt2 (D,17,257,2)
        int idx = (bid - PA_FB0) * 256 + tid;
        if (idx < STOT * DD) {
            int d = idx & 127;
            int s = idx >> 7;
            float2 a = ((const float2*)tfb)[s * DD + d];
            float2 b2 = ((const float2*)tfb)[STOT * DD + s * DD + d];
            int f = s / NFR, t = s % NFR;
            float2 r;
            r.x = -(a.x + b2.x);
            r.y = -(a.y + b2.y);
            ((float2*)fbt2)[((size_t)d * NFR + t) * NBINS + f] = r;
        }
    } else {
        // ---------------- transpose ecg (B,T,D) -> (B,D,T)
        int rel = bid - PA_TR0;
        int t0 = (rel & 127) * 32;
        int d0 = ((rel >> 7) & 3) * 32;
        int b = rel >> 9;
        int lx = tid & 31;
        int ly = tid >> 5;   // 0..7
        float (*tile)[33] = (float (*)[33])smem;
        for (int i = ly; i < 32; i += 8)
            tile[i][lx] = ecg[((size_t)b * TLEN + t0 + i) * DD + d0 + lx];
        __syncthreads();
        for (int i = ly; i < 32; i += 8)
            xT[((size_t)b * DD + d0 + i) * TLEN + t0 + lx] = tile[lx][i];
    }
}

// ----------------------------------------------------- gate = g @ w^T + b
__global__ __launch_bounds__(128) void gate_kernel(const float* __restrict__ gpart,
                                                   const float* __restrict__ w,
                                                   const float* __restrict__ bias,
                                                   float* __restrict__ gate) {
    __shared__ float gs[DD];
    int b = blockIdx.x, e = threadIdx.x;
    float acc0 = 0.0f;
#pragma unroll
    for (int fg = 0; fg < 11; ++fg)
        acc0 += gpart[((size_t)fg * BB + b) * DD + e];
    gs[e] = acc0;
    __syncthreads();
    float acc = bias[e];
    const float* wr = w + (size_t)e * DD;
    for (int d = 0; d < DD; ++d) acc += gs[d] * wr[d];
    gate[b * DD + e] = acc;
}

// ------------------------- per-(b,d): STFT -> filter*gate -> ISTFT, in-place
// Register-resident 256-pt complex FFT per wave (point i = reg*64+lane).
// Fused middle phase (thread-local slot pair), 4 barriers total.
#define SWZ(e) ((e) ^ (((e) >> 4) & 15))

#define CMULW(dr, di, c, s, xr, xi) { float _t = (dr)*(c) - (di)*(s); xi = (dr)*(s) + (di)*(c); xr = _t; }
#define BF(xr, xi, h) { \
    float pr_ = __shfl_xor(xr, h), pi_ = __shfl_xor(xi, h); \
    float dr2_ = fmaf(sg##h, xr, pr_), di2_ = fmaf(sg##h, xi, pi_); \
    CMULW(dr2_, di2_, tc##h, ts##h, xr, xi) }
#define SSTG(h) BF(a0r, a0i, h) BF(a1r, a1i, h) BF(a2r, a2i, h) BF(a3r, a3i, h)
#define BF1(xr, xi) { \
    float pr_ = __shfl_xor(xr, 1), pi_ = __shfl_xor(xi, 1); \
    xr = fmaf(sg1, xr, pr_); xi = fmaf(sg1, xi, pi_); }
#define DIF256() { \
    float dr_, di_; \
    dr_ = a0r - a2r; di_ = a0i - a2i; a0r += a2r; a0i += a2i; CMULW(dr_, di_, wa_c, wa_s, a2r, a2i) \
    dr_ = a1r - a3r; di_ = a1i - a3i; a1r += a3r; a1i += a3i; CMULW(dr_, di_, wb_c, wb_s, a3r, a3i) \
    dr_ = a0r - a1r; di_ = a0i - a1i; a0r += a1r; a0i += a1i; CMULW(dr_, di_, wc_c, wc_s, a1r, a1i) \
    dr_ = a2r - a3r; di_ = a2i - a3i; a2r += a3r; a2i += a3i; CMULW(dr_, di_, wc_c, wc_s, a3r, a3i) \
    SSTG(32) SSTG(16) SSTG(8) SSTG(4) SSTG(2) \
    BF1(a0r, a0i) BF1(a1r, a1i) BF1(a2r, a2i) BF1(a3r, a3i) }

__global__ __launch_bounds__(256, 4) void stft_filter_istft(
    float* xT, const float* __restrict__ fbt2, const float* __restrict__ gate) {
    __shared__ float2 spec[NFR * 256];   // 34816 B
    __shared__ float win[NSEG];          // 2048 B
    __shared__ float rnorm[256];         // 1024 B
    __shared__ float mct[129], mst[129]; // 1032 B middle-phase trig
    int tid = threadIdx.x;
    int lane = tid & 63, wave = tid >> 6;
    int bd = blockIdx.x;              // b*128 + d
    int d = bd & 127;
    float gat = gate[bd];
    const float scl = gat * (1.0f / 4369.0f);
    float* xrow = xT + (size_t)bd * TLEN;
    const float2* fbrow = (const float2*)(fbt2 + (size_t)d * NFR * NBINS * 2);

    for (int j = tid; j < NSEG; j += 256)
        win[j] = 0.5f - 0.5f * cospif(j * (1.0f / 256.0f));   // sin^2(pi j/512)
    {
        float s2 = 0.5f - 0.5f * cospif(tid * (1.0f / 256.0f));
        float c2 = 1.0f - s2;
        rnorm[tid] = 1.0f / (s2 * s2 + c2 * c2);
    }
    if (tid < 129) {
        mct[tid] = cospif(tid * (1.0f / 256.0f));
        mst[tid] = sinpif(tid * (1.0f / 256.0f));
    }

    // ---- hoisted twiddles (W = e^{-2pi i k/256}; ts holds -sin)
    float wa_c = cospif(lane * (1.0f / 128.0f)), wa_s = -sinpif(lane * (1.0f / 128.0f));
    float wb_c = cospif((64 + lane) * (1.0f / 128.0f)), wb_s = -sinpif((64 + lane) * (1.0f / 128.0f));
    float wc_c = cospif(lane * (1.0f / 64.0f)),  wc_s = -sinpif(lane * (1.0f / 64.0f));
#define MKT(h) \
    float tc##h, ts##h, sg##h; \
    { int set_ = lane & h; float ang_ = (float)(lane & (h - 1)) * (1.0f / h); \
      tc##h = set_ ? cospif(ang_) : 1.0f; \
      ts##h = set_ ? -sinpif(ang_) : 0.0f; \
      sg##h = set_ ? -1.0f : 1.0f; }
    MKT(32) MKT(16) MKT(8) MKT(4) MKT(2)
    float sg1 = (lane & 1) ? -1.0f : 1.0f;
#undef MKT

    // scatter (bitrev) and gather (natural) element addresses, swizzled
    int eS[4], eL[4];
#pragma unroll
    for (int j = 0; j < 4; ++j) {
        int i = j * 64 + lane;
        eS[j] = SWZ((int)(__brev((unsigned)i) >> 24));
        eL[j] = SWZ(i);
    }
    __syncthreads();

    // ---- forward: load+window -> DIF -> scatter spectrum (natural order)
    for (int t = wave; t < NFR; t += 4) {
        float a0r, a0i, a1r, a1i, a2r, a2i, a3r, a3i;
#define LOADJ(j, xr, xi) { \
        int i_ = (j) * 64 + lane; \
        int src_ = t * HOP + 2 * i_ - HOP; \
        float er_ = 0.0f, oi_ = 0.0f; \
        if (src_ >= 0 && src_ < TLEN) { \
            float2 v_ = *(const float2*)(xrow + src_); er_ = v_.x; oi_ = v_.y; } \
        float2 w_ = *(const float2*)(win + 2 * i_); \
        xr = er_ * w_.x; xi = oi_ * w_.y; }
        LOADJ(0, a0r, a0i) LOADJ(1, a1r, a1i) LOADJ(2, a2r, a2i) LOADJ(3, a3r, a3i)
#undef LOADJ
        DIF256()
        float2* sp = spec + t * 256;
        sp[eS[0]] = make_float2(a0r, a0i);
        sp[eS[1]] = make_float2(a1r, a1i);
        sp[eS[2]] = make_float2(a2r, a2i);
        sp[eS[3]] = make_float2(a3r, a3i);
    }
    __syncthreads();

    // ---- middle (fused): rfft unpack -> square -> filter*gate -> conj repack
    for (int j = tid; j < NFR * 129; j += 256) {
        int t = j / 129, m = j - t * 129;
        float2* sp = spec + t * 256;
        const float2* fbr = fbrow + t * NBINS;
        if (m == 0) {
            float2 v = sp[0];
            float re = v.x, im = v.y;
            float z0 = (re + im) * (1.0f / 256.0f);
            float zN = (re - im) * (1.0f / 256.0f);
            float2 fb0 = fbr[0], fbN = fbr[256];
            float y1r = z0 * z0 * fb0.x * scl;
            float y2r = zN * zN * fbN.x * scl;
            float Er = 0.5f * (y1r + y2r);
            float Dr = 0.5f * (y1r - y2r);
            sp[0] = make_float2(Er, -Dr);
        } else if (m == 128) {
            float2 v = sp[SWZ(128)];
            float Zr = v.x, Zi = v.y;
            float zr = Zr * (1.0f / 256.0f), zi2 = -Zi * (1.0f / 256.0f);
            float sr = zr * zr - zi2 * zi2, si = 2.0f * zr * zi2;
            float2 fb = fbr[128];
            sp[SWZ(128)] = make_float2((sr * fb.x - si * fb.y) * scl,
                                       (sr * fb.y + si * fb.x) * scl);
        } else {
            float2 vm = sp[SWZ(m)];
            float2 vc = sp[SWZ(256 - m)];
            float Amr = vm.x, Ami = vm.y;
            float Acr = vc.x, Aci = vc.y;
            float c = mct[m];
            float sn = mst[m];
            float y1r, y1i, y2r, y2i;
            {
                float Br = Acr, Bi = -Aci;
                float xer = 0.5f * (Amr + Br), xei = 0.5f * (Ami + Bi);
                float xo_r = 0.5f * (Ami - Bi), xo_i = -0.5f * (Amr - Br);
                float Xr = xer + c * xo_r + sn * xo_i;
                float Xi = xei + c * xo_i - sn * xo_r;
                float zr = Xr * (1.0f / 256.0f), zi2 = Xi * (1.0f / 256.0f);
                float sr = zr * zr - zi2 * zi2, si = 2.0f * zr * zi2;
                float2 fb = fbr[m];
                y1r = (sr * fb.x - si * fb.y) * scl;
                y1i = (sr * fb.y + si * fb.x) * scl;
            }
            {
                float Br = Amr, Bi = -Ami;
                float xer = 0.5f * (Acr + Br), xei = 0.5f * (Aci + Bi);
                float xo_r = 0.5f * (Aci - Bi), xo_i = -0.5f * (Acr - Br);
                float Xr = xer - c * xo_r + sn * xo_i;
                float Xi = xei - c * xo_i - sn * xo_r;
                float zr = Xr * (1.0f / 256.0f), zi2 = Xi * (1.0f / 256.0f);
                float sr = zr * zr - zi2 * zi2, si = 2.0f * zr * zi2;
                float2 fb = fbr[256 - m];
                y2r = (sr * fb.x - si * fb.y) * scl;
                y2i = (sr * fb.y + si * fb.x) * scl;
            }
            float Er = 0.5f * (y1r + y2r);
            float Ei = 0.5f * (y1i - y2i);
            float Dr = 0.5f * (y1r - y2r);
            float Di = 0.5f * (y1i + y2i);
            float Or = Dr * c - Di * sn;
            float Oi = Dr * sn + Di * c;
            sp[SWZ(m)] = make_float2(Er - Oi, -(Ei + Or));
            sp[SWZ(256 - m)] = make_float2(Er + Oi, Ei - Or);
        }
    }
    __syncthreads();

    // ---- inverse: gather conj(B) natural -> same DIF -> scatter time domain
    for (int t = wave; t < NFR; t += 4) {
        float2* sp = spec + t * 256;
        float2 v0 = sp[eL[0]], v1 = sp[eL[1]], v2 = sp[eL[2]], v3 = sp[eL[3]];
        float a0r = v0.x, a0i = v0.y, a1r = v1.x, a1i = v1.y;
        float a2r = v2.x, a2i = v2.y, a3r = v3.x, a3i = v3.y;
        DIF256()
        sp[eS[0]] = make_float2(a0r, a0i);
        sp[eS[1]] = make_float2(a1r, a1i);
        sp[eS[2]] = make_float2(a2r, a2i);
        sp[eS[3]] = make_float2(a3r, a3i);
    }
    __syncthreads();

    // ---- OLA (even sample = re, odd = -im)
    const float* specf = (const float*)spec;
    for (int j = tid; j < TLEN; j += 256) {
        int p = j + HOP;
        int t1 = p >> 8, t0 = t1 - 1;
        int i1 = p & 255, i0 = i1 + 256;
        int comp = j & 1;
        float v1 = specf[(t1 * 256 + SWZ(i1 >> 1)) * 2 + comp];
        float v0 = specf[(t0 * 256 + SWZ(i0 >> 1)) * 2 + comp];
        if (comp) { v1 = -v1; v0 = -v0; }
        float s = v0 * win[i0] + v1 * win[i1];
        xrow[j] = s * rnorm[i1];
    }
}

// ------------------------------- addnorm body: LN1 -> split-bf16 MFMA MLP -> LN2
// ROUND-8 VERBATIM (known-good; r9's srcB-fold into LN1 regressed: global
// loads landed on the LN1 critical path between barriers).
#define XLNS 132

__device__ __forceinline__ void mlp_gemm(const float* __restrict__ ax,
                                         const unsigned short* __restrict__ wf,
                                         int lane, f32x4 acc[8]) {
#pragma unroll
    for (int n = 0; n < 8; ++n) acc[n] = (f32x4){0.f, 0.f, 0.f, 0.f};
    const bf16x8* bh0 = (const bf16x8*)wf;
    const bf16x8* bl0 = (const bf16x8*)(wf + 16384);
#pragma unroll 1
    for (int kt = 0; kt < 4; ++kt) {
        float4 va = *(const float4*)(ax + kt * 32);
        float4 vb = *(const float4*)(ax + kt * 32 + 4);
        bf16x8 ahi, alo;
        split8(va, vb, ahi, alo);
        const bf16x8* bh = bh0 + kt * 512 + lane;
        const bf16x8* bl = bl0 + kt * 512 + lane;
#pragma unroll
        for (int n = 0; n < 8; ++n) {
            bf16x8 wh = bh[n * 64];
            bf16x8 wl = bl[n * 64];
            acc[n] = __builtin_amdgcn_mfma_f32_16x16x32_bf16(ahi, wh, acc[n], 0, 0, 0);
            acc[n] = __builtin_amdgcn_mfma_f32_16x16x32_bf16(alo, wh, acc[n], 0, 0, 0);
            acc[n] = __builtin_amdgcn_mfma_f32_16x16x32_bf16(ahi, wl, acc[n], 0, 0, 0);
        }
    }
}

template <int FUSED>
__device__ __forceinline__ void addnorm_body(
    int bid, float* xln,
    const float* __restrict__ srcA, const float* __restrict__ srcB,
    const float* __restrict__ ln1g, const float* __restrict__ ln1b,
    const unsigned short* __restrict__ w1f, const float* __restrict__ b1,
    const unsigned short* __restrict__ w2f, const float* __restrict__ b2,
    const float* __restrict__ ln2g, const float* __restrict__ ln2b,
    float* __restrict__ out) {
    int tid = threadIdx.x;
    int b = 0, t0 = 0;
    size_t R0 = 0;
    // ---- Phase A: build x0
    if (FUSED) {
        b = bid >> 6;
        t0 = (bid & 63) * 64;
        for (int i = tid; i < 64 * 128; i += 256) {
            int dd = i >> 6, r = i & 63;
            xln[r * XLNS + dd] = srcA[((size_t)b * DD + dd) * TLEN + t0 + r];
        }
        __syncthreads();
        for (int i = tid; i < 64 * 128; i += 256) {
            int r = i >> 7, dd = i & 127;
            xln[r * XLNS + dd] += srcB[((size_t)b * TLEN + t0 + r) * DD + dd];
        }
    } else {
        R0 = (size_t)bid * 64;
        for (int i = tid; i < 64 * 128; i += 256) {
            int r = i >> 7, dd = i & 127;
            xln[r * XLNS + dd] = srcA[(R0 + r) * DD + dd];
        }
    }
    __syncthreads();
    // ---- LN1 (wave per row)
    int wave = tid >> 6, lane = tid & 63;
    for (int r = wave; r < 64; r += 4) {
        float v0 = xln[r * XLNS + lane];
        float v1 = xln[r * XLNS + 64 + lane];
        float s = v0 + v1, ss = v0 * v0 + v1 * v1;
        for (int off = 32; off > 0; off >>= 1) {
            s += __shfl_xor(s, off);
            ss += __shfl_xor(ss, off);
        }
        float mean = s * (1.0f / 128.0f);
        float var = ss * (1.0f / 128.0f) - mean * mean;
        float rstd = rsqrtf(var + 1e-5f);
        xln[r * XLNS + lane] = (v0 - mean) * rstd * ln1g[lane] + ln1b[lane];
        xln[r * XLNS + 64 + lane] = (v1 - mean) * rstd * ln1g[64 + lane] + ln1b[64 + lane];
    }
    __syncthreads();
    // ---- fragment coordinates
    int q = lane >> 4, c = lane & 15;
    int rbase = wave * 16 + q * 4;                          // C-frag rows (4)
    const float* ax = &xln[(wave * 16 + c) * XLNS + q * 8]; // A-frag base
    // ---- GEMM1: acc = x @ w1
    f32x4 acc[8];
    mlp_gemm(ax, w1f, lane, acc);
    // ---- residual (post-LN1 x) at this thread's C positions
    float res[8][4];
#pragma unroll
    for (int n = 0; n < 8; ++n)
#pragma unroll
        for (int r = 0; r < 4; ++r)
            res[n][r] = xln[(rbase + r) * XLNS + n * 16 + c];
    // ---- bias + gelu
#pragma unroll
    for (int n = 0; n < 8; ++n) {
        float bb = b1[n * 16 + c];
#pragma unroll
        for (int r = 0; r < 4; ++r)
            acc[n][r] = gelu_exact(acc[n][r] + bb);
    }
    __syncthreads();   // all reads of xln(=x) done
#pragma unroll
    for (int n = 0; n < 8; ++n)
#pragma unroll
        for (int r = 0; r < 4; ++r)
            xln[(rbase + r) * XLNS + n * 16 + c] = acc[n][r];   // xln := g
    __syncthreads();
    // ---- GEMM2: acc = g @ w2; h = acc + b2 + res
    mlp_gemm(ax, w2f, lane, acc);
#pragma unroll
    for (int n = 0; n < 8; ++n) {
        float bb = b2[n * 16 + c];
#pragma unroll
        for (int r = 0; r < 4; ++r)
            acc[n][r] += bb + res[n][r];
    }
    // ---- LN2 stats: rows live in 16-lane groups (cols spread over c and n)
    float s4[4] = {0.f, 0.f, 0.f, 0.f}, ss4[4] = {0.f, 0.f, 0.f, 0.f};
#pragma unroll
    for (int n = 0; n < 8; ++n)
#pragma unroll
        for (int r = 0; r < 4; ++r) {
            float h = acc[n][r];
            s4[r] += h; ss4[r] += h * h;
        }
#pragma unroll
    for (int off = 8; off > 0; off >>= 1) {
#pragma unroll
        for (int r = 0; r < 4; ++r) {
            s4[r] += __shfl_xor(s4[r], off);
            ss4[r] += __shfl_xor(ss4[r], off);
        }
    }
    float g2v[8], b2v[8];
#pragma unroll
    for (int n = 0; n < 8; ++n) {
        g2v[n] = ln2g[n * 16 + c];
        b2v[n] = ln2b[n * 16 + c];
    }
#pragma unroll
    for (int r = 0; r < 4; ++r) {
        float mean = s4[r] * (1.0f / 128.0f);
        float var = ss4[r] * (1.0f / 128.0f) - mean * mean;
        float rstd = rsqrtf(var + 1e-5f);
        size_t orow = FUSED ? ((size_t)b * TLEN + t0 + rbase + r) * DD
                            : (R0 + rbase + r) * DD;
#pragma unroll
        for (int n = 0; n < 8; ++n)
            out[orow + n * 16 + c] = (acc[n][r] - mean) * rstd * g2v[n] + b2v[n];
    }
}

// =============== fused2: img_irfft FIRST (blocks 0..447: long-latency blocks
// start at t=0 and hide under addnorm), then addnorm<1> (448..2495).
#define F2_IR  (BB * 14)            // 448
#define F2_AN  (BB * (TLEN / 64))   // 2048

__global__ __launch_bounds__(256) void fused_text_img(
    const float* __restrict__ srcA, const float* __restrict__ ecg,
    const float* __restrict__ ln1g, const float* __restrict__ ln1b,
    const unsigned short* __restrict__ w1f, const float* __restrict__ b1,
    const unsigned short* __restrict__ w2f, const float* __restrict__ b2,
    const float* __restrict__ ln2g, const float* __restrict__ ln2b,
    float* __restrict__ out,
    const float* __restrict__ zi, const float* __restrict__ image,
    float* __restrict__ x0img) {
    __shared__ __align__(16) float xln[64 * XLNS];
    int bid = blockIdx.x;
    int tid = threadIdx.x;
    if (bid >= F2_IR) {
        addnorm_body<1>(bid - F2_IR, xln, srcA, ecg, ln1g, ln1b, w1f, b1,
                        w2f, b2, ln2g, ln2b, out);
    } else {
        // ---------------- img_irfft (ortho) + add image (LDS reuses xln)
        int rel = bid;
        float* ctab = xln;          // [196]
        float* stab = xln + 200;    // [196]
        int b = rel / 14;
        int ng = rel % 14;
        for (int m = tid; m < NPATCH; m += 256) {
            ctab[m] = cospif(m * (2.0f / 196.0f));
            stab[m] = sinpif(m * (2.0f / 196.0f));
        }
        __syncthreads();
        if (tid < 128) {
            int d = tid;
            const float2* zrow = (const float2*)zi + (size_t)b * NFREQ * DD + d;
            float acc[14];
            int mc[14];
            float2 z0 = zrow[0];
#pragma unroll
            for (int j = 0; j < 14; ++j) { acc[j] = z0.x; mc[j] = 0; }
            for (int f = 1; f <= 97; ++f) {
                float2 z = zrow[(size_t)f * DD];
#pragma unroll
                for (int j = 0; j < 14; ++j) {
                    int n = ng * 14 + j;
                    mc[j] += n;
                    if (mc[j] >= NPATCH) mc[j] -= NPATCH;
                    acc[j] += 2.0f * (z.x * ctab[mc[j]] - z.y * stab[mc[j]]);
                }
            }
            float2 z98 = zrow[98 * (size_t)DD];
#pragma unroll
            for (int j = 0; j < 14; ++j) {
                int n = ng * 14 + j;
                float a = acc[j] + ((n & 1) ? -z98.x : z98.x);
                float y = a * (1.0f / 14.0f);
                size_t idx = ((size_t)b * NPATCH + n) * DD + d;
                x0img[idx] = y + image[idx];
            }
        }
    }
}

// non-fused addnorm (image branch, runs last)
__global__ __launch_bounds__(256) void addnorm_img(
    const float* __restrict__ srcA,
    const float* __restrict__ ln1g, const float* __restrict__ ln1b,
    const unsigned short* __restrict__ w1f, const float* __restrict__ b1,
    const unsigned short* __restrict__ w2f, const float* __restrict__ b2,
    const float* __restrict__ ln2g, const float* __restrict__ ln2b,
    float* __restrict__ out) {
    __shared__ __align__(16) float xln[64 * XLNS];
    addnorm_body<0>(blockIdx.x, xln, srcA, nullptr, ln1g, ln1b, w1f, b1,
                    w2f, b2, ln2g, ln2b, out);
}

extern "C" void kernel_launch(void* const* d_in, const int* in_sizes, int n_in,
                              void* d_out, int out_size, void* d_ws, size_t ws_size,
                              hipStream_t stream) {
    (void)in_sizes; (void)n_in; (void)out_size; (void)ws_size;
    const float* ecg   = (const float*)d_in[0];
    const float* image = (const float*)d_in[1];
    const float* tfb   = (const float*)d_in[2];
    const float* ifb   = (const float*)d_in[3];
    const float* sel   = (const float*)d_in[4];
    const float* i2t_w = (const float*)d_in[5];
    const float* i2t_b = (const float*)d_in[6];
    const float* t_ln1_g = (const float*)d_in[7];
    const float* t_ln1_b = (const float*)d_in[8];
    const float* t_w1 = (const float*)d_in[9];
    const float* t_b1 = (const float*)d_in[10];
    const float* t_w2 = (const float*)d_in[11];
    const float* t_b2 = (const float*)d_in[12];
    const float* t_ln2_g = (const float*)d_in[13];
    const float* t_ln2_b = (const float*)d_in[14];
    const float* i_ln1_g = (const float*)d_in[15];
    const float* i_ln1_b = (const float*)d_in[16];
    const float* i_w1 = (const float*)d_in[17];
    const float* i_b1 = (const float*)d_in[18];
    const float* i_w2 = (const float*)d_in[19];
    const float* i_b2 = (const float*)d_in[20];
    const float* i_ln2_g = (const float*)d_in[21];
    const float* i_ln2_b = (const float*)d_in[22];
    float* out = (float*)d_out;
    float* ws = (float*)d_ws;
    unsigned short* wfb = (unsigned short*)(ws + WF_OFF);
    float* gpart = ws + X0I_OFF;   // scratch: free until img_irfft writes x0img

    // launch 1: all independent prep work (img_dft | wfrag | prep_fb | transpose)
    prep_all<<<PA_TOT, 256, 0, stream>>>(
        t_w1, t_w2, i_w1, i_w2, wfb,
        tfb, ws + FBT2_OFF,
        ecg, ws + XT_OFF,
        image, ifb, sel, ws + ZI_OFF, gpart);
    // launch 2: gate (sums img_dft partials)
    gate_kernel<<<BB, 128, 0, stream>>>(gpart, i2t_w, i2t_b, ws + GATE_OFF);
    // launch 3: stft -> filter -> istft
    stft_filter_istft<<<BB * DD, 256, 0, stream>>>(ws + XT_OFF, ws + FBT2_OFF, ws + GATE_OFF);
    // launch 4: image irfft (first, latency-bound) | text addnorm
    fused_text_img<<<F2_IR + F2_AN, 256, 0, stream>>>(
        ws + XT_OFF, ecg, t_ln1_g, t_ln1_b, wfb + 0, t_b1, wfb + 32768, t_b2,
        t_ln2_g, t_ln2_b, out,
        ws + ZI_OFF, image, ws + X0I_OFF);
    // launch 5: image addnorm
    addnorm_img<<<(BB * NPATCH) / 64, 256, 0, stream>>>(
        ws + X0I_OFF, i_ln1_g, i_ln1_b, wfb + 65536, i_b1, wfb + 98304, i_b2,
        i_ln2_g, i_ln2_b, out + (size_t)BB * TLEN * DD);
}

// Round 11
// 536.564 us; speedup vs baseline: 1.1329x; 1.0175x over previous
//
#include <hip/hip_runtime.h>
#include <math.h>

#define BB 32
#define DD 128
#define TLEN 4096
#define NSEG 512
#define HOP 256
#define NFR 17
#define NBINS 257
#define STOT 4369
#define NPATCH 196
#define NFREQ 99
#define OLAL 4608

// workspace layout (float offsets)
#define FBT2_OFF 0
#define FBT2_SZ  (DD * NFR * NBINS * 2)       // 1,118,464
#define GBUF_OFF (FBT2_OFF + FBT2_SZ)
#define GATE_OFF (GBUF_OFF + BB * DD)
#define ZI_OFF   (GATE_OFF + BB * DD)
#define ZI_SZ    (BB * NFREQ * DD * 2)        // 811,008
#define X0I_OFF  (ZI_OFF + ZI_SZ)             // reused: gpart (launch1-2), x0img (launch3-4)
#define X0I_SZ   (BB * NPATCH * DD)           // 802,816
#define XT_OFF   (X0I_OFF + X0I_SZ)
#define WF_OFF   (XT_OFF + BB * DD * TLEN)    // bf16 hi/lo weight fragments (4 mats x 32768 ushort)

typedef __attribute__((ext_vector_type(8))) short bf16x8;
typedef __attribute__((ext_vector_type(4))) float f32x4;
typedef __attribute__((ext_vector_type(8))) unsigned short u16x8;

__device__ __forceinline__ float gelu_exact(float x) {
    return 0.5f * x * (1.0f + erff(x * 0.70710678118654752f));
}

__device__ __forceinline__ short bf16_rne(float v) {
    unsigned b = __float_as_uint(v);
    return (short)((b + 0x7fffu + ((b >> 16) & 1u)) >> 16);
}

// split fp32 -> bf16 hi + bf16 lo (v ~= hi + lo, error ~2^-17 relative)
__device__ __forceinline__ void split8(float4 a, float4 b, bf16x8& hi, bf16x8& lo) {
    float v[8] = {a.x, a.y, a.z, a.w, b.x, b.y, b.z, b.w};
#pragma unroll
    for (int e = 0; e < 8; ++e) {
        unsigned bv = __float_as_uint(v[e]);
        unsigned hb = (bv + 0x7fffu + ((bv >> 16) & 1u)) & 0xffff0000u;
        float hf = __uint_as_float(hb);
        hi[e] = (short)(hb >> 16);
        lo[e] = bf16_rne(v[e] - hf);
    }
}

// =============== merged prep kernel: img_dft | prep_wfrag | prep_fb | transpose
#define PA_DFT0   0
#define PA_DFTN   (BB * 11)                     // 352
#define PA_WF0    (PA_DFT0 + PA_DFTN)           // 352
#define PA_WFN    32
#define PA_FB0    (PA_WF0 + PA_WFN)             // 384
#define PA_FBN    ((STOT * DD + 255) / 256)     // 2185
#define PA_TR0    (PA_FB0 + PA_FBN)             // 2569
#define PA_TRN    ((TLEN / 32) * (DD / 32) * BB) // 16384
#define PA_TOT    (PA_TR0 + PA_TRN)             // 18953

__global__ __launch_bounds__(256) void prep_all(
    const float* __restrict__ tw1, const float* __restrict__ tw2,
    const float* __restrict__ iw1, const float* __restrict__ iw2,
    unsigned short* __restrict__ outw,
    const float* __restrict__ tfb, float* __restrict__ fbt2,
    const float* __restrict__ ecg, float* __restrict__ xT,
    const float* __restrict__ image, const float* __restrict__ ifb,
    const float* __restrict__ sel, float* __restrict__ zi,
    float* __restrict__ gpart) {
    __shared__ float smem[32 * 33];   // transpose tile / img_dft trig tables
    int bid = blockIdx.x;
    int tid = threadIdx.x;

    if (bid < PA_DFTN) {
        // ---------------- img_dft: rfft(ortho) + filter; partial g to gpart
        float* ctab = smem;           // [196]
        float* stab = smem + 200;     // [196]
        int b = bid / 11;
        int fg = bid % 11;
        for (int m = tid; m < NPATCH; m += 256) {
            ctab[m] = cospif(m * (2.0f / 196.0f));
            stab[m] = sinpif(m * (2.0f / 196.0f));
        }
        __syncthreads();
        if (tid < 128) {
            int d = tid;
            float accr[9], acci[9];
            int mc[9];
#pragma unroll
            for (int j = 0; j < 9; ++j) { accr[j] = 0.0f; acci[j] = 0.0f; mc[j] = 0; }
            const float* img = image + (size_t)b * NPATCH * DD + d;
            for (int n = 0; n < NPATCH; ++n) {
                float v = img[(size_t)n * DD];
#pragma unroll
                for (int j = 0; j < 9; ++j) {
                    float c = ctab[mc[j]], s = stab[mc[j]];
                    accr[j] += v * c;
                    acci[j] -= v * s;
                    mc[j] += fg * 9 + j;
                    if (mc[j] >= NPATCH) mc[j] -= NPATCH;
                }
            }
            float gg = 0.0f;
#pragma unroll
            for (int j = 0; j < 9; ++j) {
                int f = fg * 9 + j;
                float Xr = accr[j] * (1.0f / 14.0f);
                float Xi = acci[j] * (1.0f / 14.0f);
                float sr = (Xr * Xr - Xi * Xi) * (1.0f / 99.0f);
                float si = 2.0f * Xr * Xi * (1.0f / 99.0f);
                float2 f0 = ((const float2*)ifb)[f * DD + d];
                float2 f1 = ((const float2*)ifb)[NFREQ * DD + f * DD + d];
                float fbr = -(f0.x + f1.x), fbi = -(f0.y + f1.y);
                float zr = sr * fbr - si * fbi;
                float zm = sr * fbi + si * fbr;
                float2 o; o.x = zr; o.y = zm;
                ((float2*)zi)[((size_t)b * NFREQ + f) * DD + d] = o;
                float2 sl = ((const float2*)sel)[f * DD + d];
                gg += zr * sl.x - zm * sl.y;
            }
            gpart[((size_t)fg * BB + b) * DD + d] = gg * (1.0f / 99.0f);
        }
    } else if (bid < PA_FB0) {
        // ---------------- prep_wfrag
        int id = (bid - PA_WF0) * 256 + tid;
        if (id < 4 * 2048) {
            int m = id >> 11;
            int r = id & 2047;
            int kt = r >> 9;
            int n = (r >> 6) & 7;
            int lane = r & 63;
            int k0 = kt * 32 + (lane >> 4) * 8;
            int col = n * 16 + (lane & 15);
            const float* w = (m == 0) ? tw1 : (m == 1) ? tw2 : (m == 2) ? iw1 : iw2;
            u16x8 hi, lo;
#pragma unroll
            for (int e = 0; e < 8; ++e) {
                float v = w[(size_t)(k0 + e) * DD + col];
                unsigned bv = __float_as_uint(v);
                unsigned hb = (bv + 0x7fffu + ((bv >> 16) & 1u)) & 0xffff0000u;
                float hf = __uint_as_float(hb);
                float lres = v - hf;
                unsigned bl = __float_as_uint(lres);
                hi[e] = (unsigned short)(hb >> 16);
                lo[e] = (unsigned short)((bl + 0x7fffu + ((bl >> 16) & 1u)) >> 16);
            }
            u16x8* base = (u16x8*)(outw + (size_t)m * 32768);
            base[r] = hi;
            base[2048 + r] = lo;
        }
    } else if (bid < PA_TR0) {
        // ---------------- prep_fb: tfb -> fbt2 (D,17,257,2)
        int idx = (bid - PA_FB0) * 256 + tid;
        if (idx < STOT * DD) {
            int d = idx & 127;
            int s = idx >> 7;
            float2 a = ((const float2*)tfb)[s * DD + d];
            float2 b2 = ((const float2*)tfb)[STOT * DD + s * DD + d];
            int f = s / NFR, t = s % NFR;
            float2 r;
            r.x = -(a.x + b2.x);
            r.y = -(a.y + b2.y);
            ((float2*)fbt2)[((size_t)d * NFR + t) * NBINS + f] = r;
        }
    } else {
        // ---------------- transpose ecg (B,T,D) -> (B,D,T)
        int rel = bid - PA_TR0;
        int t0 = (rel & 127) * 32;
        int d0 = ((rel >> 7) & 3) * 32;
        int b = rel >> 9;
        int lx = tid & 31;
        int ly = tid >> 5;   // 0..7
        float (*tile)[33] = (float (*)[33])smem;
        for (int i = ly; i < 32; i += 8)
            tile[i][lx] = ecg[((size_t)b * TLEN + t0 + i) * DD + d0 + lx];
        __syncthreads();
        for (int i = ly; i < 32; i += 8)
            xT[((size_t)b * DD + d0 + i) * TLEN + t0 + lx] = tile[lx][i];
    }
}

// ------------------------- per-(b,d): STFT -> filter*gate -> ISTFT, in-place
// Register-resident 256-pt complex FFT per wave. Fused middle phase.
// GATE FUSED: lanes<128 compute tmp[l]=(sum_fg gpart)*w[d,l] in the prologue;
// wave 0 tree-reduces during the forward phase; the post-forward barrier
// publishes gatsh before the middle phase reads it. Removes gate_kernel launch.
#define SWZ(e) ((e) ^ (((e) >> 4) & 15))

#define CMULW(dr, di, c, s, xr, xi) { float _t = (dr)*(c) - (di)*(s); xi = (dr)*(s) + (di)*(c); xr = _t; }
#define BF(xr, xi, h) { \
    float pr_ = __shfl_xor(xr, h), pi_ = __shfl_xor(xi, h); \
    float dr2_ = fmaf(sg##h, xr, pr_), di2_ = fmaf(sg##h, xi, pi_); \
    CMULW(dr2_, di2_, tc##h, ts##h, xr, xi) }
#define SSTG(h) BF(a0r, a0i, h) BF(a1r, a1i, h) BF(a2r, a2i, h) BF(a3r, a3i, h)
#define BF1(xr, xi) { \
    float pr_ = __shfl_xor(xr, 1), pi_ = __shfl_xor(xi, 1); \
    xr = fmaf(sg1, xr, pr_); xi = fmaf(sg1, xi, pi_); }
#define DIF256() { \
    float dr_, di_; \
    dr_ = a0r - a2r; di_ = a0i - a2i; a0r += a2r; a0i += a2i; CMULW(dr_, di_, wa_c, wa_s, a2r, a2i) \
    dr_ = a1r - a3r; di_ = a1i - a3i; a1r += a3r; a1i += a3i; CMULW(dr_, di_, wb_c, wb_s, a3r, a3i) \
    dr_ = a0r - a1r; di_ = a0i - a1i; a0r += a1r; a0i += a1i; CMULW(dr_, di_, wc_c, wc_s, a1r, a1i) \
    dr_ = a2r - a3r; di_ = a2i - a3i; a2r += a3r; a2i += a3i; CMULW(dr_, di_, wc_c, wc_s, a3r, a3i) \
    SSTG(32) SSTG(16) SSTG(8) SSTG(4) SSTG(2) \
    BF1(a0r, a0i) BF1(a1r, a1i) BF1(a2r, a2i) BF1(a3r, a3i) }

__global__ __launch_bounds__(256, 4) void stft_filter_istft(
    float* xT, const float* __restrict__ fbt2,
    const float* __restrict__ gpart, const float* __restrict__ i2t_w,
    const float* __restrict__ i2t_b) {
    __shared__ float2 spec[NFR * 256];   // 34816 B
    __shared__ float win[NSEG];          // 2048 B
    __shared__ float rnorm[256];         // 1024 B
    __shared__ float mct[129], mst[129]; // 1032 B middle-phase trig
    __shared__ float gtmp[DD];           // 512 B gate partials
    __shared__ float gatsh;
    int tid = threadIdx.x;
    int lane = tid & 63, wave = tid >> 6;
    int bd = blockIdx.x;              // b*128 + d
    int d = bd & 127;
    int b = bd >> 7;
    float* xrow = xT + (size_t)bd * TLEN;
    const float2* fbrow = (const float2*)(fbt2 + (size_t)d * NFR * NBINS * 2);
    float ib = i2t_b[d];

    for (int j = tid; j < NSEG; j += 256)
        win[j] = 0.5f - 0.5f * cospif(j * (1.0f / 256.0f));   // sin^2(pi j/512)
    {
        float s2 = 0.5f - 0.5f * cospif(tid * (1.0f / 256.0f));
        float c2 = 1.0f - s2;
        rnorm[tid] = 1.0f / (s2 * s2 + c2 * c2);
    }
    if (tid < 129) {
        mct[tid] = cospif(tid * (1.0f / 256.0f));
        mst[tid] = sinpif(tid * (1.0f / 256.0f));
    }
    if (tid < 128) {
        float s = 0.0f;
#pragma unroll
        for (int fg = 0; fg < 11; ++fg)
            s += gpart[((size_t)fg * BB + b) * DD + tid];
        gtmp[tid] = s * i2t_w[(size_t)d * DD + tid];
    }

    // ---- hoisted twiddles (W = e^{-2pi i k/256}; ts holds -sin)
    float wa_c = cospif(lane * (1.0f / 128.0f)), wa_s = -sinpif(lane * (1.0f / 128.0f));
    float wb_c = cospif((64 + lane) * (1.0f / 128.0f)), wb_s = -sinpif((64 + lane) * (1.0f / 128.0f));
    float wc_c = cospif(lane * (1.0f / 64.0f)),  wc_s = -sinpif(lane * (1.0f / 64.0f));
#define MKT(h) \
    float tc##h, ts##h, sg##h; \
    { int set_ = lane & h; float ang_ = (float)(lane & (h - 1)) * (1.0f / h); \
      tc##h = set_ ? cospif(ang_) : 1.0f; \
      ts##h = set_ ? -sinpif(ang_) : 0.0f; \
      sg##h = set_ ? -1.0f : 1.0f; }
    MKT(32) MKT(16) MKT(8) MKT(4) MKT(2)
    float sg1 = (lane & 1) ? -1.0f : 1.0f;
#undef MKT

    // scatter (bitrev) and gather (natural) element addresses, swizzled
    int eS[4], eL[4];
#pragma unroll
    for (int j = 0; j < 4; ++j) {
        int i = j * 64 + lane;
        eS[j] = SWZ((int)(__brev((unsigned)i) >> 24));
        eL[j] = SWZ(i);
    }
    __syncthreads();

    // gate reduce (wave 0 only; published by the post-forward barrier)
    if (tid < 64) {
        float v = gtmp[tid] + gtmp[tid + 64];
        for (int off = 32; off > 0; off >>= 1) v += __shfl_xor(v, off);
        if (tid == 0) gatsh = ib + v;
    }

    // ---- forward: load+window -> DIF -> scatter spectrum (natural order)
    for (int t = wave; t < NFR; t += 4) {
        float a0r, a0i, a1r, a1i, a2r, a2i, a3r, a3i;
#define LOADJ(j, xr, xi) { \
        int i_ = (j) * 64 + lane; \
        int src_ = t * HOP + 2 * i_ - HOP; \
        float er_ = 0.0f, oi_ = 0.0f; \
        if (src_ >= 0 && src_ < TLEN) { \
            float2 v_ = *(const float2*)(xrow + src_); er_ = v_.x; oi_ = v_.y; } \
        float2 w_ = *(const float2*)(win + 2 * i_); \
        xr = er_ * w_.x; xi = oi_ * w_.y; }
        LOADJ(0, a0r, a0i) LOADJ(1, a1r, a1i) LOADJ(2, a2r, a2i) LOADJ(3, a3r, a3i)
#undef LOADJ
        DIF256()
        float2* sp = spec + t * 256;
        sp[eS[0]] = make_float2(a0r, a0i);
        sp[eS[1]] = make_float2(a1r, a1i);
        sp[eS[2]] = make_float2(a2r, a2i);
        sp[eS[3]] = make_float2(a3r, a3i);
    }
    __syncthreads();

    const float scl = gatsh * (1.0f / 4369.0f);

    // ---- middle (fused): rfft unpack -> square -> filter*gate -> conj repack
    for (int j = tid; j < NFR * 129; j += 256) {
        int t = j / 129, m = j - t * 129;
        float2* sp = spec + t * 256;
        const float2* fbr = fbrow + t * NBINS;
        if (m == 0) {
            float2 v = sp[0];
            float re = v.x, im = v.y;
            float z0 = (re + im) * (1.0f / 256.0f);
            float zN = (re - im) * (1.0f / 256.0f);
            float2 fb0 = fbr[0], fbN = fbr[256];
            float y1r = z0 * z0 * fb0.x * scl;
            float y2r = zN * zN * fbN.x * scl;
            float Er = 0.5f * (y1r + y2r);
            float Dr = 0.5f * (y1r - y2r);
            sp[0] = make_float2(Er, -Dr);
        } else if (m == 128) {
            float2 v = sp[SWZ(128)];
            float Zr = v.x, Zi = v.y;
            float zr = Zr * (1.0f / 256.0f), zi2 = -Zi * (1.0f / 256.0f);
            float sr = zr * zr - zi2 * zi2, si = 2.0f * zr * zi2;
            float2 fb = fbr[128];
            sp[SWZ(128)] = make_float2((sr * fb.x - si * fb.y) * scl,
                                       (sr * fb.y + si * fb.x) * scl);
        } else {
            float2 vm = sp[SWZ(m)];
            float2 vc = sp[SWZ(256 - m)];
            float Amr = vm.x, Ami = vm.y;
            float Acr = vc.x, Aci = vc.y;
            float c = mct[m];
            float sn = mst[m];
            float y1r, y1i, y2r, y2i;
            {
                float Br = Acr, Bi = -Aci;
                float xer = 0.5f * (Amr + Br), xei = 0.5f * (Ami + Bi);
                float xo_r = 0.5f * (Ami - Bi), xo_i = -0.5f * (Amr - Br);
                float Xr = xer + c * xo_r + sn * xo_i;
                float Xi = xei + c * xo_i - sn * xo_r;
                float zr = Xr * (1.0f / 256.0f), zi2 = Xi * (1.0f / 256.0f);
                float sr = zr * zr - zi2 * zi2, si = 2.0f * zr * zi2;
                float2 fb = fbr[m];
                y1r = (sr * fb.x - si * fb.y) * scl;
                y1i = (sr * fb.y + si * fb.x) * scl;
            }
            {
                float Br = Amr, Bi = -Ami;
                float xer = 0.5f * (Acr + Br), xei = 0.5f * (Aci + Bi);
                float xo_r = 0.5f * (Aci - Bi), xo_i = -0.5f * (Acr - Br);
                float Xr = xer - c * xo_r + sn * xo_i;
                float Xi = xei - c * xo_i - sn * xo_r;
                float zr = Xr * (1.0f / 256.0f), zi2 = Xi * (1.0f / 256.0f);
                float sr = zr * zr - zi2 * zi2, si = 2.0f * zr * zi2;
                float2 fb = fbr[256 - m];
                y2r = (sr * fb.x - si * fb.y) * scl;
                y2i = (sr * fb.y + si * fb.x) * scl;
            }
            float Er = 0.5f * (y1r + y2r);
            float Ei = 0.5f * (y1i - y2i);
            float Dr = 0.5f * (y1r - y2r);
            float Di = 0.5f * (y1i + y2i);
            float Or = Dr * c - Di * sn;
            float Oi = Dr * sn + Di * c;
            sp[SWZ(m)] = make_float2(Er - Oi, -(Ei + Or));
            sp[SWZ(256 - m)] = make_float2(Er + Oi, Ei - Or);
        }
    }
    __syncthreads();

    // ---- inverse: gather conj(B) natural -> same DIF -> scatter time domain
    for (int t = wave; t < NFR; t += 4) {
        float2* sp = spec + t * 256;
        float2 v0 = sp[eL[0]], v1 = sp[eL[1]], v2 = sp[eL[2]], v3 = sp[eL[3]];
        float a0r = v0.x, a0i = v0.y, a1r = v1.x, a1i = v1.y;
        float a2r = v2.x, a2i = v2.y, a3r = v3.x, a3i = v3.y;
        DIF256()
        sp[eS[0]] = make_float2(a0r, a0i);
        sp[eS[1]] = make_float2(a1r, a1i);
        sp[eS[2]] = make_float2(a2r, a2i);
        sp[eS[3]] = make_float2(a3r, a3i);
    }
    __syncthreads();

    // ---- OLA (even sample = re, odd = -im)
    const float* specf = (const float*)spec;
    for (int j = tid; j < TLEN; j += 256) {
        int p = j + HOP;
        int t1 = p >> 8, t0 = t1 - 1;
        int i1 = p & 255, i0 = i1 + 256;
        int comp = j & 1;
        float v1 = specf[(t1 * 256 + SWZ(i1 >> 1)) * 2 + comp];
        float v0 = specf[(t0 * 256 + SWZ(i0 >> 1)) * 2 + comp];
        if (comp) { v1 = -v1; v0 = -v0; }
        float s = v0 * win[i0] + v1 * win[i1];
        xrow[j] = s * rnorm[i1];
    }
}

// ------------------------------- addnorm body: LN1 -> split-bf16 MFMA MLP -> LN2
// r8 structure; Phase A change: srcB prefetched into registers at kernel entry
// (8 coalesced float4 loads), added to LDS AFTER the srcA barrier -- HBM latency
// hides under the srcA scatter instead of sitting between barriers (r9 lesson).
#define XLNS 132

__device__ __forceinline__ void mlp_gemm(const float* __restrict__ ax,
                                         const unsigned short* __restrict__ wf,
                                         int lane, f32x4 acc[8]) {
#pragma unroll
    for (int n = 0; n < 8; ++n) acc[n] = (f32x4){0.f, 0.f, 0.f, 0.f};
    const bf16x8* bh0 = (const bf16x8*)wf;
    const bf16x8* bl0 = (const bf16x8*)(wf + 16384);
#pragma unroll 1
    for (int kt = 0; kt < 4; ++kt) {
        float4 va = *(const float4*)(ax + kt * 32);
        float4 vb = *(const float4*)(ax + kt * 32 + 4);
        bf16x8 ahi, alo;
        split8(va, vb, ahi, alo);
        const bf16x8* bh = bh0 + kt * 512 + lane;
        const bf16x8* bl = bl0 + kt * 512 + lane;
#pragma unroll
        for (int n = 0; n < 8; ++n) {
            bf16x8 wh = bh[n * 64];
            bf16x8 wl = bl[n * 64];
            acc[n] = __builtin_amdgcn_mfma_f32_16x16x32_bf16(ahi, wh, acc[n], 0, 0, 0);
            acc[n] = __builtin_amdgcn_mfma_f32_16x16x32_bf16(alo, wh, acc[n], 0, 0, 0);
            acc[n] = __builtin_amdgcn_mfma_f32_16x16x32_bf16(ahi, wl, acc[n], 0, 0, 0);
        }
    }
}

template <int FUSED>
__device__ __forceinline__ void addnorm_body(
    int bid, float* xln,
    const float* __restrict__ srcA, const float* __restrict__ srcB,
    const float* __restrict__ ln1g, const float* __restrict__ ln1b,
    const unsigned short* __restrict__ w1f, const float* __restrict__ b1,
    const unsigned short* __restrict__ w2f, const float* __restrict__ b2,
    const float* __restrict__ ln2g, const float* __restrict__ ln2b,
    float* __restrict__ out) {
    int tid = threadIdx.x;
    int b = 0, t0 = 0;
    size_t R0 = 0;
    // ---- Phase A: build x0
    if (FUSED) {
        b = bid >> 6;
        t0 = (bid & 63) * 64;
        // prefetch srcB (row-major, coalesced float4) into registers
        float4 rb[8];
        const float4* pB4 = (const float4*)(srcB + ((size_t)b * TLEN + t0) * DD);
#pragma unroll
        for (int k = 0; k < 8; ++k) rb[k] = pB4[tid + 256 * k];
        // srcA (B,D,T) transpose-scatter into LDS
        for (int i = tid; i < 64 * 128; i += 256) {
            int dd = i >> 6, r = i & 63;
            xln[r * XLNS + dd] = srcA[((size_t)b * DD + dd) * TLEN + t0 + r];
        }
        __syncthreads();
        // add prefetched srcB (vector LDS RMW)
#pragma unroll
        for (int k = 0; k < 8; ++k) {
            int idx4 = tid + 256 * k;
            int r = idx4 >> 5, c4 = idx4 & 31;
            float4* p = (float4*)&xln[r * XLNS + c4 * 4];
            float4 x = *p;
            x.x += rb[k].x; x.y += rb[k].y; x.z += rb[k].z; x.w += rb[k].w;
            *p = x;
        }
    } else {
        R0 = (size_t)bid * 64;
        const float4* pA4 = (const float4*)(srcA + R0 * DD);
#pragma unroll
        for (int k = 0; k < 8; ++k) {
            int idx4 = tid + 256 * k;
            int r = idx4 >> 5, c4 = idx4 & 31;
            *(float4*)&xln[r * XLNS + c4 * 4] = pA4[idx4];
        }
    }
    __syncthreads();
    // ---- LN1 (wave per row)
    int wave = tid >> 6, lane = tid & 63;
    for (int r = wave; r < 64; r += 4) {
        float v0 = xln[r * XLNS + lane];
        float v1 = xln[r * XLNS + 64 + lane];
        float s = v0 + v1, ss = v0 * v0 + v1 * v1;
        for (int off = 32; off > 0; off >>= 1) {
            s += __shfl_xor(s, off);
            ss += __shfl_xor(ss, off);
        }
        float mean = s * (1.0f / 128.0f);
        float var = ss * (1.0f / 128.0f) - mean * mean;
        float rstd = rsqrtf(var + 1e-5f);
        xln[r * XLNS + lane] = (v0 - mean) * rstd * ln1g[lane] + ln1b[lane];
        xln[r * XLNS + 64 + lane] = (v1 - mean) * rstd * ln1g[64 + lane] + ln1b[64 + lane];
    }
    __syncthreads();
    // ---- fragment coordinates
    int q = lane >> 4, c = lane & 15;
    int rbase = wave * 16 + q * 4;                          // C-frag rows (4)
    const float* ax = &xln[(wave * 16 + c) * XLNS + q * 8]; // A-frag base
    // ---- GEMM1: acc = x @ w1
    f32x4 acc[8];
    mlp_gemm(ax, w1f, lane, acc);
    // ---- residual (post-LN1 x) at this thread's C positions
    float res[8][4];
#pragma unroll
    for (int n = 0; n < 8; ++n)
#pragma unroll
        for (int r = 0; r < 4; ++r)
            res[n][r] = xln[(rbase + r) * XLNS + n * 16 + c];
    // ---- bias + gelu
#pragma unroll
    for (int n = 0; n < 8; ++n) {
        float bb = b1[n * 16 + c];
#pragma unroll
        for (int r = 0; r < 4; ++r)
            acc[n][r] = gelu_exact(acc[n][r] + bb);
    }
    __syncthreads();   // all reads of xln(=x) done
#pragma unroll
    for (int n = 0; n < 8; ++n)
#pragma unroll
        for (int r = 0; r < 4; ++r)
            xln[(rbase + r) * XLNS + n * 16 + c] = acc[n][r];   // xln := g
    __syncthreads();
    // ---- GEMM2: acc = g @ w2; h = acc + b2 + res
    mlp_gemm(ax, w2f, lane, acc);
#pragma unroll
    for (int n = 0; n < 8; ++n) {
        float bb = b2[n * 16 + c];
#pragma unroll
        for (int r = 0; r < 4; ++r)
            acc[n][r] += bb + res[n][r];
    }
    // ---- LN2 stats: rows live in 16-lane groups (cols spread over c and n)
    float s4[4] = {0.f, 0.f, 0.f, 0.f}, ss4[4] = {0.f, 0.f, 0.f, 0.f};
#pragma unroll
    for (int n = 0; n < 8; ++n)
#pragma unroll
        for (int r = 0; r < 4; ++r) {
            float h = acc[n][r];
            s4[r] += h; ss4[r] += h * h;
        }
#pragma unroll
    for (int off = 8; off > 0; off >>= 1) {
#pragma unroll
        for (int r = 0; r < 4; ++r) {
            s4[r] += __shfl_xor(s4[r], off);
            ss4[r] += __shfl_xor(ss4[r], off);
        }
    }
    float g2v[8], b2v[8];
#pragma unroll
    for (int n = 0; n < 8; ++n) {
        g2v[n] = ln2g[n * 16 + c];
        b2v[n] = ln2b[n * 16 + c];
    }
#pragma unroll
    for (int r = 0; r < 4; ++r) {
        float mean = s4[r] * (1.0f / 128.0f);
        float var = ss4[r] * (1.0f / 128.0f) - mean * mean;
        float rstd = rsqrtf(var + 1e-5f);
        size_t orow = FUSED ? ((size_t)b * TLEN + t0 + rbase + r) * DD
                            : (R0 + rbase + r) * DD;
#pragma unroll
        for (int n = 0; n < 8; ++n)
            out[orow + n * 16 + c] = (acc[n][r] - mean) * rstd * g2v[n] + b2v[n];
    }
}

// =============== fused2: img_irfft FIRST (blocks 0..447: long-latency blocks
// start at t=0 and hide under addnorm), then addnorm<1> (448..2495).
#define F2_IR  (BB * 14)            // 448
#define F2_AN  (BB * (TLEN / 64))   // 2048

__global__ __launch_bounds__(256) void fused_text_img(
    const float* __restrict__ srcA, const float* __restrict__ ecg,
    const float* __restrict__ ln1g, const float* __restrict__ ln1b,
    const unsigned short* __restrict__ w1f, const float* __restrict__ b1,
    const unsigned short* __restrict__ w2f, const float* __restrict__ b2,
    const float* __restrict__ ln2g, const float* __restrict__ ln2b,
    float* __restrict__ out,
    const float* __restrict__ zi, const float* __restrict__ image,
    float* __restrict__ x0img) {
    __shared__ __align__(16) float xln[64 * XLNS];
    int bid = blockIdx.x;
    int tid = threadIdx.x;
    if (bid >= F2_IR) {
        addnorm_body<1>(bid - F2_IR, xln, srcA, ecg, ln1g, ln1b, w1f, b1,
                        w2f, b2, ln2g, ln2b, out);
    } else {
        // ---------------- img_irfft (ortho) + add image (LDS reuses xln)
        int rel = bid;
        float* ctab = xln;          // [196]
        float* stab = xln + 200;    // [196]
        int b = rel / 14;
        int ng = rel % 14;
        for (int m = tid; m < NPATCH; m += 256) {
            ctab[m] = cospif(m * (2.0f / 196.0f));
            stab[m] = sinpif(m * (2.0f / 196.0f));
        }
        __syncthreads();
        if (tid < 128) {
            int d = tid;
            const float2* zrow = (const float2*)zi + (size_t)b * NFREQ * DD + d;
            float acc[14];
            int mc[14];
            float2 z0 = zrow[0];
#pragma unroll
            for (int j = 0; j < 14; ++j) { acc[j] = z0.x; mc[j] = 0; }
            for (int f = 1; f <= 97; ++f) {
                float2 z = zrow[(size_t)f * DD];
#pragma unroll
                for (int j = 0; j < 14; ++j) {
                    int n = ng * 14 + j;
                    mc[j] += n;
                    if (mc[j] >= NPATCH) mc[j] -= NPATCH;
                    acc[j] += 2.0f * (z.x * ctab[mc[j]] - z.y * stab[mc[j]]);
                }
            }
            float2 z98 = zrow[98 * (size_t)DD];
#pragma unroll
            for (int j = 0; j < 14; ++j) {
                int n = ng * 14 + j;
                float a = acc[j] + ((n & 1) ? -z98.x : z98.x);
                float y = a * (1.0f / 14.0f);
                size_t idx = ((size_t)b * NPATCH + n) * DD + d;
                x0img[idx] = y + image[idx];
            }
        }
    }
}

// non-fused addnorm (image branch, runs last)
__global__ __launch_bounds__(256) void addnorm_img(
    const float* __restrict__ srcA,
    const float* __restrict__ ln1g, const float* __restrict__ ln1b,
    const unsigned short* __restrict__ w1f, const float* __restrict__ b1,
    const unsigned short* __restrict__ w2f, const float* __restrict__ b2,
    const float* __restrict__ ln2g, const float* __restrict__ ln2b,
    float* __restrict__ out) {
    __shared__ __align__(16) float xln[64 * XLNS];
    addnorm_body<0>(blockIdx.x, xln, srcA, nullptr, ln1g, ln1b, w1f, b1,
                    w2f, b2, ln2g, ln2b, out);
}

extern "C" void kernel_launch(void* const* d_in, const int* in_sizes, int n_in,
                              void* d_out, int out_size, void* d_ws, size_t ws_size,
                              hipStream_t stream) {
    (void)in_sizes; (void)n_in; (void)out_size; (void)ws_size;
    const float* ecg   = (const float*)d_in[0];
    const float* image = (const float*)d_in[1];
    const float* tfb   = (const float*)d_in[2];
    const float* ifb   = (const float*)d_in[3];
    const float* sel   = (const float*)d_in[4];
    const float* i2t_w = (const float*)d_in[5];
    const float* i2t_b = (const float*)d_in[6];
    const float* t_ln1_g = (const float*)d_in[7];
    const float* t_ln1_b = (const float*)d_in[8];
    const float* t_w1 = (const float*)d_in[9];
    const float* t_b1 = (const float*)d_in[10];
    const float* t_w2 = (const float*)d_in[11];
    const float* t_b2 = (const float*)d_in[12];
    const float* t_ln2_g = (const float*)d_in[13];
    const float* t_ln2_b = (const float*)d_in[14];
    const float* i_ln1_g = (const float*)d_in[15];
    const float* i_ln1_b = (const float*)d_in[16];
    const float* i_w1 = (const float*)d_in[17];
    const float* i_b1 = (const float*)d_in[18];
    const float* i_w2 = (const float*)d_in[19];
    const float* i_b2 = (const float*)d_in[20];
    const float* i_ln2_g = (const float*)d_in[21];
    const float* i_ln2_b = (const float*)d_in[22];
    float* out = (float*)d_out;
    float* ws = (float*)d_ws;
    unsigned short* wfb = (unsigned short*)(ws + WF_OFF);
    float* gpart = ws + X0I_OFF;   // scratch: free until img_irfft writes x0img

    // launch 1: all independent prep work (img_dft | wfrag | prep_fb | transpose)
    prep_all<<<PA_TOT, 256, 0, stream>>>(
        t_w1, t_w2, i_w1, i_w2, wfb,
        tfb, ws + FBT2_OFF,
        ecg, ws + XT_OFF,
        image, ifb, sel, ws + ZI_OFF, gpart);
    // launch 2: stft -> filter(gate computed in-prologue) -> istft
    stft_filter_istft<<<BB * DD, 256, 0, stream>>>(
        ws + XT_OFF, ws + FBT2_OFF, gpart, i2t_w, i2t_b);
    // launch 3: image irfft (first, latency-bound) | text addnorm
    fused_text_img<<<F2_IR + F2_AN, 256, 0, stream>>>(
        ws + XT_OFF, ecg, t_ln1_g, t_ln1_b, wfb + 0, t_b1, wfb + 32768, t_b2,
        t_ln2_g, t_ln2_b, out,
        ws + ZI_OFF, image, ws + X0I_OFF);
    // launch 4: image addnorm
    addnorm_img<<<(BB * NPATCH) / 64, 256, 0, stream>>>(
        ws + X0I_OFF, i_ln1_g, i_ln1_b, wfb + 65536, i_b1, wfb + 98304, i_b2,
        i_ln2_g, i_ln2_b, out + (size_t)BB * TLEN * DD);
}

// Round 12
// 507.631 us; speedup vs baseline: 1.1975x; 1.0570x over previous
//
#include <hip/hip_runtime.h>
#include <math.h>

#define BB 32
#define DD 128
#define TLEN 4096
#define NSEG 512
#define HOP 256
#define NFR 17
#define NBINS 257
#define STOT 4369
#define NPATCH 196
#define NFREQ 99
#define OLAL 4608

// workspace layout (float offsets)
#define FBT2_OFF 0
#define FBT2_SZ  (DD * NFR * NBINS * 2)       // 1,118,464
#define GBUF_OFF (FBT2_OFF + FBT2_SZ)
#define GATE_OFF (GBUF_OFF + BB * DD)
#define ZI_OFF   (GATE_OFF + BB * DD)
#define ZI_SZ    (BB * NFREQ * DD * 2)        // 811,008
#define X0I_OFF  (ZI_OFF + ZI_SZ)             // x0img (launch2 write, launch3 read)
#define X0I_SZ   (BB * NPATCH * DD)           // 802,816
#define XT_OFF   (X0I_OFF + X0I_SZ)
#define WF_OFF   (XT_OFF + BB * DD * TLEN)    // bf16 hi/lo weight fragments (4 mats x 32768 ushort = 65536 floats)
#define GPART_OFF (WF_OFF + 65536)            // gate partials 11*BB*DD (own slot: must NOT alias x0img)

typedef __attribute__((ext_vector_type(8))) short bf16x8;
typedef __attribute__((ext_vector_type(4))) float f32x4;
typedef __attribute__((ext_vector_type(8))) unsigned short u16x8;

__device__ __forceinline__ float gelu_exact(float x) {
    return 0.5f * x * (1.0f + erff(x * 0.70710678118654752f));
}

__device__ __forceinline__ short bf16_rne(float v) {
    unsigned b = __float_as_uint(v);
    return (short)((b + 0x7fffu + ((b >> 16) & 1u)) >> 16);
}

// split fp32 -> bf16 hi + bf16 lo (v ~= hi + lo, error ~2^-17 relative)
__device__ __forceinline__ void split8(float4 a, float4 b, bf16x8& hi, bf16x8& lo) {
    float v[8] = {a.x, a.y, a.z, a.w, b.x, b.y, b.z, b.w};
#pragma unroll
    for (int e = 0; e < 8; ++e) {
        unsigned bv = __float_as_uint(v[e]);
        unsigned hb = (bv + 0x7fffu + ((bv >> 16) & 1u)) & 0xffff0000u;
        float hf = __uint_as_float(hb);
        hi[e] = (short)(hb >> 16);
        lo[e] = bf16_rne(v[e] - hf);
    }
}

// =============== merged prep kernel: img_dft | prep_wfrag | prep_fb | transpose
#define PA_DFT0   0
#define PA_DFTN   (BB * 11)                     // 352
#define PA_WF0    (PA_DFT0 + PA_DFTN)           // 352
#define PA_WFN    32
#define PA_FB0    (PA_WF0 + PA_WFN)             // 384
#define PA_FBN    ((STOT * DD + 255) / 256)     // 2185
#define PA_TR0    (PA_FB0 + PA_FBN)             // 2569
#define PA_TRN    ((TLEN / 32) * (DD / 32) * BB) // 16384
#define PA_TOT    (PA_TR0 + PA_TRN)             // 18953

__global__ __launch_bounds__(256) void prep_all(
    const float* __restrict__ tw1, const float* __restrict__ tw2,
    const float* __restrict__ iw1, const float* __restrict__ iw2,
    unsigned short* __restrict__ outw,
    const float* __restrict__ tfb, float* __restrict__ fbt2,
    const float* __restrict__ ecg, float* __restrict__ xT,
    const float* __restrict__ image, const float* __restrict__ ifb,
    const float* __restrict__ sel, float* __restrict__ zi,
    float* __restrict__ gpart) {
    __shared__ float smem[32 * 33];   // transpose tile / img_dft trig tables
    int bid = blockIdx.x;
    int tid = threadIdx.x;

    if (bid < PA_DFTN) {
        // ---------------- img_dft: rfft(ortho) + filter; partial g to gpart
        float* ctab = smem;           // [196]
        float* stab = smem + 200;     // [196]
        int b = bid / 11;
        int fg = bid % 11;
        for (int m = tid; m < NPATCH; m += 256) {
            ctab[m] = cospif(m * (2.0f / 196.0f));
            stab[m] = sinpif(m * (2.0f / 196.0f));
        }
        __syncthreads();
        if (tid < 128) {
            int d = tid;
            float accr[9], acci[9];
            int mc[9];
#pragma unroll
            for (int j = 0; j < 9; ++j) { accr[j] = 0.0f; acci[j] = 0.0f; mc[j] = 0; }
            const float* img = image + (size_t)b * NPATCH * DD + d;
            for (int n = 0; n < NPATCH; ++n) {
                float v = img[(size_t)n * DD];
#pragma unroll
                for (int j = 0; j < 9; ++j) {
                    float c = ctab[mc[j]], s = stab[mc[j]];
                    accr[j] += v * c;
                    acci[j] -= v * s;
                    mc[j] += fg * 9 + j;
                    if (mc[j] >= NPATCH) mc[j] -= NPATCH;
                }
            }
            float gg = 0.0f;
#pragma unroll
            for (int j = 0; j < 9; ++j) {
                int f = fg * 9 + j;
                float Xr = accr[j] * (1.0f / 14.0f);
                float Xi = acci[j] * (1.0f / 14.0f);
                float sr = (Xr * Xr - Xi * Xi) * (1.0f / 99.0f);
                float si = 2.0f * Xr * Xi * (1.0f / 99.0f);
                float2 f0 = ((const float2*)ifb)[f * DD + d];
                float2 f1 = ((const float2*)ifb)[NFREQ * DD + f * DD + d];
                float fbr = -(f0.x + f1.x), fbi = -(f0.y + f1.y);
                float zr = sr * fbr - si * fbi;
                float zm = sr * fbi + si * fbr;
                float2 o; o.x = zr; o.y = zm;
                ((float2*)zi)[((size_t)b * NFREQ + f) * DD + d] = o;
                float2 sl = ((const float2*)sel)[f * DD + d];
                gg += zr * sl.x - zm * sl.y;
            }
            gpart[((size_t)fg * BB + b) * DD + d] = gg * (1.0f / 99.0f);
        }
    } else if (bid < PA_FB0) {
        // ---------------- prep_wfrag
        int id = (bid - PA_WF0) * 256 + tid;
        if (id < 4 * 2048) {
            int m = id >> 11;
            int r = id & 2047;
            int kt = r >> 9;
            int n = (r >> 6) & 7;
            int lane = r & 63;
            int k0 = kt * 32 + (lane >> 4) * 8;
            int col = n * 16 + (lane & 15);
            const float* w = (m == 0) ? tw1 : (m == 1) ? tw2 : (m == 2) ? iw1 : iw2;
            u16x8 hi, lo;
#pragma unroll
            for (int e = 0; e < 8; ++e) {
                float v = w[(size_t)(k0 + e) * DD + col];
                unsigned bv = __float_as_uint(v);
                unsigned hb = (bv + 0x7fffu + ((bv >> 16) & 1u)) & 0xffff0000u;
                float hf = __uint_as_float(hb);
                float lres = v - hf;
                unsigned bl = __float_as_uint(lres);
                hi[e] = (unsigned short)(hb >> 16);
                lo[e] = (unsigned short)((bl + 0x7fffu + ((bl >> 16) & 1u)) >> 16);
            }
            u16x8* base = (u16x8*)(outw + (size_t)m * 32768);
            base[r] = hi;
            base[2048 + r] = lo;
        }
    } else if (bid < PA_TR0) {
        // ---------------- prep_fb: tfb -> fbt2 (D,17,257,2)
        int idx = (bid - PA_FB0) * 256 + tid;
        if (idx < STOT * DD) {
            int d = idx & 127;
            int s = idx >> 7;
            float2 a = ((const float2*)tfb)[s * DD + d];
            float2 b2 = ((const float2*)tfb)[STOT * DD + s * DD + d];
            int f = s / NFR, t = s % NFR;
            float2 r;
            r.x = -(a.x + b2.x);
            r.y = -(a.y + b2.y);
            ((float2*)fbt2)[((size_t)d * NFR + t) * NBINS + f] = r;
        }
    } else {
        // ---------------- transpose ecg (B,T,D) -> (B,D,T)
        int rel = bid - PA_TR0;
        int t0 = (rel & 127) * 32;
        int d0 = ((rel >> 7) & 3) * 32;
        int b = rel >> 9;
        int lx = tid & 31;
        int ly = tid >> 5;   // 0..7
        float (*tile)[33] = (float (*)[33])smem;
        for (int i = ly; i < 32; i += 8)
            tile[i][lx] = ecg[((size_t)b * TLEN + t0 + i) * DD + d0 + lx];
        __syncthreads();
        for (int i = ly; i < 32; i += 8)
            xT[((size_t)b * DD + d0 + i) * TLEN + t0 + lx] = tile[lx][i];
    }
}

// ============ launch 2: img_irfft (blocks 0..447, latency-bound, start early)
//              | stft_filter_istft (blocks 448..4543)
// Register-resident 256-pt complex FFT per wave; fused middle phase; gate
// computed in-prologue from gpart (own workspace slot -- must not alias x0img,
// which the irfft blocks write concurrently in this same launch).
#define SI_IR  (BB * 14)    // 448
#define SI_ST  (BB * DD)    // 4096

#define SWZ(e) ((e) ^ (((e) >> 4) & 15))

#define CMULW(dr, di, c, s, xr, xi) { float _t = (dr)*(c) - (di)*(s); xi = (dr)*(s) + (di)*(c); xr = _t; }
#define BF(xr, xi, h) { \
    float pr_ = __shfl_xor(xr, h), pi_ = __shfl_xor(xi, h); \
    float dr2_ = fmaf(sg##h, xr, pr_), di2_ = fmaf(sg##h, xi, pi_); \
    CMULW(dr2_, di2_, tc##h, ts##h, xr, xi) }
#define SSTG(h) BF(a0r, a0i, h) BF(a1r, a1i, h) BF(a2r, a2i, h) BF(a3r, a3i, h)
#define BF1(xr, xi) { \
    float pr_ = __shfl_xor(xr, 1), pi_ = __shfl_xor(xi, 1); \
    xr = fmaf(sg1, xr, pr_); xi = fmaf(sg1, xi, pi_); }
#define DIF256() { \
    float dr_, di_; \
    dr_ = a0r - a2r; di_ = a0i - a2i; a0r += a2r; a0i += a2i; CMULW(dr_, di_, wa_c, wa_s, a2r, a2i) \
    dr_ = a1r - a3r; di_ = a1i - a3i; a1r += a3r; a1i += a3i; CMULW(dr_, di_, wb_c, wb_s, a3r, a3i) \
    dr_ = a0r - a1r; di_ = a0i - a1i; a0r += a1r; a0i += a1i; CMULW(dr_, di_, wc_c, wc_s, a1r, a1i) \
    dr_ = a2r - a3r; di_ = a2i - a3i; a2r += a3r; a2i += a3i; CMULW(dr_, di_, wc_c, wc_s, a3r, a3i) \
    SSTG(32) SSTG(16) SSTG(8) SSTG(4) SSTG(2) \
    BF1(a0r, a0i) BF1(a1r, a1i) BF1(a2r, a2i) BF1(a3r, a3i) }

__global__ __launch_bounds__(256, 4) void stft_img(
    float* xT, const float* __restrict__ fbt2,
    const float* __restrict__ gpart, const float* __restrict__ i2t_w,
    const float* __restrict__ i2t_b,
    const float* __restrict__ zi, const float* __restrict__ image,
    float* __restrict__ x0img) {
    __shared__ float2 spec[NFR * 256];   // 34816 B (irfft reuses as trig tables)
    __shared__ float win[NSEG];          // 2048 B
    __shared__ float rnorm[256];         // 1024 B
    __shared__ float mct[129], mst[129]; // 1032 B middle-phase trig
    __shared__ float gtmp[DD];           // 512 B gate partials
    __shared__ float gatsh;
    int tid = threadIdx.x;

    if (blockIdx.x < SI_IR) {
        // ---------------- img_irfft (ortho) + add image
        int rel = blockIdx.x;
        float* ctab = (float*)spec;        // [196]
        float* stab = (float*)spec + 200;  // [196]
        int b = rel / 14;
        int ng = rel % 14;
        for (int m = tid; m < NPATCH; m += 256) {
            ctab[m] = cospif(m * (2.0f / 196.0f));
            stab[m] = sinpif(m * (2.0f / 196.0f));
        }
        __syncthreads();
        if (tid < 128) {
            int d = tid;
            const float2* zrow = (const float2*)zi + (size_t)b * NFREQ * DD + d;
            float acc[14];
            int mc[14];
            float2 z0 = zrow[0];
#pragma unroll
            for (int j = 0; j < 14; ++j) { acc[j] = z0.x; mc[j] = 0; }
            for (int f = 1; f <= 97; ++f) {
                float2 z = zrow[(size_t)f * DD];
#pragma unroll
                for (int j = 0; j < 14; ++j) {
                    int n = ng * 14 + j;
                    mc[j] += n;
                    if (mc[j] >= NPATCH) mc[j] -= NPATCH;
                    acc[j] += 2.0f * (z.x * ctab[mc[j]] - z.y * stab[mc[j]]);
                }
            }
            float2 z98 = zrow[98 * (size_t)DD];
#pragma unroll
            for (int j = 0; j < 14; ++j) {
                int n = ng * 14 + j;
                float a = acc[j] + ((n & 1) ? -z98.x : z98.x);
                float y = a * (1.0f / 14.0f);
                size_t idx = ((size_t)b * NPATCH + n) * DD + d;
                x0img[idx] = y + image[idx];
            }
        }
        return;
    }

    // ---------------- stft -> filter*gate -> istft
    int lane = tid & 63, wave = tid >> 6;
    int bd = blockIdx.x - SI_IR;      // b*128 + d
    int d = bd & 127;
    int b = bd >> 7;
    float* xrow = xT + (size_t)bd * TLEN;
    const float2* fbrow = (const float2*)(fbt2 + (size_t)d * NFR * NBINS * 2);
    float ib = i2t_b[d];

    for (int j = tid; j < NSEG; j += 256)
        win[j] = 0.5f - 0.5f * cospif(j * (1.0f / 256.0f));   // sin^2(pi j/512)
    {
        float s2 = 0.5f - 0.5f * cospif(tid * (1.0f / 256.0f));
        float c2 = 1.0f - s2;
        rnorm[tid] = 1.0f / (s2 * s2 + c2 * c2);
    }
    if (tid < 129) {
        mct[tid] = cospif(tid * (1.0f / 256.0f));
        mst[tid] = sinpif(tid * (1.0f / 256.0f));
    }
    if (tid < 128) {
        float s = 0.0f;
#pragma unroll
        for (int fg = 0; fg < 11; ++fg)
            s += gpart[((size_t)fg * BB + b) * DD + tid];
        gtmp[tid] = s * i2t_w[(size_t)d * DD + tid];
    }

    // ---- hoisted twiddles (W = e^{-2pi i k/256}; ts holds -sin)
    float wa_c = cospif(lane * (1.0f / 128.0f)), wa_s = -sinpif(lane * (1.0f / 128.0f));
    float wb_c = cospif((64 + lane) * (1.0f / 128.0f)), wb_s = -sinpif((64 + lane) * (1.0f / 128.0f));
    float wc_c = cospif(lane * (1.0f / 64.0f)),  wc_s = -sinpif(lane * (1.0f / 64.0f));
#define MKT(h) \
    float tc##h, ts##h, sg##h; \
    { int set_ = lane & h; float ang_ = (float)(lane & (h - 1)) * (1.0f / h); \
      tc##h = set_ ? cospif(ang_) : 1.0f; \
      ts##h = set_ ? -sinpif(ang_) : 0.0f; \
      sg##h = set_ ? -1.0f : 1.0f; }
    MKT(32) MKT(16) MKT(8) MKT(4) MKT(2)
    float sg1 = (lane & 1) ? -1.0f : 1.0f;
#undef MKT

    // scatter (bitrev) and gather (natural) element addresses, swizzled
    int eS[4], eL[4];
#pragma unroll
    for (int j = 0; j < 4; ++j) {
        int i = j * 64 + lane;
        eS[j] = SWZ((int)(__brev((unsigned)i) >> 24));
        eL[j] = SWZ(i);
    }
    __syncthreads();

    // gate reduce (wave 0 only; published by the post-forward barrier)
    if (tid < 64) {
        float v = gtmp[tid] + gtmp[tid + 64];
        for (int off = 32; off > 0; off >>= 1) v += __shfl_xor(v, off);
        if (tid == 0) gatsh = ib + v;
    }

    // ---- forward: load+window -> DIF -> scatter spectrum (natural order)
    for (int t = wave; t < NFR; t += 4) {
        float a0r, a0i, a1r, a1i, a2r, a2i, a3r, a3i;
#define LOADJ(j, xr, xi) { \
        int i_ = (j) * 64 + lane; \
        int src_ = t * HOP + 2 * i_ - HOP; \
        float er_ = 0.0f, oi_ = 0.0f; \
        if (src_ >= 0 && src_ < TLEN) { \
            float2 v_ = *(const float2*)(xrow + src_); er_ = v_.x; oi_ = v_.y; } \
        float2 w_ = *(const float2*)(win + 2 * i_); \
        xr = er_ * w_.x; xi = oi_ * w_.y; }
        LOADJ(0, a0r, a0i) LOADJ(1, a1r, a1i) LOADJ(2, a2r, a2i) LOADJ(3, a3r, a3i)
#undef LOADJ
        DIF256()
        float2* sp = spec + t * 256;
        sp[eS[0]] = make_float2(a0r, a0i);
        sp[eS[1]] = make_float2(a1r, a1i);
        sp[eS[2]] = make_float2(a2r, a2i);
        sp[eS[3]] = make_float2(a3r, a3i);
    }
    __syncthreads();

    const float scl = gatsh * (1.0f / 4369.0f);

    // ---- middle (fused): rfft unpack -> square -> filter*gate -> conj repack
    for (int j = tid; j < NFR * 129; j += 256) {
        int t = j / 129, m = j - t * 129;
        float2* sp = spec + t * 256;
        const float2* fbr = fbrow + t * NBINS;
        if (m == 0) {
            float2 v = sp[0];
            float re = v.x, im = v.y;
            float z0 = (re + im) * (1.0f / 256.0f);
            float zN = (re - im) * (1.0f / 256.0f);
            float2 fb0 = fbr[0], fbN = fbr[256];
            float y1r = z0 * z0 * fb0.x * scl;
            float y2r = zN * zN * fbN.x * scl;
            float Er = 0.5f * (y1r + y2r);
            float Dr = 0.5f * (y1r - y2r);
            sp[0] = make_float2(Er, -Dr);
        } else if (m == 128) {
            float2 v = sp[SWZ(128)];
            float Zr = v.x, Zi = v.y;
            float zr = Zr * (1.0f / 256.0f), zi2 = -Zi * (1.0f / 256.0f);
            float sr = zr * zr - zi2 * zi2, si = 2.0f * zr * zi2;
            float2 fb = fbr[128];
            sp[SWZ(128)] = make_float2((sr * fb.x - si * fb.y) * scl,
                                       (sr * fb.y + si * fb.x) * scl);
        } else {
            float2 vm = sp[SWZ(m)];
            float2 vc = sp[SWZ(256 - m)];
            float Amr = vm.x, Ami = vm.y;
            float Acr = vc.x, Aci = vc.y;
            float c = mct[m];
            float sn = mst[m];
            float y1r, y1i, y2r, y2i;
            {
                float Br = Acr, Bi = -Aci;
                float xer = 0.5f * (Amr + Br), xei = 0.5f * (Ami + Bi);
                float xo_r = 0.5f * (Ami - Bi), xo_i = -0.5f * (Amr - Br);
                float Xr = xer + c * xo_r + sn * xo_i;
                float Xi = xei + c * xo_i - sn * xo_r;
                float zr = Xr * (1.0f / 256.0f), zi2 = Xi * (1.0f / 256.0f);
                float sr = zr * zr - zi2 * zi2, si = 2.0f * zr * zi2;
                float2 fb = fbr[m];
                y1r = (sr * fb.x - si * fb.y) * scl;
                y1i = (sr * fb.y + si * fb.x) * scl;
            }
            {
                float Br = Amr, Bi = -Ami;
                float xer = 0.5f * (Acr + Br), xei = 0.5f * (Aci + Bi);
                float xo_r = 0.5f * (Aci - Bi), xo_i = -0.5f * (Acr - Br);
                float Xr = xer - c * xo_r + sn * xo_i;
                float Xi = xei - c * xo_i - sn * xo_r;
                float zr = Xr * (1.0f / 256.0f), zi2 = Xi * (1.0f / 256.0f);
                float sr = zr * zr - zi2 * zi2, si = 2.0f * zr * zi2;
                float2 fb = fbr[256 - m];
                y2r = (sr * fb.x - si * fb.y) * scl;
                y2i = (sr * fb.y + si * fb.x) * scl;
            }
            float Er = 0.5f * (y1r + y2r);
            float Ei = 0.5f * (y1i - y2i);
            float Dr = 0.5f * (y1r - y2r);
            float Di = 0.5f * (y1i + y2i);
            float Or = Dr * c - Di * sn;
            float Oi = Dr * sn + Di * c;
            sp[SWZ(m)] = make_float2(Er - Oi, -(Ei + Or));
            sp[SWZ(256 - m)] = make_float2(Er + Oi, Ei - Or);
        }
    }
    __syncthreads();

    // ---- inverse: gather conj(B) natural -> same DIF -> scatter time domain
    for (int t = wave; t < NFR; t += 4) {
        float2* sp = spec + t * 256;
        float2 v0 = sp[eL[0]], v1 = sp[eL[1]], v2 = sp[eL[2]], v3 = sp[eL[3]];
        float a0r = v0.x, a0i = v0.y, a1r = v1.x, a1i = v1.y;
        float a2r = v2.x, a2i = v2.y, a3r = v3.x, a3i = v3.y;
        DIF256()
        sp[eS[0]] = make_float2(a0r, a0i);
        sp[eS[1]] = make_float2(a1r, a1i);
        sp[eS[2]] = make_float2(a2r, a2i);
        sp[eS[3]] = make_float2(a3r, a3i);
    }
    __syncthreads();

    // ---- OLA (even sample = re, odd = -im)
    const float* specf = (const float*)spec;
    for (int j = tid; j < TLEN; j += 256) {
        int p = j + HOP;
        int t1 = p >> 8, t0 = t1 - 1;
        int i1 = p & 255, i0 = i1 + 256;
        int comp = j & 1;
        float v1 = specf[(t1 * 256 + SWZ(i1 >> 1)) * 2 + comp];
        float v0 = specf[(t0 * 256 + SWZ(i0 >> 1)) * 2 + comp];
        if (comp) { v1 = -v1; v0 = -v0; }
        float s = v0 * win[i0] + v1 * win[i1];
        xrow[j] = s * rnorm[i1];
    }
}

// ------------------------------- addnorm body: LN1 -> split-bf16 MFMA MLP -> LN2
// r11 verified structure (srcB register prefetch hides under srcA scatter).
#define XLNS 132

__device__ __forceinline__ void mlp_gemm(const float* __restrict__ ax,
                                         const unsigned short* __restrict__ wf,
                                         int lane, f32x4 acc[8]) {
#pragma unroll
    for (int n = 0; n < 8; ++n) acc[n] = (f32x4){0.f, 0.f, 0.f, 0.f};
    const bf16x8* bh0 = (const bf16x8*)wf;
    const bf16x8* bl0 = (const bf16x8*)(wf + 16384);
#pragma unroll 1
    for (int kt = 0; kt < 4; ++kt) {
        float4 va = *(const float4*)(ax + kt * 32);
        float4 vb = *(const float4*)(ax + kt * 32 + 4);
        bf16x8 ahi, alo;
        split8(va, vb, ahi, alo);
        const bf16x8* bh = bh0 + kt * 512 + lane;
        const bf16x8* bl = bl0 + kt * 512 + lane;
#pragma unroll
        for (int n = 0; n < 8; ++n) {
            bf16x8 wh = bh[n * 64];
            bf16x8 wl = bl[n * 64];
            acc[n] = __builtin_amdgcn_mfma_f32_16x16x32_bf16(ahi, wh, acc[n], 0, 0, 0);
            acc[n] = __builtin_amdgcn_mfma_f32_16x16x32_bf16(alo, wh, acc[n], 0, 0, 0);
            acc[n] = __builtin_amdgcn_mfma_f32_16x16x32_bf16(ahi, wl, acc[n], 0, 0, 0);
        }
    }
}

template <int FUSED>
__device__ __forceinline__ void addnorm_body(
    int bid, float* xln,
    const float* __restrict__ srcA, const float* __restrict__ srcB,
    const float* __restrict__ ln1g, const float* __restrict__ ln1b,
    const unsigned short* __restrict__ w1f, const float* __restrict__ b1,
    const unsigned short* __restrict__ w2f, const float* __restrict__ b2,
    const float* __restrict__ ln2g, const float* __restrict__ ln2b,
    float* __restrict__ out) {
    int tid = threadIdx.x;
    int b = 0, t0 = 0;
    size_t R0 = 0;
    // ---- Phase A: build x0
    if (FUSED) {
        b = bid >> 6;
        t0 = (bid & 63) * 64;
        // prefetch srcB (row-major, coalesced float4) into registers
        float4 rb[8];
        const float4* pB4 = (const float4*)(srcB + ((size_t)b * TLEN + t0) * DD);
#pragma unroll
        for (int k = 0; k < 8; ++k) rb[k] = pB4[tid + 256 * k];
        // srcA (B,D,T) transpose-scatter into LDS
        for (int i = tid; i < 64 * 128; i += 256) {
            int dd = i >> 6, r = i & 63;
            xln[r * XLNS + dd] = srcA[((size_t)b * DD + dd) * TLEN + t0 + r];
        }
        __syncthreads();
        // add prefetched srcB (vector LDS RMW)
#pragma unroll
        for (int k = 0; k < 8; ++k) {
            int idx4 = tid + 256 * k;
            int r = idx4 >> 5, c4 = idx4 & 31;
            float4* p = (float4*)&xln[r * XLNS + c4 * 4];
            float4 x = *p;
            x.x += rb[k].x; x.y += rb[k].y; x.z += rb[k].z; x.w += rb[k].w;
            *p = x;
        }
    } else {
        R0 = (size_t)bid * 64;
        const float4* pA4 = (const float4*)(srcA + R0 * DD);
#pragma unroll
        for (int k = 0; k < 8; ++k) {
            int idx4 = tid + 256 * k;
            int r = idx4 >> 5, c4 = idx4 & 31;
            *(float4*)&xln[r * XLNS + c4 * 4] = pA4[idx4];
        }
    }
    __syncthreads();
    // ---- LN1 (wave per row)
    int wave = tid >> 6, lane = tid & 63;
    for (int r = wave; r < 64; r += 4) {
        float v0 = xln[r * XLNS + lane];
        float v1 = xln[r * XLNS + 64 + lane];
        float s = v0 + v1, ss = v0 * v0 + v1 * v1;
        for (int off = 32; off > 0; off >>= 1) {
            s += __shfl_xor(s, off);
            ss += __shfl_xor(ss, off);
        }
        float mean = s * (1.0f / 128.0f);
        float var = ss * (1.0f / 128.0f) - mean * mean;
        float rstd = rsqrtf(var + 1e-5f);
        xln[r * XLNS + lane] = (v0 - mean) * rstd * ln1g[lane] + ln1b[lane];
        xln[r * XLNS + 64 + lane] = (v1 - mean) * rstd * ln1g[64 + lane] + ln1b[64 + lane];
    }
    __syncthreads();
    // ---- fragment coordinates
    int q = lane >> 4, c = lane & 15;
    int rbase = wave * 16 + q * 4;                          // C-frag rows (4)
    const float* ax = &xln[(wave * 16 + c) * XLNS + q * 8]; // A-frag base
    // ---- GEMM1: acc = x @ w1
    f32x4 acc[8];
    mlp_gemm(ax, w1f, lane, acc);
    // ---- residual (post-LN1 x) at this thread's C positions
    float res[8][4];
#pragma unroll
    for (int n = 0; n < 8; ++n)
#pragma unroll
        for (int r = 0; r < 4; ++r)
            res[n][r] = xln[(rbase + r) * XLNS + n * 16 + c];
    // ---- bias + gelu
#pragma unroll
    for (int n = 0; n < 8; ++n) {
        float bb = b1[n * 16 + c];
#pragma unroll
        for (int r = 0; r < 4; ++r)
            acc[n][r] = gelu_exact(acc[n][r] + bb);
    }
    __syncthreads();   // all reads of xln(=x) done
#pragma unroll
    for (int n = 0; n < 8; ++n)
#pragma unroll
        for (int r = 0; r < 4; ++r)
            xln[(rbase + r) * XLNS + n * 16 + c] = acc[n][r];   // xln := g
    __syncthreads();
    // ---- GEMM2: acc = g @ w2; h = acc + b2 + res
    mlp_gemm(ax, w2f, lane, acc);
#pragma unroll
    for (int n = 0; n < 8; ++n) {
        float bb = b2[n * 16 + c];
#pragma unroll
        for (int r = 0; r < 4; ++r)
            acc[n][r] += bb + res[n][r];
    }
    // ---- LN2 stats: rows live in 16-lane groups (cols spread over c and n)
    float s4[4] = {0.f, 0.f, 0.f, 0.f}, ss4[4] = {0.f, 0.f, 0.f, 0.f};
#pragma unroll
    for (int n = 0; n < 8; ++n)
#pragma unroll
        for (int r = 0; r < 4; ++r) {
            float h = acc[n][r];
            s4[r] += h; ss4[r] += h * h;
        }
#pragma unroll
    for (int off = 8; off > 0; off >>= 1) {
#pragma unroll
        for (int r = 0; r < 4; ++r) {
            s4[r] += __shfl_xor(s4[r], off);
            ss4[r] += __shfl_xor(ss4[r], off);
        }
    }
    float g2v[8], b2v[8];
#pragma unroll
    for (int n = 0; n < 8; ++n) {
        g2v[n] = ln2g[n * 16 + c];
        b2v[n] = ln2b[n * 16 + c];
    }
#pragma unroll
    for (int r = 0; r < 4; ++r) {
        float mean = s4[r] * (1.0f / 128.0f);
        float var = ss4[r] * (1.0f / 128.0f) - mean * mean;
        float rstd = rsqrtf(var + 1e-5f);
        size_t orow = FUSED ? ((size_t)b * TLEN + t0 + rbase + r) * DD
                            : (R0 + rbase + r) * DD;
#pragma unroll
        for (int n = 0; n < 8; ++n)
            out[orow + n * 16 + c] = (acc[n][r] - mean) * rstd * g2v[n] + b2v[n];
    }
}

// ============ launch 3: addnorm<0> (img, blocks 0..97) | addnorm<1> (text)
#define A3_IM  ((BB * NPATCH) / 64)   // 98
#define A3_AN  (BB * (TLEN / 64))     // 2048

__global__ __launch_bounds__(256) void addnorm_all(
    const float* __restrict__ x0img,
    const float* __restrict__ i_ln1g, const float* __restrict__ i_ln1b,
    const unsigned short* __restrict__ i_w1f, const float* __restrict__ i_b1,
    const unsigned short* __restrict__ i_w2f, const float* __restrict__ i_b2,
    const float* __restrict__ i_ln2g, const float* __restrict__ i_ln2b,
    float* __restrict__ out_img,
    const float* __restrict__ xT, const float* __restrict__ ecg,
    const float* __restrict__ t_ln1g, const float* __restrict__ t_ln1b,
    const unsigned short* __restrict__ t_w1f, const float* __restrict__ t_b1,
    const unsigned short* __restrict__ t_w2f, const float* __restrict__ t_b2,
    const float* __restrict__ t_ln2g, const float* __restrict__ t_ln2b,
    float* __restrict__ out_text) {
    __shared__ __align__(16) float xln[64 * XLNS];
    int bid = blockIdx.x;
    if (bid < A3_IM) {
        addnorm_body<0>(bid, xln, x0img, nullptr, i_ln1g, i_ln1b, i_w1f, i_b1,
                        i_w2f, i_b2, i_ln2g, i_ln2b, out_img);
    } else {
        addnorm_body<1>(bid - A3_IM, xln, xT, ecg, t_ln1g, t_ln1b, t_w1f, t_b1,
                        t_w2f, t_b2, t_ln2g, t_ln2b, out_text);
    }
}

extern "C" void kernel_launch(void* const* d_in, const int* in_sizes, int n_in,
                              void* d_out, int out_size, void* d_ws, size_t ws_size,
                              hipStream_t stream) {
    (void)in_sizes; (void)n_in; (void)out_size; (void)ws_size;
    const float* ecg   = (const float*)d_in[0];
    const float* image = (const float*)d_in[1];
    const float* tfb   = (const float*)d_in[2];
    const float* ifb   = (const float*)d_in[3];
    const float* sel   = (const float*)d_in[4];
    const float* i2t_w = (const float*)d_in[5];
    const float* i2t_b = (const float*)d_in[6];
    const float* t_ln1_g = (const float*)d_in[7];
    const float* t_ln1_b = (const float*)d_in[8];
    const float* t_w1 = (const float*)d_in[9];
    const float* t_b1 = (const float*)d_in[10];
    const float* t_w2 = (const float*)d_in[11];
    const float* t_b2 = (const float*)d_in[12];
    const float* t_ln2_g = (const float*)d_in[13];
    const float* t_ln2_b = (const float*)d_in[14];
    const float* i_ln1_g = (const float*)d_in[15];
    const float* i_ln1_b = (const float*)d_in[16];
    const float* i_w1 = (const float*)d_in[17];
    const float* i_b1 = (const float*)d_in[18];
    const float* i_w2 = (const float*)d_in[19];
    const float* i_b2 = (const float*)d_in[20];
    const float* i_ln2_g = (const float*)d_in[21];
    const float* i_ln2_b = (const float*)d_in[22];
    float* out = (float*)d_out;
    float* ws = (float*)d_ws;
    unsigned short* wfb = (unsigned short*)(ws + WF_OFF);
    float* gpart = ws + GPART_OFF;

    // launch 1: all independent prep work (img_dft | wfrag | prep_fb | transpose)
    prep_all<<<PA_TOT, 256, 0, stream>>>(
        t_w1, t_w2, i_w1, i_w2, wfb,
        tfb, ws + FBT2_OFF,
        ecg, ws + XT_OFF,
        image, ifb, sel, ws + ZI_OFF, gpart);
    // launch 2: image irfft (first, latency-bound) | stft->filter->istft
    stft_img<<<SI_IR + SI_ST, 256, 0, stream>>>(
        ws + XT_OFF, ws + FBT2_OFF, gpart, i2t_w, i2t_b,
        ws + ZI_OFF, image, ws + X0I_OFF);
    // launch 3: image addnorm (first) | text addnorm
    addnorm_all<<<A3_IM + A3_AN, 256, 0, stream>>>(
        ws + X0I_OFF, i_ln1_g, i_ln1_b, wfb + 65536, i_b1, wfb + 98304, i_b2,
        i_ln2_g, i_ln2_b, out + (size_t)BB * TLEN * DD,
        ws + XT_OFF, ecg, t_ln1_g, t_ln1_b, wfb + 0, t_b1, wfb + 32768, t_b2,
        t_ln2_g, t_ln2_b, out);
}